// Round 1
// baseline (13196.800 us; speedup 1.0000x reference)
//
#include <hip/hip_runtime.h>
#include <hip/hip_bf16.h>

#define NA 100000
#define NB 50000
#define EAA 1600000
#define EAB 800000
#define EBB 800000

typedef __hip_bfloat16 bf16;

__device__ __forceinline__ float b2f(bf16 v) { return __bfloat162float(v); }

// ---------------- CSR build ----------------
__global__ __launch_bounds__(256) void k_hist(const int* __restrict__ dst, int* __restrict__ cnt, int n) {
  int i = blockIdx.x * 256 + threadIdx.x;
  if (i < n) atomicAdd(&cnt[dst[i]], 1);
}

__global__ __launch_bounds__(256) void k_alloc(const int* __restrict__ cnt, int* __restrict__ start,
                                               int* __restrict__ counter, int n) {
  __shared__ int sdata[256];
  __shared__ int sbase;
  int tid = threadIdx.x;
  int i = blockIdx.x * 256 + tid;
  int v = (i < n) ? cnt[i] : 0;
  sdata[tid] = v;
  __syncthreads();
  for (int offs = 1; offs < 256; offs <<= 1) {
    int t = sdata[tid];
    if (tid >= offs) t += sdata[tid - offs];
    __syncthreads();
    sdata[tid] = t;
    __syncthreads();
  }
  if (tid == 255) sbase = atomicAdd(counter, sdata[255]);
  __syncthreads();
  if (i < n) start[i] = sbase + sdata[tid] - v;  // exclusive prefix + block base
}

__global__ __launch_bounds__(256) void k_fill(const int* __restrict__ src, const int* __restrict__ dst,
                                              const int* __restrict__ start, int* __restrict__ fill,
                                              int* __restrict__ col, int n) {
  int i = blockIdx.x * 256 + threadIdx.x;
  if (i < n) {
    int d = dst[i];
    int p = atomicAdd(&fill[d], 1);
    col[start[d] + p] = src[i];
  }
}

// ---------------- linear: t[g][n][c] = x[n] @ lin_w[g][side]  ----------------
__global__ __launch_bounds__(256) void k_lin(const float* __restrict__ x, const float* __restrict__ lin_w,
                                             int side, bf16* __restrict__ t, int N) {
  __shared__ float wT[4][64][36];   // [gate][c][k], padded
  __shared__ float xL[4][32];
  for (int idx = threadIdx.x; idx < 4 * 32 * 64; idx += 256) {
    int g = idx >> 11; int r = idx & 2047; int k = r >> 6; int c = r & 63;
    wT[g][c][k] = lin_w[((g * 2 + side) * 32 + k) * 64 + c];
  }
  __syncthreads();
  int wave = threadIdx.x >> 6, lane = threadIdx.x & 63;
  for (int j = 0; j < 16; ++j) {
    int n = blockIdx.x * 64 + wave * 16 + j;
    bool act = n < N;
    if (act && lane < 32) xL[wave][lane] = x[(size_t)n * 32 + lane];
    asm volatile("s_waitcnt lgkmcnt(0)" ::: "memory");
    if (act) {
      #pragma unroll
      for (int g = 0; g < 4; ++g) {
        float acc = 0.f;
        #pragma unroll
        for (int ks = 0; ks < 8; ++ks) {
          float4 xv = *(const float4*)&xL[wave][ks * 4];
          float4 wv = *(const float4*)&wT[g][lane][ks * 4];
          acc += xv.x * wv.x + xv.y * wv.y + xv.z * wv.z + xv.w * wv.w;
        }
        t[((size_t)g * N + n) * 64 + lane] = __float2bfloat16(acc);
      }
    }
    asm volatile("s_waitcnt lgkmcnt(0)" ::: "memory");
  }
}

// mean-agg of one dst row; lane = channel. st/deg are wave-uniform scalars.
__device__ __forceinline__ float agg_row(const bf16* __restrict__ plane, const int* __restrict__ col,
                                         int st, int deg, int lane) {
  float s = 0.f;
  int e = 0;
  for (; e + 4 <= deg; e += 4) {
    int i0 = col[st + e + 0], i1 = col[st + e + 1], i2 = col[st + e + 2], i3 = col[st + e + 3];
    float v0 = b2f(plane[(size_t)i0 * 64 + lane]);
    float v1 = b2f(plane[(size_t)i1 * 64 + lane]);
    float v2 = b2f(plane[(size_t)i2 * 64 + lane]);
    float v3 = b2f(plane[(size_t)i3 * 64 + lane]);
    s += (v0 + v1) + (v2 + v3);
  }
  for (; e < deg; ++e) s += b2f(plane[(size_t)col[st + e] * 64 + lane]);
  return s;
}

// ---------------- conv layer, A nodes: na = agg_aa@wl0 + t_a@wr0 + b0 ----------------
__global__ __launch_bounds__(256) void k_conv_a(
    const bf16* __restrict__ tc, bf16* __restrict__ tn,
    const float* __restrict__ wl_all, const float* __restrict__ wr_all, const float* __restrict__ cb_all,
    const int* __restrict__ start, const int* __restrict__ cnt, const int* __restrict__ col,
    int layer) {
  int g = blockIdx.y;
  __shared__ float wlT[64][68];     // [c][k]
  __shared__ float wrT[64][68];
  __shared__ float stg[4][8][68];   // per wave: rows 0..3 agg, 4..7 self
  size_t wb = ((size_t)g * 2 + layer) * 3;
  const float* wl = wl_all + (wb + 0) * 4096;
  const float* wr = wr_all + (wb + 0) * 4096;
  for (int idx = threadIdx.x; idx < 4096; idx += 256) {
    int k = idx >> 6, c = idx & 63;
    wlT[c][k] = wl[idx];
    wrT[c][k] = wr[idx];
  }
  __syncthreads();
  int wave = threadIdx.x >> 6, lane = threadIdx.x & 63;
  float bias = cb_all[(wb + 0) * 64 + lane];
  const bf16* plane = tc + (size_t)g * NA * 64;
  for (int grp = 0; grp < 4; ++grp) {
    int n0 = blockIdx.x * 64 + wave * 16 + grp * 4;
    #pragma unroll
    for (int i = 0; i < 4; ++i) {
      int n = n0 + i;
      float s = 0.f, tv = 0.f;
      if (n < NA) {
        int st = __builtin_amdgcn_readfirstlane(start[n]);
        int deg = __builtin_amdgcn_readfirstlane(cnt[n]);
        s = agg_row(plane, col, st, deg, lane);
        s /= (float)(deg > 1 ? deg : 1);
        tv = b2f(plane[(size_t)n * 64 + lane]);
      }
      stg[wave][i][lane] = s;
      stg[wave][4 + i][lane] = tv;
    }
    asm volatile("s_waitcnt lgkmcnt(0)" ::: "memory");
    float acc[4] = {bias, bias, bias, bias};
    #pragma unroll
    for (int ks = 0; ks < 16; ++ks) {
      float4 w1 = *(const float4*)&wlT[lane][ks * 4];
      float4 w2 = *(const float4*)&wrT[lane][ks * 4];
      #pragma unroll
      for (int i = 0; i < 4; ++i) {
        float4 a = *(const float4*)&stg[wave][i][ks * 4];
        float4 t = *(const float4*)&stg[wave][4 + i][ks * 4];
        acc[i] += a.x * w1.x + a.y * w1.y + a.z * w1.z + a.w * w1.w;
        acc[i] += t.x * w2.x + t.y * w2.y + t.z * w2.z + t.w * w2.w;
      }
    }
    asm volatile("s_waitcnt lgkmcnt(0)" ::: "memory");
    #pragma unroll
    for (int i = 0; i < 4; ++i) {
      int n = n0 + i;
      if (n < NA) tn[((size_t)g * NA + n) * 64 + lane] = __float2bfloat16(acc[i]);
    }
  }
}

// ---- conv layer, B nodes: nb = agg_ab@wl1 + agg_bb@wl2 + t_b@(wr1+wr2) + (b1+b2) ----
__global__ __launch_bounds__(256) void k_conv_b(
    const bf16* __restrict__ tA, const bf16* __restrict__ tB, bf16* __restrict__ tnB,
    const float* __restrict__ wl_all, const float* __restrict__ wr_all, const float* __restrict__ cb_all,
    const int* __restrict__ start_ab, const int* __restrict__ cnt_ab, const int* __restrict__ col_ab,
    const int* __restrict__ start_bb, const int* __restrict__ cnt_bb, const int* __restrict__ col_bb,
    int layer) {
  int g = blockIdx.y;
  __shared__ float wl1T[64][68];
  __shared__ float wl2T[64][68];
  __shared__ float wrcT[64][68];
  __shared__ float stg[4][12][68];  // rows 0..3 agg_ab, 4..7 agg_bb, 8..11 self
  size_t wb = ((size_t)g * 2 + layer) * 3;
  const float* wl1 = wl_all + (wb + 1) * 4096;
  const float* wl2 = wl_all + (wb + 2) * 4096;
  const float* wr1 = wr_all + (wb + 1) * 4096;
  const float* wr2 = wr_all + (wb + 2) * 4096;
  for (int idx = threadIdx.x; idx < 4096; idx += 256) {
    int k = idx >> 6, c = idx & 63;
    wl1T[c][k] = wl1[idx];
    wl2T[c][k] = wl2[idx];
    wrcT[c][k] = wr1[idx] + wr2[idx];
  }
  __syncthreads();
  int wave = threadIdx.x >> 6, lane = threadIdx.x & 63;
  float bias = cb_all[(wb + 1) * 64 + lane] + cb_all[(wb + 2) * 64 + lane];
  const bf16* pA = tA + (size_t)g * NA * 64;
  const bf16* pB = tB + (size_t)g * NB * 64;
  for (int grp = 0; grp < 4; ++grp) {
    int n0 = blockIdx.x * 64 + wave * 16 + grp * 4;
    #pragma unroll
    for (int i = 0; i < 4; ++i) {
      int n = n0 + i;
      float sab = 0.f, sbb = 0.f, tv = 0.f;
      if (n < NB) {
        int st = __builtin_amdgcn_readfirstlane(start_ab[n]);
        int deg = __builtin_amdgcn_readfirstlane(cnt_ab[n]);
        sab = agg_row(pA, col_ab, st, deg, lane);
        sab /= (float)(deg > 1 ? deg : 1);
        st = __builtin_amdgcn_readfirstlane(start_bb[n]);
        deg = __builtin_amdgcn_readfirstlane(cnt_bb[n]);
        sbb = agg_row(pB, col_bb, st, deg, lane);
        sbb /= (float)(deg > 1 ? deg : 1);
        tv = b2f(pB[(size_t)n * 64 + lane]);
      }
      stg[wave][i][lane] = sab;
      stg[wave][4 + i][lane] = sbb;
      stg[wave][8 + i][lane] = tv;
    }
    asm volatile("s_waitcnt lgkmcnt(0)" ::: "memory");
    float acc[4] = {bias, bias, bias, bias};
    #pragma unroll
    for (int ks = 0; ks < 16; ++ks) {
      float4 w1 = *(const float4*)&wl1T[lane][ks * 4];
      float4 w2 = *(const float4*)&wl2T[lane][ks * 4];
      float4 w3 = *(const float4*)&wrcT[lane][ks * 4];
      #pragma unroll
      for (int i = 0; i < 4; ++i) {
        float4 a = *(const float4*)&stg[wave][i][ks * 4];
        float4 b = *(const float4*)&stg[wave][4 + i][ks * 4];
        float4 t = *(const float4*)&stg[wave][8 + i][ks * 4];
        acc[i] += a.x * w1.x + a.y * w1.y + a.z * w1.z + a.w * w1.w;
        acc[i] += b.x * w2.x + b.y * w2.y + b.z * w2.z + b.w * w2.w;
        acc[i] += t.x * w3.x + t.y * w3.y + t.z * w3.z + t.w * w3.w;
      }
    }
    asm volatile("s_waitcnt lgkmcnt(0)" ::: "memory");
    #pragma unroll
    for (int i = 0; i < 4; ++i) {
      int n = n0 + i;
      if (n < NB) tnB[((size_t)g * NB + n) * 64 + lane] = __float2bfloat16(acc[i]);
    }
  }
}

// ---------------- final LSTM combine ----------------
__global__ __launch_bounds__(256) void k_final(const bf16* __restrict__ t, const float* __restrict__ lin_b,
                                               int side, const float* __restrict__ cin,
                                               float* __restrict__ h, float* __restrict__ cnout, int N) {
  size_t i = (size_t)blockIdx.x * 256 + threadIdx.x;
  size_t tot = (size_t)N * 64;
  if (i < tot) {
    int c = (int)(i & 63);
    float zi = b2f(t[i])           + lin_b[(0 * 2 + side) * 64 + c];
    float zf = b2f(t[tot + i])     + lin_b[(1 * 2 + side) * 64 + c];
    float zo = b2f(t[2 * tot + i]) + lin_b[(2 * 2 + side) * 64 + c];
    float zg = b2f(t[3 * tot + i]) + lin_b[(3 * 2 + side) * 64 + c];
    float ig = 1.f / (1.f + expf(-zi));
    float fg = 1.f / (1.f + expf(-zf));
    float og = 1.f / (1.f + expf(-zo));
    float gg = tanhf(zg);
    float cv = fg * cin[i] + ig * gg;
    h[i] = og * tanhf(cv);
    cnout[i] = cv;
  }
}

extern "C" void kernel_launch(void* const* d_in, const int* in_sizes, int n_in,
                              void* d_out, int out_size, void* d_ws, size_t ws_size,
                              hipStream_t stream) {
  (void)in_sizes; (void)n_in; (void)out_size; (void)ws_size;
  const float* x_a    = (const float*)d_in[0];
  const float* x_b    = (const float*)d_in[1];
  const float* c_a    = (const float*)d_in[2];
  const float* c_b    = (const float*)d_in[3];
  const float* lin_w  = (const float*)d_in[4];
  const float* lin_b  = (const float*)d_in[5];
  const float* conv_wl = (const float*)d_in[6];
  const float* conv_wr = (const float*)d_in[7];
  const float* conv_cb = (const float*)d_in[8];
  const int* src_aa = (const int*)d_in[9];
  const int* dst_aa = (const int*)d_in[10];
  const int* src_ab = (const int*)d_in[11];
  const int* dst_ab = (const int*)d_in[12];
  const int* src_bb = (const int*)d_in[13];
  const int* dst_bb = (const int*)d_in[14];

  char* ws = (char*)d_ws;
  size_t off = 0;
  auto alloc = [&](size_t bytes) -> char* {
    off = (off + 255) & ~(size_t)255;
    char* p = ws + off;
    off += bytes;
    return p;
  };
  bf16* tA0 = (bf16*)alloc((size_t)4 * NA * 64 * 2);
  bf16* tA1 = (bf16*)alloc((size_t)4 * NA * 64 * 2);
  bf16* tB0 = (bf16*)alloc((size_t)4 * NB * 64 * 2);
  bf16* tB1 = (bf16*)alloc((size_t)4 * NB * 64 * 2);
  int* col_aa  = (int*)alloc((size_t)EAA * 4);
  int* col_ab  = (int*)alloc((size_t)EAB * 4);
  int* col_bb  = (int*)alloc((size_t)EBB * 4);
  int* start_aa = (int*)alloc((size_t)NA * 4);
  int* start_ab = (int*)alloc((size_t)NB * 4);
  int* start_bb = (int*)alloc((size_t)NB * 4);
  size_t zbeg = (off + 255) & ~(size_t)255;
  int* cnt_aa  = (int*)alloc((size_t)NA * 4);
  int* cnt_ab  = (int*)alloc((size_t)NB * 4);
  int* cnt_bb  = (int*)alloc((size_t)NB * 4);
  int* fill_aa = (int*)alloc((size_t)NA * 4);
  int* fill_ab = (int*)alloc((size_t)NB * 4);
  int* fill_bb = (int*)alloc((size_t)NB * 4);
  int* ctr     = (int*)alloc(256);
  size_t zend = off;
  hipMemsetAsync(ws + zbeg, 0, zend - zbeg, stream);

  // CSR build (counts/cols are layer- and gate-invariant)
  k_hist<<<(EAA + 255) / 256, 256, 0, stream>>>(dst_aa, cnt_aa, EAA);
  k_hist<<<(EAB + 255) / 256, 256, 0, stream>>>(dst_ab, cnt_ab, EAB);
  k_hist<<<(EBB + 255) / 256, 256, 0, stream>>>(dst_bb, cnt_bb, EBB);
  k_alloc<<<(NA + 255) / 256, 256, 0, stream>>>(cnt_aa, start_aa, ctr + 0, NA);
  k_alloc<<<(NB + 255) / 256, 256, 0, stream>>>(cnt_ab, start_ab, ctr + 1, NB);
  k_alloc<<<(NB + 255) / 256, 256, 0, stream>>>(cnt_bb, start_bb, ctr + 2, NB);
  k_fill<<<(EAA + 255) / 256, 256, 0, stream>>>(src_aa, dst_aa, start_aa, fill_aa, col_aa, EAA);
  k_fill<<<(EAB + 255) / 256, 256, 0, stream>>>(src_ab, dst_ab, start_ab, fill_ab, col_ab, EAB);
  k_fill<<<(EBB + 255) / 256, 256, 0, stream>>>(src_bb, dst_bb, start_bb, fill_bb, col_bb, EBB);

  const int GA = (NA + 63) / 64, GB = (NB + 63) / 64;
  k_lin<<<GA, 256, 0, stream>>>(x_a, lin_w, 0, tA0, NA);
  k_lin<<<GB, 256, 0, stream>>>(x_b, lin_w, 1, tB0, NB);

  // layer 0: read *0 -> write *1
  k_conv_a<<<dim3(GA, 4), 256, 0, stream>>>(tA0, tA1, conv_wl, conv_wr, conv_cb,
                                            start_aa, cnt_aa, col_aa, 0);
  k_conv_b<<<dim3(GB, 4), 256, 0, stream>>>(tA0, tB0, tB1, conv_wl, conv_wr, conv_cb,
                                            start_ab, cnt_ab, col_ab, start_bb, cnt_bb, col_bb, 0);
  // layer 1: read *1 -> write *0
  k_conv_a<<<dim3(GA, 4), 256, 0, stream>>>(tA1, tA0, conv_wl, conv_wr, conv_cb,
                                            start_aa, cnt_aa, col_aa, 1);
  k_conv_b<<<dim3(GB, 4), 256, 0, stream>>>(tA1, tB1, tB0, conv_wl, conv_wr, conv_cb,
                                            start_ab, cnt_ab, col_ab, start_bb, cnt_bb, col_bb, 1);

  float* out = (float*)d_out;
  float* h_a  = out;
  float* h_b  = out + (size_t)NA * 64;
  float* cn_a = out + (size_t)(NA + NB) * 64;
  float* cn_b = out + (size_t)(2 * NA + NB) * 64;
  k_final<<<(NA * 64 + 255) / 256, 256, 0, stream>>>(tA0, lin_b, 0, c_a, h_a, cn_a, NA);
  k_final<<<(NB * 64 + 255) / 256, 256, 0, stream>>>(tB0, lin_b, 1, c_b, h_b, cn_b, NB);
}

// Round 2
// 1131.420 us; speedup vs baseline: 11.6639x; 11.6639x over previous
//
#include <hip/hip_runtime.h>
#include <hip/hip_bf16.h>

#define NA 100000
#define NB 50000
#define EAA 1600000
#define EAB 800000
#define EBB 800000

typedef __hip_bfloat16 bf16;
typedef __attribute__((ext_vector_type(8))) short bf16x8;
typedef __attribute__((ext_vector_type(4))) float f32x4;

__device__ __forceinline__ float b2f(bf16 v) { return __bfloat162float(v); }
__device__ __forceinline__ float u2f(unsigned short u) {
  union { unsigned int i; float f; } x; x.i = ((unsigned int)u) << 16; return x.f;
}
__device__ __forceinline__ unsigned short f2u(float f) {
  __hip_bfloat16 h = __float2bfloat16(f);
  return *reinterpret_cast<unsigned short*>(&h);
}
__device__ __forceinline__ short f2bs(float f) {
  __hip_bfloat16 h = __float2bfloat16(f);
  return *reinterpret_cast<short*>(&h);
}

// ---------------- CSR build ----------------
__global__ __launch_bounds__(256) void k_hist(const int* __restrict__ dst, int* __restrict__ cnt, int n) {
  int i = blockIdx.x * 256 + threadIdx.x;
  if (i < n) atomicAdd(&cnt[dst[i]], 1);
}

__global__ __launch_bounds__(256) void k_alloc(const int* __restrict__ cnt, int* __restrict__ start,
                                               int* __restrict__ counter, int n) {
  __shared__ int sdata[256];
  __shared__ int sbase;
  int tid = threadIdx.x;
  int i = blockIdx.x * 256 + tid;
  int v = (i < n) ? cnt[i] : 0;
  sdata[tid] = v;
  __syncthreads();
  for (int offs = 1; offs < 256; offs <<= 1) {
    int t = sdata[tid];
    if (tid >= offs) t += sdata[tid - offs];
    __syncthreads();
    sdata[tid] = t;
    __syncthreads();
  }
  if (tid == 255) sbase = atomicAdd(counter, sdata[255]);
  __syncthreads();
  if (i < n) start[i] = sbase + sdata[tid] - v;
}

__global__ __launch_bounds__(256) void k_fill(const int* __restrict__ src, const int* __restrict__ dst,
                                              const int* __restrict__ start, int* __restrict__ fill,
                                              int* __restrict__ col, int n) {
  int i = blockIdx.x * 256 + threadIdx.x;
  if (i < n) {
    int d = dst[i];
    int p = atomicAdd(&fill[d], 1);
    col[start[d] + p] = src[i];
  }
}

// ------- linear: t[n][g][c] = x[n] @ lin_w[g][side]; layout [node][4][64] bf16 -------
__global__ __launch_bounds__(256) void k_lin(const float* __restrict__ x, const float* __restrict__ lin_w,
                                             int side, bf16* __restrict__ t, int N) {
  __shared__ float wT[4][64][36];   // [gate][c][k], padded
  __shared__ float xL[4][32];
  for (int idx = threadIdx.x; idx < 4 * 32 * 64; idx += 256) {
    int g = idx >> 11; int r = idx & 2047; int k = r >> 6; int c = r & 63;
    wT[g][c][k] = lin_w[((g * 2 + side) * 32 + k) * 64 + c];
  }
  __syncthreads();
  int wave = threadIdx.x >> 6, lane = threadIdx.x & 63;
  for (int j = 0; j < 16; ++j) {
    int n = blockIdx.x * 64 + wave * 16 + j;
    bool act = n < N;
    if (act && lane < 32) xL[wave][lane] = x[(size_t)n * 32 + lane];
    asm volatile("s_waitcnt lgkmcnt(0)" ::: "memory");
    if (act) {
      #pragma unroll
      for (int g = 0; g < 4; ++g) {
        float acc = 0.f;
        #pragma unroll
        for (int ks = 0; ks < 8; ++ks) {
          float4 xv = *(const float4*)&xL[wave][ks * 4];
          float4 wv = *(const float4*)&wT[g][lane][ks * 4];
          acc += xv.x * wv.x + xv.y * wv.y + xv.z * wv.z + xv.w * wv.w;
        }
        t[(size_t)n * 256 + g * 64 + lane] = __float2bfloat16(acc);
      }
    }
    asm volatile("s_waitcnt lgkmcnt(0)" ::: "memory");
  }
}

// ------- mean aggregation: one wave per dst node; row = 512B (4 gates x 64ch bf16) -------
__global__ __launch_bounds__(256) void k_agg(const bf16* __restrict__ src, bf16* __restrict__ dst,
                                             const int* __restrict__ start, const int* __restrict__ cnt,
                                             const int* __restrict__ col, int N) {
  int n = blockIdx.x * 4 + (threadIdx.x >> 6);
  if (n >= N) return;
  int lane = threadIdx.x & 63;
  int st = start[n];
  int deg = cnt[n];
  float a0 = 0.f, a1 = 0.f, a2 = 0.f, a3 = 0.f;
  int e = 0;
  for (; e + 4 <= deg; e += 4) {
    int i0 = col[st + e + 0], i1 = col[st + e + 1], i2 = col[st + e + 2], i3 = col[st + e + 3];
    ushort4 v0 = *(const ushort4*)(src + (size_t)i0 * 256 + lane * 4);
    ushort4 v1 = *(const ushort4*)(src + (size_t)i1 * 256 + lane * 4);
    ushort4 v2 = *(const ushort4*)(src + (size_t)i2 * 256 + lane * 4);
    ushort4 v3 = *(const ushort4*)(src + (size_t)i3 * 256 + lane * 4);
    a0 += (u2f(v0.x) + u2f(v1.x)) + (u2f(v2.x) + u2f(v3.x));
    a1 += (u2f(v0.y) + u2f(v1.y)) + (u2f(v2.y) + u2f(v3.y));
    a2 += (u2f(v0.z) + u2f(v1.z)) + (u2f(v2.z) + u2f(v3.z));
    a3 += (u2f(v0.w) + u2f(v1.w)) + (u2f(v2.w) + u2f(v3.w));
  }
  for (; e < deg; ++e) {
    int i0 = col[st + e];
    ushort4 v = *(const ushort4*)(src + (size_t)i0 * 256 + lane * 4);
    a0 += u2f(v.x); a1 += u2f(v.y); a2 += u2f(v.z); a3 += u2f(v.w);
  }
  float inv = 1.f / (float)(deg > 1 ? deg : 1);
  ushort4 o;
  o.x = f2u(a0 * inv); o.y = f2u(a1 * inv); o.z = f2u(a2 * inv); o.w = f2u(a3 * inv);
  *(ushort4*)(dst + (size_t)n * 256 + lane * 4) = o;
}

// ------- A-side conv matmul: tnext[n][g] = [agg|t] @ [WL;WR] + b0; in-place (agg in tnext) -------
__global__ __launch_bounds__(256) void k_mm_a(
    const bf16* __restrict__ tcur, bf16* __restrict__ tnext,
    const float* __restrict__ wl_all, const float* __restrict__ wr_all,
    const float* __restrict__ cb_all, int layer) {
  int g = blockIdx.y;
  int wave = threadIdx.x >> 6, lane = threadIdx.x & 63;
  int l15 = lane & 15, l4 = lane >> 4;
  size_t wb = ((size_t)g * 2 + layer) * 3;
  const float* WL = wl_all + wb * 4096;
  const float* WR = wr_all + wb * 4096;
  bf16x8 Bf[4][4];
  #pragma unroll
  for (int kk = 0; kk < 4; ++kk) {
    const float* W = (kk < 2) ? WL : WR;
    int kb = (kk & 1) * 32 + l4 * 8;
    #pragma unroll
    for (int nt = 0; nt < 4; ++nt) {
      int c = nt * 16 + l15;
      bf16x8 b;
      #pragma unroll
      for (int j = 0; j < 8; ++j) b[j] = f2bs(W[(kb + j) * 64 + c]);
      Bf[kk][nt] = b;
    }
  }
  float biasv[4];
  #pragma unroll
  for (int nt = 0; nt < 4; ++nt) biasv[nt] = cb_all[wb * 64 + nt * 16 + l15];

  for (int rep = 0; rep < 4; ++rep) {
    int row0 = blockIdx.x * 256 + wave * 64 + rep * 16;
    int r = row0 + l15;
    bool ok = r < NA;
    f32x4 acc[4] = {{0,0,0,0},{0,0,0,0},{0,0,0,0},{0,0,0,0}};
    #pragma unroll
    for (int kk = 0; kk < 4; ++kk) {
      const bf16* srcp = (kk < 2) ? tnext : tcur;
      int koff = (kk & 1) * 32 + l4 * 8;
      bf16x8 a = {0,0,0,0,0,0,0,0};
      if (ok) a = *(const bf16x8*)(srcp + (size_t)r * 256 + g * 64 + koff);
      #pragma unroll
      for (int nt = 0; nt < 4; ++nt)
        acc[nt] = __builtin_amdgcn_mfma_f32_16x16x32_bf16(a, Bf[kk][nt], acc[nt], 0, 0, 0);
    }
    #pragma unroll
    for (int nt = 0; nt < 4; ++nt) {
      #pragma unroll
      for (int q = 0; q < 4; ++q) {
        int orow = row0 + l4 * 4 + q;
        if (orow < NA)
          tnext[(size_t)orow * 256 + g * 64 + nt * 16 + l15] = __float2bfloat16(acc[nt][q] + biasv[nt]);
      }
    }
  }
}

// ------- B-side conv matmul: K=256 [aggab|aggbb|t|t] @ [wl1;wl2;wr1;wr2] + (b1+b2) -------
__global__ __launch_bounds__(256) void k_mm_b(
    const bf16* __restrict__ tcur, bf16* __restrict__ tnext /* aggab + out */,
    const bf16* __restrict__ aggbb,
    const float* __restrict__ wl_all, const float* __restrict__ wr_all,
    const float* __restrict__ cb_all, int layer) {
  int g = blockIdx.y;
  int wave = threadIdx.x >> 6, lane = threadIdx.x & 63;
  int l15 = lane & 15, l4 = lane >> 4;
  size_t wb = ((size_t)g * 2 + layer) * 3;
  const float* Wm[4] = { wl_all + (wb + 1) * 4096, wl_all + (wb + 2) * 4096,
                         wr_all + (wb + 1) * 4096, wr_all + (wb + 2) * 4096 };
  bf16x8 Bf[8][4];
  #pragma unroll
  for (int kk = 0; kk < 8; ++kk) {
    const float* W = Wm[kk >> 1];
    int kb = (kk & 1) * 32 + l4 * 8;
    #pragma unroll
    for (int nt = 0; nt < 4; ++nt) {
      int c = nt * 16 + l15;
      bf16x8 b;
      #pragma unroll
      for (int j = 0; j < 8; ++j) b[j] = f2bs(W[(kb + j) * 64 + c]);
      Bf[kk][nt] = b;
    }
  }
  float biasv[4];
  #pragma unroll
  for (int nt = 0; nt < 4; ++nt)
    biasv[nt] = cb_all[(wb + 1) * 64 + nt * 16 + l15] + cb_all[(wb + 2) * 64 + nt * 16 + l15];

  for (int rep = 0; rep < 4; ++rep) {
    int row0 = blockIdx.x * 256 + wave * 64 + rep * 16;
    int r = row0 + l15;
    bool ok = r < NB;
    f32x4 acc[4] = {{0,0,0,0},{0,0,0,0},{0,0,0,0},{0,0,0,0}};
    #pragma unroll
    for (int kk = 0; kk < 8; ++kk) {
      const bf16* srcp = (kk < 2) ? tnext : (kk < 4) ? aggbb : tcur;
      int koff = (kk & 1) * 32 + l4 * 8;
      bf16x8 a = {0,0,0,0,0,0,0,0};
      if (ok) a = *(const bf16x8*)(srcp + (size_t)r * 256 + g * 64 + koff);
      #pragma unroll
      for (int nt = 0; nt < 4; ++nt)
        acc[nt] = __builtin_amdgcn_mfma_f32_16x16x32_bf16(a, Bf[kk][nt], acc[nt], 0, 0, 0);
    }
    #pragma unroll
    for (int nt = 0; nt < 4; ++nt) {
      #pragma unroll
      for (int q = 0; q < 4; ++q) {
        int orow = row0 + l4 * 4 + q;
        if (orow < NB)
          tnext[(size_t)orow * 256 + g * 64 + nt * 16 + l15] = __float2bfloat16(acc[nt][q] + biasv[nt]);
      }
    }
  }
}

// ---------------- final LSTM combine ----------------
__global__ __launch_bounds__(256) void k_final(const bf16* __restrict__ t, const float* __restrict__ lin_b,
                                               int side, const float* __restrict__ cin,
                                               float* __restrict__ h, float* __restrict__ cnout, int N) {
  size_t i = (size_t)blockIdx.x * 256 + threadIdx.x;
  size_t tot = (size_t)N * 64;
  if (i < tot) {
    size_t n = i >> 6;
    int c = (int)(i & 63);
    float zi = b2f(t[n * 256 + 0 * 64 + c]) + lin_b[(0 * 2 + side) * 64 + c];
    float zf = b2f(t[n * 256 + 1 * 64 + c]) + lin_b[(1 * 2 + side) * 64 + c];
    float zo = b2f(t[n * 256 + 2 * 64 + c]) + lin_b[(2 * 2 + side) * 64 + c];
    float zg = b2f(t[n * 256 + 3 * 64 + c]) + lin_b[(3 * 2 + side) * 64 + c];
    float ig = 1.f / (1.f + expf(-zi));
    float fg = 1.f / (1.f + expf(-zf));
    float og = 1.f / (1.f + expf(-zo));
    float gg = tanhf(zg);
    float cv = fg * cin[i] + ig * gg;
    h[i] = og * tanhf(cv);
    cnout[i] = cv;
  }
}

extern "C" void kernel_launch(void* const* d_in, const int* in_sizes, int n_in,
                              void* d_out, int out_size, void* d_ws, size_t ws_size,
                              hipStream_t stream) {
  (void)in_sizes; (void)n_in; (void)out_size; (void)ws_size;
  const float* x_a    = (const float*)d_in[0];
  const float* x_b    = (const float*)d_in[1];
  const float* c_a    = (const float*)d_in[2];
  const float* c_b    = (const float*)d_in[3];
  const float* lin_w  = (const float*)d_in[4];
  const float* lin_b  = (const float*)d_in[5];
  const float* conv_wl = (const float*)d_in[6];
  const float* conv_wr = (const float*)d_in[7];
  const float* conv_cb = (const float*)d_in[8];
  const int* src_aa = (const int*)d_in[9];
  const int* dst_aa = (const int*)d_in[10];
  const int* src_ab = (const int*)d_in[11];
  const int* dst_ab = (const int*)d_in[12];
  const int* src_bb = (const int*)d_in[13];
  const int* dst_bb = (const int*)d_in[14];

  char* ws = (char*)d_ws;
  size_t off = 0;
  auto alloc = [&](size_t bytes) -> char* {
    off = (off + 255) & ~(size_t)255;
    char* p = ws + off;
    off += bytes;
    return p;
  };
  bf16* tA0 = (bf16*)alloc((size_t)NA * 256 * 2);   // [node][4][64]
  bf16* tA1 = (bf16*)alloc((size_t)NA * 256 * 2);
  bf16* tB0 = (bf16*)alloc((size_t)NB * 256 * 2);
  bf16* tB1 = (bf16*)alloc((size_t)NB * 256 * 2);
  int* col_aa  = (int*)alloc((size_t)EAA * 4);
  int* col_ab  = (int*)alloc((size_t)EAB * 4);
  int* col_bb  = (int*)alloc((size_t)EBB * 4);
  int* start_aa = (int*)alloc((size_t)NA * 4);
  int* start_ab = (int*)alloc((size_t)NB * 4);
  int* start_bb = (int*)alloc((size_t)NB * 4);
  size_t zbeg = (off + 255) & ~(size_t)255;
  int* cnt_aa  = (int*)alloc((size_t)NA * 4);
  int* cnt_ab  = (int*)alloc((size_t)NB * 4);
  int* cnt_bb  = (int*)alloc((size_t)NB * 4);
  int* fill_aa = (int*)alloc((size_t)NA * 4);
  int* fill_ab = (int*)alloc((size_t)NB * 4);
  int* fill_bb = (int*)alloc((size_t)NB * 4);
  int* ctr     = (int*)alloc(256);
  size_t zend = off;
  hipMemsetAsync(ws + zbeg, 0, zend - zbeg, stream);

  // CSR build
  k_hist<<<(EAA + 255) / 256, 256, 0, stream>>>(dst_aa, cnt_aa, EAA);
  k_hist<<<(EAB + 255) / 256, 256, 0, stream>>>(dst_ab, cnt_ab, EAB);
  k_hist<<<(EBB + 255) / 256, 256, 0, stream>>>(dst_bb, cnt_bb, EBB);
  k_alloc<<<(NA + 255) / 256, 256, 0, stream>>>(cnt_aa, start_aa, ctr + 0, NA);
  k_alloc<<<(NB + 255) / 256, 256, 0, stream>>>(cnt_ab, start_ab, ctr + 1, NB);
  k_alloc<<<(NB + 255) / 256, 256, 0, stream>>>(cnt_bb, start_bb, ctr + 2, NB);
  k_fill<<<(EAA + 255) / 256, 256, 0, stream>>>(src_aa, dst_aa, start_aa, fill_aa, col_aa, EAA);
  k_fill<<<(EAB + 255) / 256, 256, 0, stream>>>(src_ab, dst_ab, start_ab, fill_ab, col_ab, EAB);
  k_fill<<<(EBB + 255) / 256, 256, 0, stream>>>(src_bb, dst_bb, start_bb, fill_bb, col_bb, EBB);

  const int GA = (NA + 63) / 64, GB = (NB + 63) / 64;
  k_lin<<<GA, 256, 0, stream>>>(x_a, lin_w, 0, tA0, NA);
  k_lin<<<GB, 256, 0, stream>>>(x_b, lin_w, 1, tB0, NB);

  const int AGA = (NA + 3) / 4, AGB = (NB + 3) / 4;
  const int MMA = (NA + 255) / 256, MMB = (NB + 255) / 256;

  // ---- layer 0: cur = *0, next = *1; aggbb scratch reuses tA0's space after mm_a ----
  k_agg<<<AGA, 256, 0, stream>>>(tA0, tA1, start_aa, cnt_aa, col_aa, NA);
  k_agg<<<AGB, 256, 0, stream>>>(tA0, tB1, start_ab, cnt_ab, col_ab, NB);
  k_mm_a<<<dim3(MMA, 4), 256, 0, stream>>>(tA0, tA1, conv_wl, conv_wr, conv_cb, 0);
  k_agg<<<AGB, 256, 0, stream>>>(tB0, tA0 /*scratch*/, start_bb, cnt_bb, col_bb, NB);
  k_mm_b<<<dim3(MMB, 4), 256, 0, stream>>>(tB0, tB1, tA0 /*aggbb*/, conv_wl, conv_wr, conv_cb, 0);

  // ---- layer 1: cur = *1, next = *0; aggbb scratch reuses tA1's space after mm_a ----
  k_agg<<<AGA, 256, 0, stream>>>(tA1, tA0, start_aa, cnt_aa, col_aa, NA);
  k_agg<<<AGB, 256, 0, stream>>>(tA1, tB0, start_ab, cnt_ab, col_ab, NB);
  k_mm_a<<<dim3(MMA, 4), 256, 0, stream>>>(tA1, tA0, conv_wl, conv_wr, conv_cb, 1);
  k_agg<<<AGB, 256, 0, stream>>>(tB1, tA1 /*scratch*/, start_bb, cnt_bb, col_bb, NB);
  k_mm_b<<<dim3(MMB, 4), 256, 0, stream>>>(tB1, tB0, tA1 /*aggbb*/, conv_wl, conv_wr, conv_cb, 1);

  float* out = (float*)d_out;
  float* h_a  = out;
  float* h_b  = out + (size_t)NA * 64;
  float* cn_a = out + (size_t)(NA + NB) * 64;
  float* cn_b = out + (size_t)(2 * NA + NB) * 64;
  k_final<<<(NA * 64 + 255) / 256, 256, 0, stream>>>(tA0, lin_b, 0, c_a, h_a, cn_a, NA);
  k_final<<<(NB * 64 + 255) / 256, 256, 0, stream>>>(tB0, lin_b, 1, c_b, h_b, cn_b, NB);
}

// Round 3
// 855.652 us; speedup vs baseline: 15.4231x; 1.3223x over previous
//
#include <hip/hip_runtime.h>
#include <hip/hip_bf16.h>

#define NA 100000
#define NB 50000
#define EAA 1600000
#define EAB 800000
#define EBB 800000

typedef __hip_bfloat16 bf16;
typedef __attribute__((ext_vector_type(8))) short bf16x8;
typedef __attribute__((ext_vector_type(4))) float f32x4;

__device__ __forceinline__ float b2f(bf16 v) { return __bfloat162float(v); }
__device__ __forceinline__ float u2f(unsigned short u) {
  union { unsigned int i; float f; } x; x.i = ((unsigned int)u) << 16; return x.f;
}
__device__ __forceinline__ unsigned short f2u(float f) {
  __hip_bfloat16 h = __float2bfloat16(f);
  return *reinterpret_cast<unsigned short*>(&h);
}
__device__ __forceinline__ short f2bs(float f) {
  __hip_bfloat16 h = __float2bfloat16(f);
  return *reinterpret_cast<short*>(&h);
}

// ---------------- CSR build (3 edge sets fused per kernel) ----------------
__global__ __launch_bounds__(256) void k_hist3(const int* __restrict__ da, const int* __restrict__ db,
                                               const int* __restrict__ dc,
                                               int* __restrict__ ca, int* __restrict__ cb,
                                               int* __restrict__ cc) {
  int b = blockIdx.x;
  const int* dst; int* cnt; int i;
  if (b < 6250)      { dst = da; cnt = ca; i = b * 256 + threadIdx.x;          if (i >= EAA) return; }
  else if (b < 9375) { dst = db; cnt = cb; i = (b - 6250) * 256 + threadIdx.x; if (i >= EAB) return; }
  else               { dst = dc; cnt = cc; i = (b - 9375) * 256 + threadIdx.x; if (i >= EBB) return; }
  atomicAdd(&cnt[dst[i]], 1);
}

__global__ __launch_bounds__(256) void k_alloc3(
    const int* __restrict__ ca, const int* __restrict__ cb, const int* __restrict__ cc,
    int* __restrict__ sa, int* __restrict__ sb, int* __restrict__ sc, int* __restrict__ ctr) {
  __shared__ int sdata[256];
  __shared__ int sbase;
  int b = blockIdx.x;
  const int* cnt; int* start; int* counter; int n; int lb;
  if (b < 391)      { cnt = ca; start = sa; counter = ctr + 0; n = NA; lb = b; }
  else if (b < 587) { cnt = cb; start = sb; counter = ctr + 1; n = NB; lb = b - 391; }
  else              { cnt = cc; start = sc; counter = ctr + 2; n = NB; lb = b - 587; }
  int tid = threadIdx.x;
  int i = lb * 256 + tid;
  int v = (i < n) ? cnt[i] : 0;
  sdata[tid] = v;
  __syncthreads();
  for (int offs = 1; offs < 256; offs <<= 1) {
    int t = sdata[tid];
    if (tid >= offs) t += sdata[tid - offs];
    __syncthreads();
    sdata[tid] = t;
    __syncthreads();
  }
  if (tid == 255) sbase = atomicAdd(counter, sdata[255]);
  __syncthreads();
  if (i < n) start[i] = sbase + sdata[tid] - v;
}

__global__ __launch_bounds__(256) void k_fill3(
    const int* __restrict__ s1, const int* __restrict__ d1,
    const int* __restrict__ s2, const int* __restrict__ d2,
    const int* __restrict__ s3, const int* __restrict__ d3,
    const int* __restrict__ t1, const int* __restrict__ t2, const int* __restrict__ t3,
    int* __restrict__ f1, int* __restrict__ f2, int* __restrict__ f3,
    int* __restrict__ c1, int* __restrict__ c2, int* __restrict__ c3) {
  int b = blockIdx.x;
  const int* src; const int* dst; const int* start; int* fill; int* col; int i;
  if (b < 6250)      { src = s1; dst = d1; start = t1; fill = f1; col = c1; i = b * 256 + threadIdx.x;          if (i >= EAA) return; }
  else if (b < 9375) { src = s2; dst = d2; start = t2; fill = f2; col = c2; i = (b - 6250) * 256 + threadIdx.x; if (i >= EAB) return; }
  else               { src = s3; dst = d3; start = t3; fill = f3; col = c3; i = (b - 9375) * 256 + threadIdx.x; if (i >= EBB) return; }
  int d = dst[i];
  int p = atomicAdd(&fill[d], 1);
  col[start[d] + p] = src[i];
}

// ---------------- cast x (f32) -> bf16, both node types ----------------
__global__ __launch_bounds__(256) void k_cast2(const float* __restrict__ xa, const float* __restrict__ xb,
                                               bf16* __restrict__ ya, bf16* __restrict__ yb) {
  int i = blockIdx.x * 256 + threadIdx.x;
  const float* x; bf16* y; int base;
  if (i < 800000)       { x = xa; y = ya; base = i * 4; }
  else if (i < 1200000) { x = xb; y = yb; base = (i - 800000) * 4; }
  else return;
  float4 v = *(const float4*)(x + base);
  ushort4 o; o.x = f2u(v.x); o.y = f2u(v.y); o.z = f2u(v.z); o.w = f2u(v.w);
  *(ushort4*)(y + base) = o;
}

// ---- fold lin_w into layer-0 conv weights: 5 terms x 4 gates of [32x64] = LW @ R ----
// term0: LW0@wl[e0]  term1: LW0@wr[e0]  term2: LW0@wl[e1]  term3: LW1@wl[e2]  term4: LW1@(wr[e1]+wr[e2])
__global__ __launch_bounds__(256) void k_wprep(const float* __restrict__ lin_w,
                                               const float* __restrict__ wl_all,
                                               const float* __restrict__ wr_all,
                                               float* __restrict__ Wc) {
  int id = blockIdx.x;            // term*4 + g
  int term = id >> 2, g = id & 3;
  const float* LW = lin_w + ((size_t)g * 2 + (term >= 3 ? 1 : 0)) * 2048;
  size_t wb = (size_t)g * 6;      // (g*2+0)*3
  const float* R1; const float* R2 = nullptr;
  switch (term) {
    case 0: R1 = wl_all + (wb + 0) * 4096; break;
    case 1: R1 = wr_all + (wb + 0) * 4096; break;
    case 2: R1 = wl_all + (wb + 1) * 4096; break;
    case 3: R1 = wl_all + (wb + 2) * 4096; break;
    default: R1 = wr_all + (wb + 1) * 4096; R2 = wr_all + (wb + 2) * 4096; break;
  }
  int r = threadIdx.x >> 3;
  int c0 = (threadIdx.x & 7) * 8;
  float acc[8] = {0, 0, 0, 0, 0, 0, 0, 0};
  for (int k = 0; k < 64; ++k) {
    float lw = LW[r * 64 + k];
    #pragma unroll
    for (int j = 0; j < 8; ++j) {
      float w = R1[k * 64 + c0 + j];
      if (R2) w += R2[k * 64 + c0 + j];
      acc[j] += lw * w;
    }
  }
  #pragma unroll
  for (int j = 0; j < 8; ++j) Wc[(size_t)id * 2048 + r * 64 + c0 + j] = acc[j];
}

// ---- 32-ch mean agg of x (64B rows), 3 segments fused; 4 edges x 16 lanes per wave ----
__global__ __launch_bounds__(256) void k_agg32(
    const bf16* __restrict__ xa, const bf16* __restrict__ xb,
    bf16* __restrict__ axaa, bf16* __restrict__ axab, bf16* __restrict__ axbb,
    const int* __restrict__ st_aa, const int* __restrict__ ct_aa, const int* __restrict__ col_aa,
    const int* __restrict__ st_ab, const int* __restrict__ ct_ab, const int* __restrict__ col_ab,
    const int* __restrict__ st_bb, const int* __restrict__ ct_bb, const int* __restrict__ col_bb) {
  int b = blockIdx.x;
  const bf16* src; bf16* dst; const int* start; const int* cnt; const int* col; int n0;
  if (b < 25000)      { src = xa; dst = axaa; start = st_aa; cnt = ct_aa; col = col_aa; n0 = b * 4; }
  else if (b < 37500) { src = xa; dst = axab; start = st_ab; cnt = ct_ab; col = col_ab; n0 = (b - 25000) * 4; }
  else                { src = xb; dst = axbb; start = st_bb; cnt = ct_bb; col = col_bb; n0 = (b - 37500) * 4; }
  int wave = threadIdx.x >> 6, lane = threadIdx.x & 63;
  int n = n0 + wave;
  int e4 = lane >> 4, c16 = lane & 15;
  int st = start[n];
  int deg = cnt[n];
  float s0 = 0.f, s1 = 0.f;
  #pragma unroll 4
  for (int e = e4; e < deg; e += 4) {
    int i = col[st + e];
    ushort2 v = *(const ushort2*)(src + (size_t)i * 32 + c16 * 2);
    s0 += u2f(v.x);
    s1 += u2f(v.y);
  }
  s0 += __shfl_xor(s0, 16); s1 += __shfl_xor(s1, 16);
  s0 += __shfl_xor(s0, 32); s1 += __shfl_xor(s1, 32);
  if (e4 == 0) {
    float inv = 1.f / (float)(deg > 1 ? deg : 1);
    ushort2 o; o.x = f2u(s0 * inv); o.y = f2u(s1 * inv);
    *(ushort2*)(dst + (size_t)n * 32 + c16 * 2) = o;
  }
}

// ---- 512B-row mean agg (layer 1), one wave per node, 8-deep MLP ----
__global__ __launch_bounds__(256) void k_agg512(const bf16* __restrict__ src, bf16* __restrict__ dst,
                                                const int* __restrict__ start, const int* __restrict__ cnt,
                                                const int* __restrict__ col, int N) {
  int n = blockIdx.x * 4 + (threadIdx.x >> 6);
  if (n >= N) return;
  int lane = threadIdx.x & 63;
  int st = start[n];
  int deg = cnt[n];
  float a0 = 0.f, a1 = 0.f, a2 = 0.f, a3 = 0.f;
  int e = 0;
  for (; e + 8 <= deg; e += 8) {
    int idx[8];
    #pragma unroll
    for (int j = 0; j < 8; ++j) idx[j] = col[st + e + j];
    #pragma unroll
    for (int j = 0; j < 8; ++j) {
      ushort4 v = *(const ushort4*)(src + (size_t)idx[j] * 256 + lane * 4);
      a0 += u2f(v.x); a1 += u2f(v.y); a2 += u2f(v.z); a3 += u2f(v.w);
    }
  }
  for (; e + 4 <= deg; e += 4) {
    int i0 = col[st + e + 0], i1 = col[st + e + 1], i2 = col[st + e + 2], i3 = col[st + e + 3];
    ushort4 v0 = *(const ushort4*)(src + (size_t)i0 * 256 + lane * 4);
    ushort4 v1 = *(const ushort4*)(src + (size_t)i1 * 256 + lane * 4);
    ushort4 v2 = *(const ushort4*)(src + (size_t)i2 * 256 + lane * 4);
    ushort4 v3 = *(const ushort4*)(src + (size_t)i3 * 256 + lane * 4);
    a0 += (u2f(v0.x) + u2f(v1.x)) + (u2f(v2.x) + u2f(v3.x));
    a1 += (u2f(v0.y) + u2f(v1.y)) + (u2f(v2.y) + u2f(v3.y));
    a2 += (u2f(v0.z) + u2f(v1.z)) + (u2f(v2.z) + u2f(v3.z));
    a3 += (u2f(v0.w) + u2f(v1.w)) + (u2f(v2.w) + u2f(v3.w));
  }
  for (; e < deg; ++e) {
    int i0 = col[st + e];
    ushort4 v = *(const ushort4*)(src + (size_t)i0 * 256 + lane * 4);
    a0 += u2f(v.x); a1 += u2f(v.y); a2 += u2f(v.z); a3 += u2f(v.w);
  }
  float inv = 1.f / (float)(deg > 1 ? deg : 1);
  ushort4 o;
  o.x = f2u(a0 * inv); o.y = f2u(a1 * inv); o.z = f2u(a2 * inv); o.w = f2u(a3 * inv);
  *(ushort4*)(dst + (size_t)n * 256 + lane * 4) = o;
}

// ---- layer-0 A matmul: t1[n][g] = axaa@W1_g + xa@W2_g + b(g,0,0); K=32 per term ----
__global__ __launch_bounds__(256) void k_mm0_a(
    const bf16* __restrict__ xa, const bf16* __restrict__ axaa, bf16* __restrict__ tout,
    const float* __restrict__ Wc, const float* __restrict__ cb_all) {
  int g = blockIdx.y;
  int wave = threadIdx.x >> 6, lane = threadIdx.x & 63;
  int l15 = lane & 15, l4 = lane >> 4;
  const float* Wm[2] = { Wc + (size_t)(0 * 4 + g) * 2048, Wc + (size_t)(1 * 4 + g) * 2048 };
  bf16x8 Bf[2][4];
  #pragma unroll
  for (int kk = 0; kk < 2; ++kk) {
    #pragma unroll
    for (int nt = 0; nt < 4; ++nt) {
      bf16x8 bv;
      #pragma unroll
      for (int j = 0; j < 8; ++j) bv[j] = f2bs(Wm[kk][(l4 * 8 + j) * 64 + nt * 16 + l15]);
      Bf[kk][nt] = bv;
    }
  }
  size_t wb = (size_t)g * 6;
  float biasv[4];
  #pragma unroll
  for (int nt = 0; nt < 4; ++nt) biasv[nt] = cb_all[wb * 64 + nt * 16 + l15];

  for (int rep = 0; rep < 4; ++rep) {
    int row0 = blockIdx.x * 256 + wave * 64 + rep * 16;
    int r = row0 + l15;
    bool ok = r < NA;
    f32x4 acc[4] = {{0,0,0,0},{0,0,0,0},{0,0,0,0},{0,0,0,0}};
    bf16x8 aA = {0,0,0,0,0,0,0,0}, aX = {0,0,0,0,0,0,0,0};
    if (ok) {
      aA = *(const bf16x8*)(axaa + (size_t)r * 32 + l4 * 8);
      aX = *(const bf16x8*)(xa + (size_t)r * 32 + l4 * 8);
    }
    #pragma unroll
    for (int nt = 0; nt < 4; ++nt) {
      acc[nt] = __builtin_amdgcn_mfma_f32_16x16x32_bf16(aA, Bf[0][nt], acc[nt], 0, 0, 0);
      acc[nt] = __builtin_amdgcn_mfma_f32_16x16x32_bf16(aX, Bf[1][nt], acc[nt], 0, 0, 0);
    }
    #pragma unroll
    for (int nt = 0; nt < 4; ++nt) {
      #pragma unroll
      for (int q = 0; q < 4; ++q) {
        int orow = row0 + l4 * 4 + q;
        if (orow < NA)
          tout[(size_t)orow * 256 + g * 64 + nt * 16 + l15] = __float2bfloat16(acc[nt][q] + biasv[nt]);
      }
    }
  }
}

// ---- layer-0 B matmul: t1[n][g] = axab@W3 + axbb@W4 + xb@W5 + (b(g,0,1)+b(g,0,2)) ----
__global__ __launch_bounds__(256) void k_mm0_b(
    const bf16* __restrict__ xb, const bf16* __restrict__ axab, const bf16* __restrict__ axbb,
    bf16* __restrict__ tout, const float* __restrict__ Wc, const float* __restrict__ cb_all) {
  int g = blockIdx.y;
  int wave = threadIdx.x >> 6, lane = threadIdx.x & 63;
  int l15 = lane & 15, l4 = lane >> 4;
  const float* Wm[3] = { Wc + (size_t)(2 * 4 + g) * 2048, Wc + (size_t)(3 * 4 + g) * 2048,
                         Wc + (size_t)(4 * 4 + g) * 2048 };
  bf16x8 Bf[3][4];
  #pragma unroll
  for (int kk = 0; kk < 3; ++kk) {
    #pragma unroll
    for (int nt = 0; nt < 4; ++nt) {
      bf16x8 bv;
      #pragma unroll
      for (int j = 0; j < 8; ++j) bv[j] = f2bs(Wm[kk][(l4 * 8 + j) * 64 + nt * 16 + l15]);
      Bf[kk][nt] = bv;
    }
  }
  size_t wb = (size_t)g * 6;
  float biasv[4];
  #pragma unroll
  for (int nt = 0; nt < 4; ++nt)
    biasv[nt] = cb_all[(wb + 1) * 64 + nt * 16 + l15] + cb_all[(wb + 2) * 64 + nt * 16 + l15];

  for (int rep = 0; rep < 4; ++rep) {
    int row0 = blockIdx.x * 256 + wave * 64 + rep * 16;
    int r = row0 + l15;
    bool ok = r < NB;
    f32x4 acc[4] = {{0,0,0,0},{0,0,0,0},{0,0,0,0},{0,0,0,0}};
    bf16x8 a0 = {0,0,0,0,0,0,0,0}, a1 = {0,0,0,0,0,0,0,0}, a2 = {0,0,0,0,0,0,0,0};
    if (ok) {
      a0 = *(const bf16x8*)(axab + (size_t)r * 32 + l4 * 8);
      a1 = *(const bf16x8*)(axbb + (size_t)r * 32 + l4 * 8);
      a2 = *(const bf16x8*)(xb + (size_t)r * 32 + l4 * 8);
    }
    #pragma unroll
    for (int nt = 0; nt < 4; ++nt) {
      acc[nt] = __builtin_amdgcn_mfma_f32_16x16x32_bf16(a0, Bf[0][nt], acc[nt], 0, 0, 0);
      acc[nt] = __builtin_amdgcn_mfma_f32_16x16x32_bf16(a1, Bf[1][nt], acc[nt], 0, 0, 0);
      acc[nt] = __builtin_amdgcn_mfma_f32_16x16x32_bf16(a2, Bf[2][nt], acc[nt], 0, 0, 0);
    }
    #pragma unroll
    for (int nt = 0; nt < 4; ++nt) {
      #pragma unroll
      for (int q = 0; q < 4; ++q) {
        int orow = row0 + l4 * 4 + q;
        if (orow < NB)
          tout[(size_t)orow * 256 + g * 64 + nt * 16 + l15] = __float2bfloat16(acc[nt][q] + biasv[nt]);
      }
    }
  }
}

// ------- layer-1 A matmul: tnext = [agg|t] @ [WL;WR] + b; agg pre-staged in tnext -------
__global__ __launch_bounds__(256) void k_mm_a(
    const bf16* __restrict__ tcur, bf16* __restrict__ tnext,
    const float* __restrict__ wl_all, const float* __restrict__ wr_all,
    const float* __restrict__ cb_all, int layer) {
  int g = blockIdx.y;
  int wave = threadIdx.x >> 6, lane = threadIdx.x & 63;
  int l15 = lane & 15, l4 = lane >> 4;
  size_t wb = ((size_t)g * 2 + layer) * 3;
  const float* WL = wl_all + wb * 4096;
  const float* WR = wr_all + wb * 4096;
  bf16x8 Bf[4][4];
  #pragma unroll
  for (int kk = 0; kk < 4; ++kk) {
    const float* W = (kk < 2) ? WL : WR;
    int kb = (kk & 1) * 32 + l4 * 8;
    #pragma unroll
    for (int nt = 0; nt < 4; ++nt) {
      int c = nt * 16 + l15;
      bf16x8 bv;
      #pragma unroll
      for (int j = 0; j < 8; ++j) bv[j] = f2bs(W[(kb + j) * 64 + c]);
      Bf[kk][nt] = bv;
    }
  }
  float biasv[4];
  #pragma unroll
  for (int nt = 0; nt < 4; ++nt) biasv[nt] = cb_all[wb * 64 + nt * 16 + l15];

  for (int rep = 0; rep < 4; ++rep) {
    int row0 = blockIdx.x * 256 + wave * 64 + rep * 16;
    int r = row0 + l15;
    bool ok = r < NA;
    f32x4 acc[4] = {{0,0,0,0},{0,0,0,0},{0,0,0,0},{0,0,0,0}};
    #pragma unroll
    for (int kk = 0; kk < 4; ++kk) {
      const bf16* srcp = (kk < 2) ? tnext : tcur;
      int koff = (kk & 1) * 32 + l4 * 8;
      bf16x8 a = {0,0,0,0,0,0,0,0};
      if (ok) a = *(const bf16x8*)(srcp + (size_t)r * 256 + g * 64 + koff);
      #pragma unroll
      for (int nt = 0; nt < 4; ++nt)
        acc[nt] = __builtin_amdgcn_mfma_f32_16x16x32_bf16(a, Bf[kk][nt], acc[nt], 0, 0, 0);
    }
    #pragma unroll
    for (int nt = 0; nt < 4; ++nt) {
      #pragma unroll
      for (int q = 0; q < 4; ++q) {
        int orow = row0 + l4 * 4 + q;
        if (orow < NA)
          tnext[(size_t)orow * 256 + g * 64 + nt * 16 + l15] = __float2bfloat16(acc[nt][q] + biasv[nt]);
      }
    }
  }
}

// ------- layer-1 B matmul: K=256 [aggab|aggbb|t|t] @ [wl1;wl2;wr1;wr2] + (b1+b2) -------
__global__ __launch_bounds__(256) void k_mm_b(
    const bf16* __restrict__ tcur, bf16* __restrict__ tnext,
    const bf16* __restrict__ aggbb,
    const float* __restrict__ wl_all, const float* __restrict__ wr_all,
    const float* __restrict__ cb_all, int layer) {
  int g = blockIdx.y;
  int wave = threadIdx.x >> 6, lane = threadIdx.x & 63;
  int l15 = lane & 15, l4 = lane >> 4;
  size_t wb = ((size_t)g * 2 + layer) * 3;
  const float* Wm[4] = { wl_all + (wb + 1) * 4096, wl_all + (wb + 2) * 4096,
                         wr_all + (wb + 1) * 4096, wr_all + (wb + 2) * 4096 };
  bf16x8 Bf[8][4];
  #pragma unroll
  for (int kk = 0; kk < 8; ++kk) {
    const float* W = Wm[kk >> 1];
    int kb = (kk & 1) * 32 + l4 * 8;
    #pragma unroll
    for (int nt = 0; nt < 4; ++nt) {
      int c = nt * 16 + l15;
      bf16x8 bv;
      #pragma unroll
      for (int j = 0; j < 8; ++j) bv[j] = f2bs(W[(kb + j) * 64 + c]);
      Bf[kk][nt] = bv;
    }
  }
  float biasv[4];
  #pragma unroll
  for (int nt = 0; nt < 4; ++nt)
    biasv[nt] = cb_all[(wb + 1) * 64 + nt * 16 + l15] + cb_all[(wb + 2) * 64 + nt * 16 + l15];

  for (int rep = 0; rep < 4; ++rep) {
    int row0 = blockIdx.x * 256 + wave * 64 + rep * 16;
    int r = row0 + l15;
    bool ok = r < NB;
    f32x4 acc[4] = {{0,0,0,0},{0,0,0,0},{0,0,0,0},{0,0,0,0}};
    #pragma unroll
    for (int kk = 0; kk < 8; ++kk) {
      const bf16* srcp = (kk < 2) ? tnext : (kk < 4) ? aggbb : tcur;
      int koff = (kk & 1) * 32 + l4 * 8;
      bf16x8 a = {0,0,0,0,0,0,0,0};
      if (ok) a = *(const bf16x8*)(srcp + (size_t)r * 256 + g * 64 + koff);
      #pragma unroll
      for (int nt = 0; nt < 4; ++nt)
        acc[nt] = __builtin_amdgcn_mfma_f32_16x16x32_bf16(a, Bf[kk][nt], acc[nt], 0, 0, 0);
    }
    #pragma unroll
    for (int nt = 0; nt < 4; ++nt) {
      #pragma unroll
      for (int q = 0; q < 4; ++q) {
        int orow = row0 + l4 * 4 + q;
        if (orow < NB)
          tnext[(size_t)orow * 256 + g * 64 + nt * 16 + l15] = __float2bfloat16(acc[nt][q] + biasv[nt]);
      }
    }
  }
}

// ---------------- final LSTM combine, A+B fused ----------------
__global__ __launch_bounds__(256) void k_final2(const bf16* __restrict__ tA, const bf16* __restrict__ tB,
                                                const float* __restrict__ lin_b,
                                                const float* __restrict__ ca, const float* __restrict__ cbv,
                                                float* __restrict__ out) {
  const size_t TOTA = (size_t)NA * 64, TOTB = (size_t)NB * 64;
  size_t i = (size_t)blockIdx.x * 256 + threadIdx.x;
  const bf16* t; const float* cin; float* h; float* cn; size_t idx; int side;
  if (i < TOTA)             { t = tA; cin = ca;  h = out;        cn = out + TOTA + TOTB;     idx = i;        side = 0; }
  else if (i < TOTA + TOTB) { t = tB; cin = cbv; h = out + TOTA; cn = out + 2 * TOTA + TOTB; idx = i - TOTA; side = 1; }
  else return;
  size_t n = idx >> 6;
  int c = (int)(idx & 63);
  float zi = b2f(t[n * 256 + 0 * 64 + c]) + lin_b[(0 * 2 + side) * 64 + c];
  float zf = b2f(t[n * 256 + 1 * 64 + c]) + lin_b[(1 * 2 + side) * 64 + c];
  float zo = b2f(t[n * 256 + 2 * 64 + c]) + lin_b[(2 * 2 + side) * 64 + c];
  float zg = b2f(t[n * 256 + 3 * 64 + c]) + lin_b[(3 * 2 + side) * 64 + c];
  float ig = 1.f / (1.f + expf(-zi));
  float fg = 1.f / (1.f + expf(-zf));
  float og = 1.f / (1.f + expf(-zo));
  float gg = tanhf(zg);
  float cv = fg * cin[idx] + ig * gg;
  h[idx] = og * tanhf(cv);
  cn[idx] = cv;
}

extern "C" void kernel_launch(void* const* d_in, const int* in_sizes, int n_in,
                              void* d_out, int out_size, void* d_ws, size_t ws_size,
                              hipStream_t stream) {
  (void)in_sizes; (void)n_in; (void)out_size; (void)ws_size;
  const float* x_a    = (const float*)d_in[0];
  const float* x_b    = (const float*)d_in[1];
  const float* c_a    = (const float*)d_in[2];
  const float* c_b    = (const float*)d_in[3];
  const float* lin_w  = (const float*)d_in[4];
  const float* lin_b  = (const float*)d_in[5];
  const float* conv_wl = (const float*)d_in[6];
  const float* conv_wr = (const float*)d_in[7];
  const float* conv_cb = (const float*)d_in[8];
  const int* src_aa = (const int*)d_in[9];
  const int* dst_aa = (const int*)d_in[10];
  const int* src_ab = (const int*)d_in[11];
  const int* dst_ab = (const int*)d_in[12];
  const int* src_bb = (const int*)d_in[13];
  const int* dst_bb = (const int*)d_in[14];

  char* ws = (char*)d_ws;
  size_t off = 0;
  auto alloc = [&](size_t bytes) -> char* {
    off = (off + 255) & ~(size_t)255;
    char* p = ws + off;
    off += bytes;
    return p;
  };
  bf16* tA0 = (bf16*)alloc((size_t)NA * 256 * 2);   // layer-1 aggA staging + final A
  bf16* tA1 = (bf16*)alloc((size_t)NA * 256 * 2);   // layer-0 A out; later aggBB scratch
  bf16* tB0 = (bf16*)alloc((size_t)NB * 256 * 2);   // layer-1 aggAB staging + final B
  bf16* tB1 = (bf16*)alloc((size_t)NB * 256 * 2);   // layer-0 B out
  bf16* xab = (bf16*)alloc((size_t)NA * 32 * 2);
  bf16* xbb = (bf16*)alloc((size_t)NB * 32 * 2);
  bf16* axaa = (bf16*)alloc((size_t)NA * 32 * 2);
  bf16* axab = (bf16*)alloc((size_t)NB * 32 * 2);
  bf16* axbb = (bf16*)alloc((size_t)NB * 32 * 2);
  float* Wc  = (float*)alloc((size_t)20 * 2048 * 4);
  int* col_aa  = (int*)alloc((size_t)EAA * 4);
  int* col_ab  = (int*)alloc((size_t)EAB * 4);
  int* col_bb  = (int*)alloc((size_t)EBB * 4);
  int* start_aa = (int*)alloc((size_t)NA * 4);
  int* start_ab = (int*)alloc((size_t)NB * 4);
  int* start_bb = (int*)alloc((size_t)NB * 4);
  size_t zbeg = (off + 255) & ~(size_t)255;
  int* cnt_aa  = (int*)alloc((size_t)NA * 4);
  int* cnt_ab  = (int*)alloc((size_t)NB * 4);
  int* cnt_bb  = (int*)alloc((size_t)NB * 4);
  int* fill_aa = (int*)alloc((size_t)NA * 4);
  int* fill_ab = (int*)alloc((size_t)NB * 4);
  int* fill_bb = (int*)alloc((size_t)NB * 4);
  int* ctr     = (int*)alloc(256);
  size_t zend = off;
  hipMemsetAsync(ws + zbeg, 0, zend - zbeg, stream);

  // weight folding + x cast (independent of CSR)
  k_wprep<<<20, 256, 0, stream>>>(lin_w, conv_wl, conv_wr, Wc);
  k_cast2<<<4688, 256, 0, stream>>>(x_a, x_b, xab, xbb);

  // CSR build (fused across the 3 edge sets)
  k_hist3<<<12500, 256, 0, stream>>>(dst_aa, dst_ab, dst_bb, cnt_aa, cnt_ab, cnt_bb);
  k_alloc3<<<783, 256, 0, stream>>>(cnt_aa, cnt_ab, cnt_bb, start_aa, start_ab, start_bb, ctr);
  k_fill3<<<12500, 256, 0, stream>>>(src_aa, dst_aa, src_ab, dst_ab, src_bb, dst_bb,
                                     start_aa, start_ab, start_bb,
                                     fill_aa, fill_ab, fill_bb,
                                     col_aa, col_ab, col_bb);

  // layer 0: aggregate raw x (32ch) once, then folded-weight matmuls
  k_agg32<<<50000, 256, 0, stream>>>(xab, xbb, axaa, axab, axbb,
                                     start_aa, cnt_aa, col_aa,
                                     start_ab, cnt_ab, col_ab,
                                     start_bb, cnt_bb, col_bb);
  const int MMA = (NA + 255) / 256, MMB = (NB + 255) / 256;
  k_mm0_a<<<dim3(MMA, 4), 256, 0, stream>>>(xab, axaa, tA1, Wc, conv_cb);
  k_mm0_b<<<dim3(MMB, 4), 256, 0, stream>>>(xbb, axab, axbb, tB1, Wc, conv_cb);

  // layer 1: full 4-gate 512B aggregation + K=128/256 matmuls
  const int AGA = NA / 4, AGB = NB / 4;
  k_agg512<<<AGA, 256, 0, stream>>>(tA1, tA0, start_aa, cnt_aa, col_aa, NA);
  k_agg512<<<AGB, 256, 0, stream>>>(tA1, tB0, start_ab, cnt_ab, col_ab, NB);
  k_mm_a<<<dim3(MMA, 4), 256, 0, stream>>>(tA1, tA0, conv_wl, conv_wr, conv_cb, 1);
  k_agg512<<<AGB, 256, 0, stream>>>(tB1, tA1 /*scratch*/, start_bb, cnt_bb, col_bb, NB);
  k_mm_b<<<dim3(MMB, 4), 256, 0, stream>>>(tB1, tB0, tA1 /*aggbb*/, conv_wl, conv_wr, conv_cb, 1);

  // final LSTM combine
  k_final2<<<37500, 256, 0, stream>>>(tA0, tB0, lin_b, c_a, c_b, (float*)d_out);
}

// Round 4
// 658.862 us; speedup vs baseline: 20.0297x; 1.2987x over previous
//
#include <hip/hip_runtime.h>
#include <hip/hip_bf16.h>

#define NA 100000
#define NB 50000
#define EAA 1600000
#define EAB 800000
#define EBB 800000

typedef __hip_bfloat16 bf16;
typedef __attribute__((ext_vector_type(8))) short bf16x8;
typedef __attribute__((ext_vector_type(4))) float f32x4;

__device__ __forceinline__ float u2f(unsigned short u) {
  union { unsigned int i; float f; } x; x.i = ((unsigned int)u) << 16; return x.f;
}
__device__ __forceinline__ unsigned short f2u(float f) {
  __hip_bfloat16 h = __float2bfloat16(f);
  return *reinterpret_cast<unsigned short*>(&h);
}
__device__ __forceinline__ short f2bs(float f) {
  __hip_bfloat16 h = __float2bfloat16(f);
  return *reinterpret_cast<short*>(&h);
}
__device__ __forceinline__ float fast_sigmoid(float z) {
  return 1.f / (1.f + __expf(-z));
}
__device__ __forceinline__ float fast_tanh(float z) {
  z = fminf(fmaxf(z, -15.f), 15.f);
  float t = __expf(2.f * z);
  return (t - 1.f) / (t + 1.f);
}

// ---------------- CSR build ----------------
// hist + per-edge position (single atomic pass)
__global__ __launch_bounds__(256) void k_hist3p(
    const int* __restrict__ da, const int* __restrict__ db, const int* __restrict__ dc,
    int* __restrict__ ca, int* __restrict__ cb, int* __restrict__ cc,
    int* __restrict__ pa, int* __restrict__ pb, int* __restrict__ pc) {
  int b = blockIdx.x;
  const int* dst; int* cnt; int* pos; int i;
  if (b < 6250)      { dst = da; cnt = ca; pos = pa; i = b * 256 + threadIdx.x;          if (i >= EAA) return; }
  else if (b < 9375) { dst = db; cnt = cb; pos = pb; i = (b - 6250) * 256 + threadIdx.x; if (i >= EAB) return; }
  else               { dst = dc; cnt = cc; pos = pc; i = (b - 9375) * 256 + threadIdx.x; if (i >= EBB) return; }
  pos[i] = atomicAdd(&cnt[dst[i]], 1);
}

__global__ __launch_bounds__(256) void k_alloc3(
    const int* __restrict__ ca, const int* __restrict__ cb, const int* __restrict__ cc,
    int* __restrict__ sa, int* __restrict__ sb, int* __restrict__ sc, int* __restrict__ ctr) {
  __shared__ int sdata[256];
  __shared__ int sbase;
  int b = blockIdx.x;
  const int* cnt; int* start; int* counter; int n; int lb;
  if (b < 391)      { cnt = ca; start = sa; counter = ctr + 0; n = NA; lb = b; }
  else if (b < 587) { cnt = cb; start = sb; counter = ctr + 1; n = NB; lb = b - 391; }
  else              { cnt = cc; start = sc; counter = ctr + 2; n = NB; lb = b - 587; }
  int tid = threadIdx.x;
  int i = lb * 256 + tid;
  int v = (i < n) ? cnt[i] : 0;
  sdata[tid] = v;
  __syncthreads();
  for (int offs = 1; offs < 256; offs <<= 1) {
    int t = sdata[tid];
    if (tid >= offs) t += sdata[tid - offs];
    __syncthreads();
    sdata[tid] = t;
    __syncthreads();
  }
  if (tid == 255) sbase = atomicAdd(counter, sdata[255]);
  __syncthreads();
  if (i < n) start[i] = sbase + sdata[tid] - v;
}

// fill with precomputed positions — no atomics
__global__ __launch_bounds__(256) void k_fill3p(
    const int* __restrict__ s1, const int* __restrict__ d1,
    const int* __restrict__ s2, const int* __restrict__ d2,
    const int* __restrict__ s3, const int* __restrict__ d3,
    const int* __restrict__ t1, const int* __restrict__ t2, const int* __restrict__ t3,
    const int* __restrict__ p1, const int* __restrict__ p2, const int* __restrict__ p3,
    int* __restrict__ c1, int* __restrict__ c2, int* __restrict__ c3) {
  int b = blockIdx.x;
  const int* src; const int* dst; const int* start; const int* pos; int* col; int i;
  if (b < 6250)      { src = s1; dst = d1; start = t1; pos = p1; col = c1; i = b * 256 + threadIdx.x;          if (i >= EAA) return; }
  else if (b < 9375) { src = s2; dst = d2; start = t2; pos = p2; col = c2; i = (b - 6250) * 256 + threadIdx.x; if (i >= EAB) return; }
  else               { src = s3; dst = d3; start = t3; pos = p3; col = c3; i = (b - 9375) * 256 + threadIdx.x; if (i >= EBB) return; }
  col[start[dst[i]] + pos[i]] = src[i];
}

// ---------------- cast x (f32) -> bf16 ----------------
__global__ __launch_bounds__(256) void k_cast2(const float* __restrict__ xa, const float* __restrict__ xb,
                                               bf16* __restrict__ ya, bf16* __restrict__ yb) {
  int i = blockIdx.x * 256 + threadIdx.x;
  const float* x; bf16* y; int base;
  if (i < 800000)       { x = xa; y = ya; base = i * 4; }
  else if (i < 1200000) { x = xb; y = yb; base = (i - 800000) * 4; }
  else return;
  float4 v = *(const float4*)(x + base);
  ushort4 o; o.x = f2u(v.x); o.y = f2u(v.y); o.z = f2u(v.z); o.w = f2u(v.w);
  *(ushort4*)(y + base) = o;
}

// ---------------- fold the entire linear 2-layer chain into 32x64 mats ----------------
// A-side terms: z_a = P2@WA2 + P@WA1 + xa@WA0 + m_aa*bmask_aa + bconst_a
// B-side terms: z_b = Q2@WQ2 + Q@WQ + S@WS + T@WT + R@WR + xb@WX
//               + m_ab*bmask_ab + m_bb*bmask_bb + bconst_b
__global__ __launch_bounds__(256) void k_wfold(
    const float* __restrict__ lin_w, const float* __restrict__ wl, const float* __restrict__ wr,
    const float* __restrict__ cbv, const float* __restrict__ lin_b,
    float* __restrict__ Wf, float* __restrict__ Bv) {
  int g = blockIdx.x;
  __shared__ float M1[32][64], M2[32][64], N1[32][64], N2[32][64], N3[32][64];
  int r = threadIdx.x >> 3;
  int c0 = (threadIdx.x & 7) * 8;
  const float* L0 = lin_w + (size_t)(g * 2 + 0) * 2048;
  const float* L1 = lin_w + (size_t)(g * 2 + 1) * 2048;
  const float* wl00 = wl + (size_t)((g * 2 + 0) * 3 + 0) * 4096;
  const float* wl10 = wl + (size_t)((g * 2 + 0) * 3 + 1) * 4096;
  const float* wl20 = wl + (size_t)((g * 2 + 0) * 3 + 2) * 4096;
  const float* wr00 = wr + (size_t)((g * 2 + 0) * 3 + 0) * 4096;
  const float* wr10 = wr + (size_t)((g * 2 + 0) * 3 + 1) * 4096;
  const float* wr20 = wr + (size_t)((g * 2 + 0) * 3 + 2) * 4096;
  const float* wl01 = wl + (size_t)((g * 2 + 1) * 3 + 0) * 4096;
  const float* wl11 = wl + (size_t)((g * 2 + 1) * 3 + 1) * 4096;
  const float* wl21 = wl + (size_t)((g * 2 + 1) * 3 + 2) * 4096;
  const float* wr01 = wr + (size_t)((g * 2 + 1) * 3 + 0) * 4096;
  const float* wr11 = wr + (size_t)((g * 2 + 1) * 3 + 1) * 4096;
  const float* wr21 = wr + (size_t)((g * 2 + 1) * 3 + 2) * 4096;

  // phase 1: intermediates
  {
    float a1[8], a2[8], a3[8], a4[8], a5[8];
    #pragma unroll
    for (int j = 0; j < 8; ++j) { a1[j] = a2[j] = a3[j] = a4[j] = a5[j] = 0.f; }
    for (int k = 0; k < 64; ++k) {
      float l0 = L0[r * 64 + k], l1 = L1[r * 64 + k];
      #pragma unroll
      for (int j = 0; j < 8; ++j) {
        int c = c0 + j;
        a1[j] += l0 * wl00[k * 64 + c];
        a2[j] += l0 * wr00[k * 64 + c];
        a3[j] += l0 * wl10[k * 64 + c];
        a4[j] += l1 * wl20[k * 64 + c];
        a5[j] += l1 * (wr10[k * 64 + c] + wr20[k * 64 + c]);
      }
    }
    #pragma unroll
    for (int j = 0; j < 8; ++j) {
      M1[r][c0 + j] = a1[j]; M2[r][c0 + j] = a2[j]; N1[r][c0 + j] = a3[j];
      N2[r][c0 + j] = a4[j]; N3[r][c0 + j] = a5[j];
    }
  }
  __syncthreads();

  // phase 2: 9 output mats
  float* WA = Wf + (size_t)(g * 3) * 2048;
  float* WB = Wf + (size_t)(12 + g * 6) * 2048;
  {
    float o0[8], o1[8], o2[8], o3[8], o4[8], o5[8], o6[8], o7[8], o8[8];
    #pragma unroll
    for (int j = 0; j < 8; ++j) { o0[j]=o1[j]=o2[j]=o3[j]=o4[j]=o5[j]=o6[j]=o7[j]=o8[j]=0.f; }
    for (int k = 0; k < 64; ++k) {
      float m1 = M1[r][k], m2 = M2[r][k], n1 = N1[r][k], n2 = N2[r][k], n3 = N3[r][k];
      #pragma unroll
      for (int j = 0; j < 8; ++j) {
        int c = c0 + j;
        float vwl01 = wl01[k * 64 + c], vwr01 = wr01[k * 64 + c];
        float vwl11 = wl11[k * 64 + c], vwl21 = wl21[k * 64 + c];
        float vwrB1 = wr11[k * 64 + c] + wr21[k * 64 + c];
        o0[j] += m1 * vwl01;                 // WA2
        o1[j] += m2 * vwl01 + m1 * vwr01;    // WA1
        o2[j] += m2 * vwr01;                 // WA0
        o3[j] += m1 * vwl11;                 // WQ2
        o4[j] += m2 * vwl11 + n1 * vwrB1;    // WQ
        o5[j] += n1 * vwl21;                 // WS
        o6[j] += n2 * vwl21;                 // WT
        o7[j] += n2 * vwrB1 + n3 * vwl21;    // WR
        o8[j] += n3 * vwrB1;                 // WX
      }
    }
    #pragma unroll
    for (int j = 0; j < 8; ++j) {
      int c = c0 + j;
      WA[0 * 2048 + r * 64 + c] = o0[j];
      WA[1 * 2048 + r * 64 + c] = o1[j];
      WA[2 * 2048 + r * 64 + c] = o2[j];
      WB[0 * 2048 + r * 64 + c] = o3[j];
      WB[1 * 2048 + r * 64 + c] = o4[j];
      WB[2 * 2048 + r * 64 + c] = o5[j];
      WB[3 * 2048 + r * 64 + c] = o6[j];
      WB[4 * 2048 + r * 64 + c] = o7[j];
      WB[5 * 2048 + r * 64 + c] = o8[j];
    }
  }

  // bias vectors
  if (threadIdx.x < 64) {
    int c = threadIdx.x;
    const float* b00 = cbv + (size_t)((g * 2 + 0) * 3 + 0) * 64;
    const float* b10 = cbv + (size_t)((g * 2 + 0) * 3 + 1) * 64;
    const float* b20 = cbv + (size_t)((g * 2 + 0) * 3 + 2) * 64;
    const float* b01 = cbv + (size_t)((g * 2 + 1) * 3 + 0) * 64;
    const float* b11 = cbv + (size_t)((g * 2 + 1) * 3 + 1) * 64;
    const float* b21 = cbv + (size_t)((g * 2 + 1) * 3 + 2) * 64;
    float s_maa = 0.f, s_ca = 0.f, s_mab = 0.f, s_mbb = 0.f, s_cb = 0.f;
    for (int k = 0; k < 64; ++k) {
      float v0 = b00[k], vb = b10[k] + b20[k];
      s_maa += v0 * wl01[k * 64 + c];
      s_ca  += v0 * wr01[k * 64 + c];
      s_mab += v0 * wl11[k * 64 + c];
      s_mbb += vb * wl21[k * 64 + c];
      s_cb  += vb * (wr11[k * 64 + c] + wr21[k * 64 + c]);
    }
    Bv[(g * 5 + 0) * 64 + c] = s_maa;
    Bv[(g * 5 + 1) * 64 + c] = s_ca + b01[c] + lin_b[(g * 2 + 0) * 64 + c];
    Bv[(g * 5 + 2) * 64 + c] = s_mab;
    Bv[(g * 5 + 3) * 64 + c] = s_mbb;
    Bv[(g * 5 + 4) * 64 + c] = s_cb + b11[c] + b21[c] + lin_b[(g * 2 + 1) * 64 + c];
  }
}

// ---- pass-1 32-ch mean agg: P=A_aa(xa), Q=A_ab(xa), R=A_bb(xb) ----
__global__ __launch_bounds__(256) void k_aggP1(
    const bf16* __restrict__ xa, const bf16* __restrict__ xb,
    bf16* __restrict__ P, bf16* __restrict__ Q, bf16* __restrict__ R,
    const int* __restrict__ st_aa, const int* __restrict__ ct_aa, const int* __restrict__ col_aa,
    const int* __restrict__ st_ab, const int* __restrict__ ct_ab, const int* __restrict__ col_ab,
    const int* __restrict__ st_bb, const int* __restrict__ ct_bb, const int* __restrict__ col_bb) {
  int b = blockIdx.x;
  const bf16* src; bf16* dst; const int* start; const int* cnt; const int* col; int n0;
  if (b < 25000)      { src = xa; dst = P; start = st_aa; cnt = ct_aa; col = col_aa; n0 = b * 4; }
  else if (b < 37500) { src = xa; dst = Q; start = st_ab; cnt = ct_ab; col = col_ab; n0 = (b - 25000) * 4; }
  else                { src = xb; dst = R; start = st_bb; cnt = ct_bb; col = col_bb; n0 = (b - 37500) * 4; }
  int wave = threadIdx.x >> 6, lane = threadIdx.x & 63;
  int n = n0 + wave;
  int e4 = lane >> 4, c16 = lane & 15;
  int st = start[n];
  int deg = cnt[n];
  float s0 = 0.f, s1 = 0.f;
  #pragma unroll 4
  for (int e = e4; e < deg; e += 4) {
    int i = col[st + e];
    ushort2 v = *(const ushort2*)(src + (size_t)i * 32 + c16 * 2);
    s0 += u2f(v.x);
    s1 += u2f(v.y);
  }
  s0 += __shfl_xor(s0, 16); s1 += __shfl_xor(s1, 16);
  s0 += __shfl_xor(s0, 32); s1 += __shfl_xor(s1, 32);
  if (e4 == 0) {
    float inv = 1.f / (float)(deg > 1 ? deg : 1);
    ushort2 o; o.x = f2u(s0 * inv); o.y = f2u(s1 * inv);
    *(ushort2*)(dst + (size_t)n * 32 + c16 * 2) = o;
  }
}

// ---- pass-2: P2=A_aa(P), Q2=A_ab(P), S=A_bb(Q) & T=A_bb(R) fused ----
__global__ __launch_bounds__(256) void k_aggP2(
    const bf16* __restrict__ P, const bf16* __restrict__ Q, const bf16* __restrict__ R,
    bf16* __restrict__ P2, bf16* __restrict__ Q2, bf16* __restrict__ S, bf16* __restrict__ T,
    const int* __restrict__ st_aa, const int* __restrict__ ct_aa, const int* __restrict__ col_aa,
    const int* __restrict__ st_ab, const int* __restrict__ ct_ab, const int* __restrict__ col_ab,
    const int* __restrict__ st_bb, const int* __restrict__ ct_bb, const int* __restrict__ col_bb) {
  int b = blockIdx.x;
  int wave = threadIdx.x >> 6, lane = threadIdx.x & 63;
  int e4 = lane >> 4, c16 = lane & 15;
  if (b < 37500) {
    const bf16* src; bf16* dst; const int* start; const int* cnt; const int* col; int n0;
    if (b < 25000) { src = P; dst = P2; start = st_aa; cnt = ct_aa; col = col_aa; n0 = b * 4; }
    else           { src = P; dst = Q2; start = st_ab; cnt = ct_ab; col = col_ab; n0 = (b - 25000) * 4; }
    int n = n0 + wave;
    int st = start[n];
    int deg = cnt[n];
    float s0 = 0.f, s1 = 0.f;
    #pragma unroll 4
    for (int e = e4; e < deg; e += 4) {
      int i = col[st + e];
      ushort2 v = *(const ushort2*)(src + (size_t)i * 32 + c16 * 2);
      s0 += u2f(v.x);
      s1 += u2f(v.y);
    }
    s0 += __shfl_xor(s0, 16); s1 += __shfl_xor(s1, 16);
    s0 += __shfl_xor(s0, 32); s1 += __shfl_xor(s1, 32);
    if (e4 == 0) {
      float inv = 1.f / (float)(deg > 1 ? deg : 1);
      ushort2 o; o.x = f2u(s0 * inv); o.y = f2u(s1 * inv);
      *(ushort2*)(dst + (size_t)n * 32 + c16 * 2) = o;
    }
  } else {
    // S = A_bb(Q), T = A_bb(R): same edges, gather both planes
    int n = (b - 37500) * 4 + wave;
    int st = st_bb[n];
    int deg = ct_bb[n];
    float q0 = 0.f, q1 = 0.f, r0 = 0.f, r1 = 0.f;
    #pragma unroll 2
    for (int e = e4; e < deg; e += 4) {
      int i = col_bb[st + e];
      ushort2 vq = *(const ushort2*)(Q + (size_t)i * 32 + c16 * 2);
      ushort2 vr = *(const ushort2*)(R + (size_t)i * 32 + c16 * 2);
      q0 += u2f(vq.x); q1 += u2f(vq.y);
      r0 += u2f(vr.x); r1 += u2f(vr.y);
    }
    q0 += __shfl_xor(q0, 16); q1 += __shfl_xor(q1, 16);
    r0 += __shfl_xor(r0, 16); r1 += __shfl_xor(r1, 16);
    q0 += __shfl_xor(q0, 32); q1 += __shfl_xor(q1, 32);
    r0 += __shfl_xor(r0, 32); r1 += __shfl_xor(r1, 32);
    if (e4 == 0) {
      float inv = 1.f / (float)(deg > 1 ? deg : 1);
      ushort2 o1v; o1v.x = f2u(q0 * inv); o1v.y = f2u(q1 * inv);
      *(ushort2*)(S + (size_t)n * 32 + c16 * 2) = o1v;
      ushort2 o2v; o2v.x = f2u(r0 * inv); o2v.y = f2u(r1 * inv);
      *(ushort2*)(T + (size_t)n * 32 + c16 * 2) = o2v;
    }
  }
}

// ---- final A: z (3 MFMA terms x 4 gates) + mask/bias + LSTM -> h_a, cn_a ----
__global__ __launch_bounds__(256) void k_finA(
    const bf16* __restrict__ xa, const bf16* __restrict__ P, const bf16* __restrict__ P2,
    const float* __restrict__ Wf, const float* __restrict__ Bv, const int* __restrict__ cnt_aa,
    const float* __restrict__ c_a, float* __restrict__ out) {
  __shared__ short frag[12 * 4 * 64 * 8];   // 48 KB bf16 B-fragments
  for (int s = threadIdx.x; s < 12 * 4 * 64; s += 256) {
    int mat = s >> 8, nt = (s >> 6) & 3, ln = s & 63;
    const float* w = Wf + (size_t)mat * 2048 + (size_t)((ln >> 4) * 8) * 64 + nt * 16 + (ln & 15);
    bf16x8 v;
    #pragma unroll
    for (int j = 0; j < 8; ++j) v[j] = f2bs(w[j * 64]);
    *(bf16x8*)&frag[(size_t)s * 8] = v;
  }
  __syncthreads();
  int wave = threadIdx.x >> 6, lane = threadIdx.x & 63;
  int l15 = lane & 15, l4 = lane >> 4;
  const size_t TOTA = (size_t)NA * 64, TOTB = (size_t)NB * 64;
  float* h = out;
  float* cn = out + TOTA + TOTB;
  for (int rep = 0; rep < 4; ++rep) {
    int row0 = blockIdx.x * 256 + wave * 64 + rep * 16;
    int r = row0 + l15;
    bool ok = r < NA;
    bf16x8 a0 = {0,0,0,0,0,0,0,0}, a1 = a0, a2 = a0;
    if (ok) {
      a0 = *(const bf16x8*)(P2 + (size_t)r * 32 + l4 * 8);
      a1 = *(const bf16x8*)(P  + (size_t)r * 32 + l4 * 8);
      a2 = *(const bf16x8*)(xa + (size_t)r * 32 + l4 * 8);
    }
    f32x4 z[4][4];
    #pragma unroll
    for (int g = 0; g < 4; ++g) {
      #pragma unroll
      for (int nt = 0; nt < 4; ++nt) {
        f32x4 acc = {0.f, 0.f, 0.f, 0.f};
        acc = __builtin_amdgcn_mfma_f32_16x16x32_bf16(a0, *(bf16x8*)&frag[(((g * 3 + 0) * 4 + nt) * 64 + lane) * 8], acc, 0, 0, 0);
        acc = __builtin_amdgcn_mfma_f32_16x16x32_bf16(a1, *(bf16x8*)&frag[(((g * 3 + 1) * 4 + nt) * 64 + lane) * 8], acc, 0, 0, 0);
        acc = __builtin_amdgcn_mfma_f32_16x16x32_bf16(a2, *(bf16x8*)&frag[(((g * 3 + 2) * 4 + nt) * 64 + lane) * 8], acc, 0, 0, 0);
        z[g][nt] = acc;
      }
    }
    float m[4];
    #pragma unroll
    for (int q = 0; q < 4; ++q) {
      int rr = row0 + l4 * 4 + q;
      m[q] = (rr < NA && cnt_aa[rr] > 0) ? 1.f : 0.f;
    }
    #pragma unroll
    for (int nt = 0; nt < 4; ++nt) {
      int col = nt * 16 + l15;
      #pragma unroll
      for (int q = 0; q < 4; ++q) {
        int rr = row0 + l4 * 4 + q;
        if (rr >= NA) continue;
        float zi = z[0][nt][q] + m[q] * Bv[(0 * 5 + 0) * 64 + col] + Bv[(0 * 5 + 1) * 64 + col];
        float zf = z[1][nt][q] + m[q] * Bv[(1 * 5 + 0) * 64 + col] + Bv[(1 * 5 + 1) * 64 + col];
        float zo = z[2][nt][q] + m[q] * Bv[(2 * 5 + 0) * 64 + col] + Bv[(2 * 5 + 1) * 64 + col];
        float zg = z[3][nt][q] + m[q] * Bv[(3 * 5 + 0) * 64 + col] + Bv[(3 * 5 + 1) * 64 + col];
        float ig = fast_sigmoid(zi);
        float fg = fast_sigmoid(zf);
        float og = fast_sigmoid(zo);
        float gg = fast_tanh(zg);
        size_t idx = (size_t)rr * 64 + col;
        float cv = fg * c_a[idx] + ig * gg;
        h[idx] = og * fast_tanh(cv);
        cn[idx] = cv;
      }
    }
  }
}

// ---- final B: 6 MFMA terms x 4 gates + 2 masks + bias + LSTM -> h_b, cn_b ----
__global__ __launch_bounds__(256) void k_finB(
    const bf16* __restrict__ xb, const bf16* __restrict__ Q, const bf16* __restrict__ R,
    const bf16* __restrict__ Q2, const bf16* __restrict__ S, const bf16* __restrict__ T,
    const float* __restrict__ Wf, const float* __restrict__ Bv,
    const int* __restrict__ cnt_ab, const int* __restrict__ cnt_bb,
    const float* __restrict__ c_b, float* __restrict__ out) {
  extern __shared__ short fragB[];   // 24*4*64*8 shorts = 96 KB
  for (int s = threadIdx.x; s < 24 * 4 * 64; s += 256) {
    int mat = s >> 8, nt = (s >> 6) & 3, ln = s & 63;
    const float* w = Wf + (size_t)(12 + mat) * 2048 + (size_t)((ln >> 4) * 8) * 64 + nt * 16 + (ln & 15);
    bf16x8 v;
    #pragma unroll
    for (int j = 0; j < 8; ++j) v[j] = f2bs(w[j * 64]);
    *(bf16x8*)&fragB[(size_t)s * 8] = v;
  }
  __syncthreads();
  int wave = threadIdx.x >> 6, lane = threadIdx.x & 63;
  int l15 = lane & 15, l4 = lane >> 4;
  const size_t TOTA = (size_t)NA * 64, TOTB = (size_t)NB * 64;
  float* h = out + TOTA;
  float* cn = out + 2 * TOTA + TOTB;
  for (int rep = 0; rep < 4; ++rep) {
    int row0 = blockIdx.x * 256 + wave * 64 + rep * 16;
    int r = row0 + l15;
    bool ok = r < NB;
    bf16x8 a0 = {0,0,0,0,0,0,0,0}, a1 = a0, a2 = a0, a3 = a0, a4 = a0, a5 = a0;
    if (ok) {
      a0 = *(const bf16x8*)(Q2 + (size_t)r * 32 + l4 * 8);
      a1 = *(const bf16x8*)(Q  + (size_t)r * 32 + l4 * 8);
      a2 = *(const bf16x8*)(S  + (size_t)r * 32 + l4 * 8);
      a3 = *(const bf16x8*)(T  + (size_t)r * 32 + l4 * 8);
      a4 = *(const bf16x8*)(R  + (size_t)r * 32 + l4 * 8);
      a5 = *(const bf16x8*)(xb + (size_t)r * 32 + l4 * 8);
    }
    f32x4 z[4][4];
    #pragma unroll
    for (int g = 0; g < 4; ++g) {
      #pragma unroll
      for (int nt = 0; nt < 4; ++nt) {
        f32x4 acc = {0.f, 0.f, 0.f, 0.f};
        acc = __builtin_amdgcn_mfma_f32_16x16x32_bf16(a0, *(bf16x8*)&fragB[(((g * 6 + 0) * 4 + nt) * 64 + lane) * 8], acc, 0, 0, 0);
        acc = __builtin_amdgcn_mfma_f32_16x16x32_bf16(a1, *(bf16x8*)&fragB[(((g * 6 + 1) * 4 + nt) * 64 + lane) * 8], acc, 0, 0, 0);
        acc = __builtin_amdgcn_mfma_f32_16x16x32_bf16(a2, *(bf16x8*)&fragB[(((g * 6 + 2) * 4 + nt) * 64 + lane) * 8], acc, 0, 0, 0);
        acc = __builtin_amdgcn_mfma_f32_16x16x32_bf16(a3, *(bf16x8*)&fragB[(((g * 6 + 3) * 4 + nt) * 64 + lane) * 8], acc, 0, 0, 0);
        acc = __builtin_amdgcn_mfma_f32_16x16x32_bf16(a4, *(bf16x8*)&fragB[(((g * 6 + 4) * 4 + nt) * 64 + lane) * 8], acc, 0, 0, 0);
        acc = __builtin_amdgcn_mfma_f32_16x16x32_bf16(a5, *(bf16x8*)&fragB[(((g * 6 + 5) * 4 + nt) * 64 + lane) * 8], acc, 0, 0, 0);
        z[g][nt] = acc;
      }
    }
    float mab[4], mbb[4];
    #pragma unroll
    for (int q = 0; q < 4; ++q) {
      int rr = row0 + l4 * 4 + q;
      bool okr = rr < NB;
      mab[q] = (okr && cnt_ab[rr] > 0) ? 1.f : 0.f;
      mbb[q] = (okr && cnt_bb[rr] > 0) ? 1.f : 0.f;
    }
    #pragma unroll
    for (int nt = 0; nt < 4; ++nt) {
      int col = nt * 16 + l15;
      #pragma unroll
      for (int q = 0; q < 4; ++q) {
        int rr = row0 + l4 * 4 + q;
        if (rr >= NB) continue;
        float zi = z[0][nt][q] + mab[q] * Bv[(0 * 5 + 2) * 64 + col] + mbb[q] * Bv[(0 * 5 + 3) * 64 + col] + Bv[(0 * 5 + 4) * 64 + col];
        float zf = z[1][nt][q] + mab[q] * Bv[(1 * 5 + 2) * 64 + col] + mbb[q] * Bv[(1 * 5 + 3) * 64 + col] + Bv[(1 * 5 + 4) * 64 + col];
        float zo = z[2][nt][q] + mab[q] * Bv[(2 * 5 + 2) * 64 + col] + mbb[q] * Bv[(2 * 5 + 3) * 64 + col] + Bv[(2 * 5 + 4) * 64 + col];
        float zg = z[3][nt][q] + mab[q] * Bv[(3 * 5 + 2) * 64 + col] + mbb[q] * Bv[(3 * 5 + 3) * 64 + col] + Bv[(3 * 5 + 4) * 64 + col];
        float ig = fast_sigmoid(zi);
        float fg = fast_sigmoid(zf);
        float og = fast_sigmoid(zo);
        float gg = fast_tanh(zg);
        size_t idx = (size_t)rr * 64 + col;
        float cv = fg * c_b[idx] + ig * gg;
        h[idx] = og * fast_tanh(cv);
        cn[idx] = cv;
      }
    }
  }
}

extern "C" void kernel_launch(void* const* d_in, const int* in_sizes, int n_in,
                              void* d_out, int out_size, void* d_ws, size_t ws_size,
                              hipStream_t stream) {
  (void)in_sizes; (void)n_in; (void)out_size; (void)ws_size;
  const float* x_a    = (const float*)d_in[0];
  const float* x_b    = (const float*)d_in[1];
  const float* c_a    = (const float*)d_in[2];
  const float* c_b    = (const float*)d_in[3];
  const float* lin_w  = (const float*)d_in[4];
  const float* lin_b  = (const float*)d_in[5];
  const float* conv_wl = (const float*)d_in[6];
  const float* conv_wr = (const float*)d_in[7];
  const float* conv_cb = (const float*)d_in[8];
  const int* src_aa = (const int*)d_in[9];
  const int* dst_aa = (const int*)d_in[10];
  const int* src_ab = (const int*)d_in[11];
  const int* dst_ab = (const int*)d_in[12];
  const int* src_bb = (const int*)d_in[13];
  const int* dst_bb = (const int*)d_in[14];

  char* ws = (char*)d_ws;
  size_t off = 0;
  auto alloc = [&](size_t bytes) -> char* {
    off = (off + 255) & ~(size_t)255;
    char* p = ws + off;
    off += bytes;
    return p;
  };
  bf16* xab = (bf16*)alloc((size_t)NA * 32 * 2);
  bf16* xbb = (bf16*)alloc((size_t)NB * 32 * 2);
  bf16* P   = (bf16*)alloc((size_t)NA * 32 * 2);
  bf16* P2  = (bf16*)alloc((size_t)NA * 32 * 2);
  bf16* Q   = (bf16*)alloc((size_t)NB * 32 * 2);
  bf16* R   = (bf16*)alloc((size_t)NB * 32 * 2);
  bf16* Q2  = (bf16*)alloc((size_t)NB * 32 * 2);
  bf16* S   = (bf16*)alloc((size_t)NB * 32 * 2);
  bf16* T   = (bf16*)alloc((size_t)NB * 32 * 2);
  float* Wf = (float*)alloc((size_t)36 * 2048 * 4);
  float* Bv = (float*)alloc((size_t)4 * 5 * 64 * 4);
  int* col_aa  = (int*)alloc((size_t)EAA * 4);
  int* col_ab  = (int*)alloc((size_t)EAB * 4);
  int* col_bb  = (int*)alloc((size_t)EBB * 4);
  int* pos_aa  = (int*)alloc((size_t)EAA * 4);
  int* pos_ab  = (int*)alloc((size_t)EAB * 4);
  int* pos_bb  = (int*)alloc((size_t)EBB * 4);
  int* start_aa = (int*)alloc((size_t)NA * 4);
  int* start_ab = (int*)alloc((size_t)NB * 4);
  int* start_bb = (int*)alloc((size_t)NB * 4);
  size_t zbeg = (off + 255) & ~(size_t)255;
  int* cnt_aa  = (int*)alloc((size_t)NA * 4);
  int* cnt_ab  = (int*)alloc((size_t)NB * 4);
  int* cnt_bb  = (int*)alloc((size_t)NB * 4);
  int* ctr     = (int*)alloc(256);
  size_t zend = off;
  hipMemsetAsync(ws + zbeg, 0, zend - zbeg, stream);

  // independent prep
  k_wfold<<<4, 256, 0, stream>>>(lin_w, conv_wl, conv_wr, conv_cb, lin_b, Wf, Bv);
  k_cast2<<<4688, 256, 0, stream>>>(x_a, x_b, xab, xbb);

  // CSR build
  k_hist3p<<<12500, 256, 0, stream>>>(dst_aa, dst_ab, dst_bb, cnt_aa, cnt_ab, cnt_bb,
                                      pos_aa, pos_ab, pos_bb);
  k_alloc3<<<783, 256, 0, stream>>>(cnt_aa, cnt_ab, cnt_bb, start_aa, start_ab, start_bb, ctr);
  k_fill3p<<<12500, 256, 0, stream>>>(src_aa, dst_aa, src_ab, dst_ab, src_bb, dst_bb,
                                      start_aa, start_ab, start_bb,
                                      pos_aa, pos_ab, pos_bb,
                                      col_aa, col_ab, col_bb);

  // aggregation chains (32-ch rows only)
  k_aggP1<<<50000, 256, 0, stream>>>(xab, xbb, P, Q, R,
                                     start_aa, cnt_aa, col_aa,
                                     start_ab, cnt_ab, col_ab,
                                     start_bb, cnt_bb, col_bb);
  k_aggP2<<<50000, 256, 0, stream>>>(P, Q, R, P2, Q2, S, T,
                                     start_aa, cnt_aa, col_aa,
                                     start_ab, cnt_ab, col_ab,
                                     start_bb, cnt_bb, col_bb);

  // fused z-matmul + LSTM
  k_finA<<<391, 256, 0, stream>>>(xab, P, P2, Wf, Bv, cnt_aa, c_a, (float*)d_out);
  k_finB<<<196, 256, 24 * 4 * 64 * 8 * sizeof(short), stream>>>(
      xbb, Q, R, Q2, S, T, Wf, Bv, cnt_ab, cnt_bb, c_b, (float*)d_out);
}

// Round 5
// 560.040 us; speedup vs baseline: 23.5640x; 1.1765x over previous
//
#include <hip/hip_runtime.h>
#include <hip/hip_bf16.h>

#define NA 100000
#define NB 50000
#define EAA 1600000
#define EAB 800000
#define EBB 800000

#define NBKAA 782   // ceil(NA/128)
#define NBKB  391   // ceil(NB/128)
#define BKA 200     // blocks for aa set (8000 edges each)
#define BKB 100     // blocks for ab/bb sets (8000 edges each)
#define DCAP 4096   // kD staging capacity (mean 2048, sd ~45 for aa)

typedef __hip_bfloat16 bf16;
typedef __attribute__((ext_vector_type(8))) short bf16x8;
typedef __attribute__((ext_vector_type(4))) float f32x4;

__device__ __forceinline__ float u2f(unsigned short u) {
  union { unsigned int i; float f; } x; x.i = ((unsigned int)u) << 16; return x.f;
}
__device__ __forceinline__ unsigned short f2u(float f) {
  __hip_bfloat16 h = __float2bfloat16(f);
  return *reinterpret_cast<unsigned short*>(&h);
}
__device__ __forceinline__ short f2bs(float f) {
  __hip_bfloat16 h = __float2bfloat16(f);
  return *reinterpret_cast<short*>(&h);
}
__device__ __forceinline__ float fast_sigmoid(float z) {
  return 1.f / (1.f + __expf(-z));
}
__device__ __forceinline__ float fast_tanh(float z) {
  z = fminf(fmaxf(z, -15.f), 15.f);
  float t = __expf(2.f * z);
  return (t - 1.f) / (t + 1.f);
}

// =============== CSR build: atomic-free counting sort ===============
// Phase A: per-block LDS bucket histogram -> bin[blk][bucket]
__global__ __launch_bounds__(256) void kA_bin(
    const int* __restrict__ d1, const int* __restrict__ d2, const int* __restrict__ d3,
    int* __restrict__ binAA, int* __restrict__ binAB, int* __restrict__ binBB) {
  __shared__ int h[1024];
  int blk = blockIdx.x;
  const int* dst; int* out; int e0, nbk;
  if (blk < BKA)            { dst = d1; out = binAA + blk * NBKAA; e0 = blk * 8000; nbk = NBKAA; }
  else if (blk < BKA + BKB) { int k = blk - BKA; dst = d2; out = binAB + k * NBKB; e0 = k * 8000; nbk = NBKB; }
  else                      { int k = blk - BKA - BKB; dst = d3; out = binBB + k * NBKB; e0 = k * 8000; nbk = NBKB; }
  for (int i = threadIdx.x; i < nbk; i += 256) h[i] = 0;
  __syncthreads();
  for (int i = threadIdx.x; i < 8000; i += 256) atomicAdd(&h[dst[e0 + i] >> 7], 1);
  __syncthreads();
  for (int i = threadIdx.x; i < nbk; i += 256) out[i] = h[i];
}

// Phase B1: per-bucket exclusive scan across blocks (one wave per bucket)
__global__ __launch_bounds__(256) void kB1(
    int* __restrict__ binAA, int* __restrict__ binAB, int* __restrict__ binBB,
    int* __restrict__ totAA, int* __restrict__ totAB, int* __restrict__ totBB) {
  int wave = threadIdx.x >> 6, lane = threadIdx.x & 63;
  int wid = blockIdx.x * 4 + wave;
  int* bin; int* tot; int b, nblk, nbk;
  if (wid < NBKAA)              { bin = binAA; tot = totAA; b = wid; nblk = BKA; nbk = NBKAA; }
  else if (wid < NBKAA + NBKB)  { bin = binAB; tot = totAB; b = wid - NBKAA; nblk = BKB; nbk = NBKB; }
  else                          { bin = binBB; tot = totBB; b = wid - NBKAA - NBKB; nblk = BKB; nbk = NBKB; }
  int C = (nblk + 63) / 64;  // 4 for aa, 2 for ab/bb
  int vals[4]; int s = 0;
  for (int j = 0; j < C; ++j) { int k = lane * C + j; vals[j] = (k < nblk) ? bin[k * nbk + b] : 0; s += vals[j]; }
  int pre = s;
  for (int o = 1; o < 64; o <<= 1) { int x = __shfl_up(pre, o); if (lane >= o) pre += x; }
  int run = pre - s;
  for (int j = 0; j < C; ++j) { int k = lane * C + j; if (k < nblk) { int v = vals[j]; bin[k * nbk + b] = run; run += v; } }
  if (lane == 63) tot[b] = pre;
}

// Phase B2: per-set exclusive scan of bucket totals -> bucketStart (+ sentinel)
__global__ __launch_bounds__(256) void kB2(
    const int* __restrict__ totAA, const int* __restrict__ totAB, const int* __restrict__ totBB,
    int* __restrict__ bsAA, int* __restrict__ bsAB, int* __restrict__ bsBB) {
  __shared__ int part[256];
  int set = blockIdx.x; const int* tot; int* bs; int nbk;
  if (set == 0)      { tot = totAA; bs = bsAA; nbk = NBKAA; }
  else if (set == 1) { tot = totAB; bs = bsAB; nbk = NBKB; }
  else               { tot = totBB; bs = bsBB; nbk = NBKB; }
  int t = threadIdx.x;
  int v[4]; int s = 0;
  #pragma unroll
  for (int j = 0; j < 4; ++j) { int k = t * 4 + j; v[j] = (k < nbk) ? tot[k] : 0; s += v[j]; }
  part[t] = s;
  __syncthreads();
  for (int o = 1; o < 256; o <<= 1) {
    int x = (t >= o) ? part[t - o] : 0;
    __syncthreads();
    part[t] += x;
    __syncthreads();
  }
  int run = part[t] - s;
  #pragma unroll
  for (int j = 0; j < 4; ++j) { int k = t * 4 + j; if (k < nbk) { bs[k] = run; run += v[j]; } }
  if (t == 255) bs[nbk] = part[255];
}

// Phase C: scatter edges into bucket order, packed as src | (dstLow<<24)
__global__ __launch_bounds__(256) void kC_scatter(
    const int* __restrict__ s1, const int* __restrict__ d1,
    const int* __restrict__ s2, const int* __restrict__ d2,
    const int* __restrict__ s3, const int* __restrict__ d3,
    const int* __restrict__ binAA, const int* __restrict__ binAB, const int* __restrict__ binBB,
    const int* __restrict__ bsAA, const int* __restrict__ bsAB, const int* __restrict__ bsBB,
    int* __restrict__ pkAA, int* __restrict__ pkAB, int* __restrict__ pkBB) {
  __shared__ int baseL[1024];
  __shared__ int run[1024];
  int blk = blockIdx.x;
  const int* src; const int* dst; const int* bin; const int* bs; int* pk; int e0, nbk, bofs;
  if (blk < BKA)            { src = s1; dst = d1; bin = binAA; bs = bsAA; pk = pkAA; e0 = blk * 8000; nbk = NBKAA; bofs = blk * NBKAA; }
  else if (blk < BKA + BKB) { int k = blk - BKA; src = s2; dst = d2; bin = binAB; bs = bsAB; pk = pkAB; e0 = k * 8000; nbk = NBKB; bofs = k * NBKB; }
  else                      { int k = blk - BKA - BKB; src = s3; dst = d3; bin = binBB; bs = bsBB; pk = pkBB; e0 = k * 8000; nbk = NBKB; bofs = k * NBKB; }
  for (int i = threadIdx.x; i < nbk; i += 256) { baseL[i] = bs[i] + bin[bofs + i]; run[i] = 0; }
  __syncthreads();
  for (int i = threadIdx.x; i < 8000; i += 256) {
    int d = dst[e0 + i];
    int b = d >> 7;
    int off = atomicAdd(&run[b], 1);
    pk[baseL[b] + off] = src[e0 + i] | ((d & 127) << 24);
  }
}

// Phase D: per-bucket node sort -> col (coalesced), start/cnt per node
__global__ __launch_bounds__(256) void kD_nodesort(
    const int* __restrict__ pkAA, const int* __restrict__ pkAB, const int* __restrict__ pkBB,
    const int* __restrict__ bsAA, const int* __restrict__ bsAB, const int* __restrict__ bsBB,
    int* __restrict__ colAA, int* __restrict__ colAB, int* __restrict__ colBB,
    int* __restrict__ stAA, int* __restrict__ ctAA,
    int* __restrict__ stAB, int* __restrict__ ctAB,
    int* __restrict__ stBB, int* __restrict__ ctBB) {
  __shared__ int hist[128], nodeOff[129], run[128];
  __shared__ int stage[DCAP];
  int wid = blockIdx.x;
  const int* pk; const int* bs; int* col; int* stn; int* ctn; int b, N;
  if (wid < NBKAA)             { pk = pkAA; bs = bsAA; col = colAA; stn = stAA; ctn = ctAA; b = wid; N = NA; }
  else if (wid < NBKAA + NBKB) { pk = pkAB; bs = bsAB; col = colAB; stn = stAB; ctn = ctAB; b = wid - NBKAA; N = NB; }
  else                         { pk = pkBB; bs = bsBB; col = colBB; stn = stBB; ctn = ctBB; b = wid - NBKAA - NBKB; N = NB; }
  int node0 = b * 128;
  int base = bs[b], cntB = bs[b + 1] - base;
  int t = threadIdx.x;
  if (t < 128) hist[t] = 0;
  __syncthreads();
  for (int i = t; i < cntB; i += 256) atomicAdd(&hist[pk[base + i] >> 24], 1);
  __syncthreads();
  if (t < 64) {
    int v0 = hist[2 * t], v1 = hist[2 * t + 1];
    int s = v0 + v1; int pre = s;
    for (int o = 1; o < 64; o <<= 1) { int x = __shfl_up(pre, o); if (t >= o) pre += x; }
    int ex = pre - s;
    nodeOff[2 * t] = ex; nodeOff[2 * t + 1] = ex + v0;
    if (t == 63) nodeOff[128] = pre;
    run[2 * t] = 0; run[2 * t + 1] = 0;
  }
  __syncthreads();
  if (t < 128) {
    int n = node0 + t;
    if (n < N) { ctn[n] = hist[t]; stn[n] = base + nodeOff[t]; }
  }
  if (cntB <= DCAP) {
    for (int i = t; i < cntB; i += 256) {
      int e = pk[base + i]; int ln = e >> 24;
      int off = atomicAdd(&run[ln], 1);
      stage[nodeOff[ln] + off] = e & 0xFFFFFF;
    }
    __syncthreads();
    for (int i = t; i < cntB; i += 256) col[base + i] = stage[i];
  } else {
    for (int i = t; i < cntB; i += 256) {
      int e = pk[base + i]; int ln = e >> 24;
      int off = atomicAdd(&run[ln], 1);
      col[base + nodeOff[ln] + off] = e & 0xFFFFFF;
    }
  }
}

// ---------------- cast x (f32) -> bf16 ----------------
__global__ __launch_bounds__(256) void k_cast2(const float* __restrict__ xa, const float* __restrict__ xb,
                                               bf16* __restrict__ ya, bf16* __restrict__ yb) {
  int i = blockIdx.x * 256 + threadIdx.x;
  const float* x; bf16* y; int base;
  if (i < 800000)       { x = xa; y = ya; base = i * 4; }
  else if (i < 1200000) { x = xb; y = yb; base = (i - 800000) * 4; }
  else return;
  float4 v = *(const float4*)(x + base);
  ushort4 o; o.x = f2u(v.x); o.y = f2u(v.y); o.z = f2u(v.z); o.w = f2u(v.w);
  *(ushort4*)(y + base) = o;
}

// ---------------- fold the entire linear 2-layer chain into 32x64 mats ----------------
__global__ __launch_bounds__(256) void k_wfold(
    const float* __restrict__ lin_w, const float* __restrict__ wl, const float* __restrict__ wr,
    const float* __restrict__ cbv, const float* __restrict__ lin_b,
    float* __restrict__ Wf, float* __restrict__ Bv) {
  int g = blockIdx.x;
  __shared__ float M1[32][64], M2[32][64], N1[32][64], N2[32][64], N3[32][64];
  int r = threadIdx.x >> 3;
  int c0 = (threadIdx.x & 7) * 8;
  const float* L0 = lin_w + (size_t)(g * 2 + 0) * 2048;
  const float* L1 = lin_w + (size_t)(g * 2 + 1) * 2048;
  const float* wl00 = wl + (size_t)((g * 2 + 0) * 3 + 0) * 4096;
  const float* wl10 = wl + (size_t)((g * 2 + 0) * 3 + 1) * 4096;
  const float* wl20 = wl + (size_t)((g * 2 + 0) * 3 + 2) * 4096;
  const float* wr00 = wr + (size_t)((g * 2 + 0) * 3 + 0) * 4096;
  const float* wr10 = wr + (size_t)((g * 2 + 0) * 3 + 1) * 4096;
  const float* wr20 = wr + (size_t)((g * 2 + 0) * 3 + 2) * 4096;
  const float* wl01 = wl + (size_t)((g * 2 + 1) * 3 + 0) * 4096;
  const float* wl11 = wl + (size_t)((g * 2 + 1) * 3 + 1) * 4096;
  const float* wl21 = wl + (size_t)((g * 2 + 1) * 3 + 2) * 4096;
  const float* wr01 = wr + (size_t)((g * 2 + 1) * 3 + 0) * 4096;
  const float* wr11 = wr + (size_t)((g * 2 + 1) * 3 + 1) * 4096;
  const float* wr21 = wr + (size_t)((g * 2 + 1) * 3 + 2) * 4096;

  {
    float a1[8], a2[8], a3[8], a4[8], a5[8];
    #pragma unroll
    for (int j = 0; j < 8; ++j) { a1[j] = a2[j] = a3[j] = a4[j] = a5[j] = 0.f; }
    for (int k = 0; k < 64; ++k) {
      float l0 = L0[r * 64 + k], l1 = L1[r * 64 + k];
      #pragma unroll
      for (int j = 0; j < 8; ++j) {
        int c = c0 + j;
        a1[j] += l0 * wl00[k * 64 + c];
        a2[j] += l0 * wr00[k * 64 + c];
        a3[j] += l0 * wl10[k * 64 + c];
        a4[j] += l1 * wl20[k * 64 + c];
        a5[j] += l1 * (wr10[k * 64 + c] + wr20[k * 64 + c]);
      }
    }
    #pragma unroll
    for (int j = 0; j < 8; ++j) {
      M1[r][c0 + j] = a1[j]; M2[r][c0 + j] = a2[j]; N1[r][c0 + j] = a3[j];
      N2[r][c0 + j] = a4[j]; N3[r][c0 + j] = a5[j];
    }
  }
  __syncthreads();

  float* WA = Wf + (size_t)(g * 3) * 2048;
  float* WB = Wf + (size_t)(12 + g * 6) * 2048;
  {
    float o0[8], o1[8], o2[8], o3[8], o4[8], o5[8], o6[8], o7[8], o8[8];
    #pragma unroll
    for (int j = 0; j < 8; ++j) { o0[j]=o1[j]=o2[j]=o3[j]=o4[j]=o5[j]=o6[j]=o7[j]=o8[j]=0.f; }
    for (int k = 0; k < 64; ++k) {
      float m1 = M1[r][k], m2 = M2[r][k], n1 = N1[r][k], n2 = N2[r][k], n3 = N3[r][k];
      #pragma unroll
      for (int j = 0; j < 8; ++j) {
        int c = c0 + j;
        float vwl01 = wl01[k * 64 + c], vwr01 = wr01[k * 64 + c];
        float vwl11 = wl11[k * 64 + c], vwl21 = wl21[k * 64 + c];
        float vwrB1 = wr11[k * 64 + c] + wr21[k * 64 + c];
        o0[j] += m1 * vwl01;
        o1[j] += m2 * vwl01 + m1 * vwr01;
        o2[j] += m2 * vwr01;
        o3[j] += m1 * vwl11;
        o4[j] += m2 * vwl11 + n1 * vwrB1;
        o5[j] += n1 * vwl21;
        o6[j] += n2 * vwl21;
        o7[j] += n2 * vwrB1 + n3 * vwl21;
        o8[j] += n3 * vwrB1;
      }
    }
    #pragma unroll
    for (int j = 0; j < 8; ++j) {
      int c = c0 + j;
      WA[0 * 2048 + r * 64 + c] = o0[j];
      WA[1 * 2048 + r * 64 + c] = o1[j];
      WA[2 * 2048 + r * 64 + c] = o2[j];
      WB[0 * 2048 + r * 64 + c] = o3[j];
      WB[1 * 2048 + r * 64 + c] = o4[j];
      WB[2 * 2048 + r * 64 + c] = o5[j];
      WB[3 * 2048 + r * 64 + c] = o6[j];
      WB[4 * 2048 + r * 64 + c] = o7[j];
      WB[5 * 2048 + r * 64 + c] = o8[j];
    }
  }

  if (threadIdx.x < 64) {
    int c = threadIdx.x;
    const float* b00 = cbv + (size_t)((g * 2 + 0) * 3 + 0) * 64;
    const float* b10 = cbv + (size_t)((g * 2 + 0) * 3 + 1) * 64;
    const float* b20 = cbv + (size_t)((g * 2 + 0) * 3 + 2) * 64;
    const float* b01 = cbv + (size_t)((g * 2 + 1) * 3 + 0) * 64;
    const float* b11 = cbv + (size_t)((g * 2 + 1) * 3 + 1) * 64;
    const float* b21 = cbv + (size_t)((g * 2 + 1) * 3 + 2) * 64;
    float s_maa = 0.f, s_ca = 0.f, s_mab = 0.f, s_mbb = 0.f, s_cb = 0.f;
    for (int k = 0; k < 64; ++k) {
      float v0 = b00[k], vb = b10[k] + b20[k];
      s_maa += v0 * wl01[k * 64 + c];
      s_ca  += v0 * wr01[k * 64 + c];
      s_mab += v0 * wl11[k * 64 + c];
      s_mbb += vb * wl21[k * 64 + c];
      s_cb  += vb * (wr11[k * 64 + c] + wr21[k * 64 + c]);
    }
    Bv[(g * 5 + 0) * 64 + c] = s_maa;
    Bv[(g * 5 + 1) * 64 + c] = s_ca + b01[c] + lin_b[(g * 2 + 0) * 64 + c];
    Bv[(g * 5 + 2) * 64 + c] = s_mab;
    Bv[(g * 5 + 3) * 64 + c] = s_mbb;
    Bv[(g * 5 + 4) * 64 + c] = s_cb + b11[c] + b21[c] + lin_b[(g * 2 + 1) * 64 + c];
  }
}

// ---- pass-1 32-ch mean agg: P=A_aa(xa), Q=A_ab(xa), R=A_bb(xb) ----
__global__ __launch_bounds__(256) void k_aggP1(
    const bf16* __restrict__ xa, const bf16* __restrict__ xb,
    bf16* __restrict__ P, bf16* __restrict__ Q, bf16* __restrict__ R,
    const int* __restrict__ st_aa, const int* __restrict__ ct_aa, const int* __restrict__ col_aa,
    const int* __restrict__ st_ab, const int* __restrict__ ct_ab, const int* __restrict__ col_ab,
    const int* __restrict__ st_bb, const int* __restrict__ ct_bb, const int* __restrict__ col_bb) {
  int b = blockIdx.x;
  const bf16* src; bf16* dst; const int* start; const int* cnt; const int* col; int n0;
  if (b < 25000)      { src = xa; dst = P; start = st_aa; cnt = ct_aa; col = col_aa; n0 = b * 4; }
  else if (b < 37500) { src = xa; dst = Q; start = st_ab; cnt = ct_ab; col = col_ab; n0 = (b - 25000) * 4; }
  else                { src = xb; dst = R; start = st_bb; cnt = ct_bb; col = col_bb; n0 = (b - 37500) * 4; }
  int wave = threadIdx.x >> 6, lane = threadIdx.x & 63;
  int n = n0 + wave;
  int e4 = lane >> 4, c16 = lane & 15;
  int st = start[n];
  int deg = cnt[n];
  float s0 = 0.f, s1 = 0.f;
  #pragma unroll 4
  for (int e = e4; e < deg; e += 4) {
    int i = col[st + e];
    ushort2 v = *(const ushort2*)(src + (size_t)i * 32 + c16 * 2);
    s0 += u2f(v.x);
    s1 += u2f(v.y);
  }
  s0 += __shfl_xor(s0, 16); s1 += __shfl_xor(s1, 16);
  s0 += __shfl_xor(s0, 32); s1 += __shfl_xor(s1, 32);
  if (e4 == 0) {
    float inv = 1.f / (float)(deg > 1 ? deg : 1);
    ushort2 o; o.x = f2u(s0 * inv); o.y = f2u(s1 * inv);
    *(ushort2*)(dst + (size_t)n * 32 + c16 * 2) = o;
  }
}

// ---- pass-2: P2=A_aa(P), Q2=A_ab(P), S=A_bb(Q) & T=A_bb(R) fused ----
__global__ __launch_bounds__(256) void k_aggP2(
    const bf16* __restrict__ P, const bf16* __restrict__ Q, const bf16* __restrict__ R,
    bf16* __restrict__ P2, bf16* __restrict__ Q2, bf16* __restrict__ S, bf16* __restrict__ T,
    const int* __restrict__ st_aa, const int* __restrict__ ct_aa, const int* __restrict__ col_aa,
    const int* __restrict__ st_ab, const int* __restrict__ ct_ab, const int* __restrict__ col_ab,
    const int* __restrict__ st_bb, const int* __restrict__ ct_bb, const int* __restrict__ col_bb) {
  int b = blockIdx.x;
  int wave = threadIdx.x >> 6, lane = threadIdx.x & 63;
  int e4 = lane >> 4, c16 = lane & 15;
  if (b < 37500) {
    const bf16* src; bf16* dst; const int* start; const int* cnt; const int* col; int n0;
    if (b < 25000) { src = P; dst = P2; start = st_aa; cnt = ct_aa; col = col_aa; n0 = b * 4; }
    else           { src = P; dst = Q2; start = st_ab; cnt = ct_ab; col = col_ab; n0 = (b - 25000) * 4; }
    int n = n0 + wave;
    int st = start[n];
    int deg = cnt[n];
    float s0 = 0.f, s1 = 0.f;
    #pragma unroll 4
    for (int e = e4; e < deg; e += 4) {
      int i = col[st + e];
      ushort2 v = *(const ushort2*)(src + (size_t)i * 32 + c16 * 2);
      s0 += u2f(v.x);
      s1 += u2f(v.y);
    }
    s0 += __shfl_xor(s0, 16); s1 += __shfl_xor(s1, 16);
    s0 += __shfl_xor(s0, 32); s1 += __shfl_xor(s1, 32);
    if (e4 == 0) {
      float inv = 1.f / (float)(deg > 1 ? deg : 1);
      ushort2 o; o.x = f2u(s0 * inv); o.y = f2u(s1 * inv);
      *(ushort2*)(dst + (size_t)n * 32 + c16 * 2) = o;
    }
  } else {
    int n = (b - 37500) * 4 + wave;
    int st = st_bb[n];
    int deg = ct_bb[n];
    float q0 = 0.f, q1 = 0.f, r0 = 0.f, r1 = 0.f;
    #pragma unroll 2
    for (int e = e4; e < deg; e += 4) {
      int i = col_bb[st + e];
      ushort2 vq = *(const ushort2*)(Q + (size_t)i * 32 + c16 * 2);
      ushort2 vr = *(const ushort2*)(R + (size_t)i * 32 + c16 * 2);
      q0 += u2f(vq.x); q1 += u2f(vq.y);
      r0 += u2f(vr.x); r1 += u2f(vr.y);
    }
    q0 += __shfl_xor(q0, 16); q1 += __shfl_xor(q1, 16);
    r0 += __shfl_xor(r0, 16); r1 += __shfl_xor(r1, 16);
    q0 += __shfl_xor(q0, 32); q1 += __shfl_xor(q1, 32);
    r0 += __shfl_xor(r0, 32); r1 += __shfl_xor(r1, 32);
    if (e4 == 0) {
      float inv = 1.f / (float)(deg > 1 ? deg : 1);
      ushort2 o1v; o1v.x = f2u(q0 * inv); o1v.y = f2u(q1 * inv);
      *(ushort2*)(S + (size_t)n * 32 + c16 * 2) = o1v;
      ushort2 o2v; o2v.x = f2u(r0 * inv); o2v.y = f2u(r1 * inv);
      *(ushort2*)(T + (size_t)n * 32 + c16 * 2) = o2v;
    }
  }
}

// ---- final A: z (3 MFMA terms x 4 gates) + mask/bias + LSTM -> h_a, cn_a ----
__global__ __launch_bounds__(256) void k_finA(
    const bf16* __restrict__ xa, const bf16* __restrict__ P, const bf16* __restrict__ P2,
    const float* __restrict__ Wf, const float* __restrict__ Bv, const int* __restrict__ cnt_aa,
    const float* __restrict__ c_a, float* __restrict__ out) {
  __shared__ short frag[12 * 4 * 64 * 8];
  for (int s = threadIdx.x; s < 12 * 4 * 64; s += 256) {
    int mat = s >> 8, nt = (s >> 6) & 3, ln = s & 63;
    const float* w = Wf + (size_t)mat * 2048 + (size_t)((ln >> 4) * 8) * 64 + nt * 16 + (ln & 15);
    bf16x8 v;
    #pragma unroll
    for (int j = 0; j < 8; ++j) v[j] = f2bs(w[j * 64]);
    *(bf16x8*)&frag[(size_t)s * 8] = v;
  }
  __syncthreads();
  int wave = threadIdx.x >> 6, lane = threadIdx.x & 63;
  int l15 = lane & 15, l4 = lane >> 4;
  const size_t TOTA = (size_t)NA * 64, TOTB = (size_t)NB * 64;
  float* h = out;
  float* cn = out + TOTA + TOTB;
  for (int rep = 0; rep < 4; ++rep) {
    int row0 = blockIdx.x * 256 + wave * 64 + rep * 16;
    int r = row0 + l15;
    bool ok = r < NA;
    bf16x8 a0 = {0,0,0,0,0,0,0,0}, a1 = a0, a2 = a0;
    if (ok) {
      a0 = *(const bf16x8*)(P2 + (size_t)r * 32 + l4 * 8);
      a1 = *(const bf16x8*)(P  + (size_t)r * 32 + l4 * 8);
      a2 = *(const bf16x8*)(xa + (size_t)r * 32 + l4 * 8);
    }
    f32x4 z[4][4];
    #pragma unroll
    for (int g = 0; g < 4; ++g) {
      #pragma unroll
      for (int nt = 0; nt < 4; ++nt) {
        f32x4 acc = {0.f, 0.f, 0.f, 0.f};
        acc = __builtin_amdgcn_mfma_f32_16x16x32_bf16(a0, *(bf16x8*)&frag[(((g * 3 + 0) * 4 + nt) * 64 + lane) * 8], acc, 0, 0, 0);
        acc = __builtin_amdgcn_mfma_f32_16x16x32_bf16(a1, *(bf16x8*)&frag[(((g * 3 + 1) * 4 + nt) * 64 + lane) * 8], acc, 0, 0, 0);
        acc = __builtin_amdgcn_mfma_f32_16x16x32_bf16(a2, *(bf16x8*)&frag[(((g * 3 + 2) * 4 + nt) * 64 + lane) * 8], acc, 0, 0, 0);
        z[g][nt] = acc;
      }
    }
    float m[4];
    #pragma unroll
    for (int q = 0; q < 4; ++q) {
      int rr = row0 + l4 * 4 + q;
      m[q] = (rr < NA && cnt_aa[rr] > 0) ? 1.f : 0.f;
    }
    #pragma unroll
    for (int nt = 0; nt < 4; ++nt) {
      int col = nt * 16 + l15;
      #pragma unroll
      for (int q = 0; q < 4; ++q) {
        int rr = row0 + l4 * 4 + q;
        if (rr >= NA) continue;
        float zi = z[0][nt][q] + m[q] * Bv[(0 * 5 + 0) * 64 + col] + Bv[(0 * 5 + 1) * 64 + col];
        float zf = z[1][nt][q] + m[q] * Bv[(1 * 5 + 0) * 64 + col] + Bv[(1 * 5 + 1) * 64 + col];
        float zo = z[2][nt][q] + m[q] * Bv[(2 * 5 + 0) * 64 + col] + Bv[(2 * 5 + 1) * 64 + col];
        float zg = z[3][nt][q] + m[q] * Bv[(3 * 5 + 0) * 64 + col] + Bv[(3 * 5 + 1) * 64 + col];
        float ig = fast_sigmoid(zi);
        float fg = fast_sigmoid(zf);
        float og = fast_sigmoid(zo);
        float gg = fast_tanh(zg);
        size_t idx = (size_t)rr * 64 + col;
        float cv = fg * c_a[idx] + ig * gg;
        h[idx] = og * fast_tanh(cv);
        cn[idx] = cv;
      }
    }
  }
}

// ---- final B: 6 MFMA terms x 4 gates + 2 masks + bias + LSTM -> h_b, cn_b ----
__global__ __launch_bounds__(256) void k_finB(
    const bf16* __restrict__ xb, const bf16* __restrict__ Q, const bf16* __restrict__ R,
    const bf16* __restrict__ Q2, const bf16* __restrict__ S, const bf16* __restrict__ T,
    const float* __restrict__ Wf, const float* __restrict__ Bv,
    const int* __restrict__ cnt_ab, const int* __restrict__ cnt_bb,
    const float* __restrict__ c_b, float* __restrict__ out) {
  extern __shared__ short fragB[];
  for (int s = threadIdx.x; s < 24 * 4 * 64; s += 256) {
    int mat = s >> 8, nt = (s >> 6) & 3, ln = s & 63;
    const float* w = Wf + (size_t)(12 + mat) * 2048 + (size_t)((ln >> 4) * 8) * 64 + nt * 16 + (ln & 15);
    bf16x8 v;
    #pragma unroll
    for (int j = 0; j < 8; ++j) v[j] = f2bs(w[j * 64]);
    *(bf16x8*)&fragB[(size_t)s * 8] = v;
  }
  __syncthreads();
  int wave = threadIdx.x >> 6, lane = threadIdx.x & 63;
  int l15 = lane & 15, l4 = lane >> 4;
  const size_t TOTA = (size_t)NA * 64, TOTB = (size_t)NB * 64;
  float* h = out + TOTA;
  float* cn = out + 2 * TOTA + TOTB;
  for (int rep = 0; rep < 4; ++rep) {
    int row0 = blockIdx.x * 256 + wave * 64 + rep * 16;
    int r = row0 + l15;
    bool ok = r < NB;
    bf16x8 a0 = {0,0,0,0,0,0,0,0}, a1 = a0, a2 = a0, a3 = a0, a4 = a0, a5 = a0;
    if (ok) {
      a0 = *(const bf16x8*)(Q2 + (size_t)r * 32 + l4 * 8);
      a1 = *(const bf16x8*)(Q  + (size_t)r * 32 + l4 * 8);
      a2 = *(const bf16x8*)(S  + (size_t)r * 32 + l4 * 8);
      a3 = *(const bf16x8*)(T  + (size_t)r * 32 + l4 * 8);
      a4 = *(const bf16x8*)(R  + (size_t)r * 32 + l4 * 8);
      a5 = *(const bf16x8*)(xb + (size_t)r * 32 + l4 * 8);
    }
    f32x4 z[4][4];
    #pragma unroll
    for (int g = 0; g < 4; ++g) {
      #pragma unroll
      for (int nt = 0; nt < 4; ++nt) {
        f32x4 acc = {0.f, 0.f, 0.f, 0.f};
        acc = __builtin_amdgcn_mfma_f32_16x16x32_bf16(a0, *(bf16x8*)&fragB[(((g * 6 + 0) * 4 + nt) * 64 + lane) * 8], acc, 0, 0, 0);
        acc = __builtin_amdgcn_mfma_f32_16x16x32_bf16(a1, *(bf16x8*)&fragB[(((g * 6 + 1) * 4 + nt) * 64 + lane) * 8], acc, 0, 0, 0);
        acc = __builtin_amdgcn_mfma_f32_16x16x32_bf16(a2, *(bf16x8*)&fragB[(((g * 6 + 2) * 4 + nt) * 64 + lane) * 8], acc, 0, 0, 0);
        acc = __builtin_amdgcn_mfma_f32_16x16x32_bf16(a3, *(bf16x8*)&fragB[(((g * 6 + 3) * 4 + nt) * 64 + lane) * 8], acc, 0, 0, 0);
        acc = __builtin_amdgcn_mfma_f32_16x16x32_bf16(a4, *(bf16x8*)&fragB[(((g * 6 + 4) * 4 + nt) * 64 + lane) * 8], acc, 0, 0, 0);
        acc = __builtin_amdgcn_mfma_f32_16x16x32_bf16(a5, *(bf16x8*)&fragB[(((g * 6 + 5) * 4 + nt) * 64 + lane) * 8], acc, 0, 0, 0);
        z[g][nt] = acc;
      }
    }
    float mab[4], mbb[4];
    #pragma unroll
    for (int q = 0; q < 4; ++q) {
      int rr = row0 + l4 * 4 + q;
      bool okr = rr < NB;
      mab[q] = (okr && cnt_ab[rr] > 0) ? 1.f : 0.f;
      mbb[q] = (okr && cnt_bb[rr] > 0) ? 1.f : 0.f;
    }
    #pragma unroll
    for (int nt = 0; nt < 4; ++nt) {
      int col = nt * 16 + l15;
      #pragma unroll
      for (int q = 0; q < 4; ++q) {
        int rr = row0 + l4 * 4 + q;
        if (rr >= NB) continue;
        float zi = z[0][nt][q] + mab[q] * Bv[(0 * 5 + 2) * 64 + col] + mbb[q] * Bv[(0 * 5 + 3) * 64 + col] + Bv[(0 * 5 + 4) * 64 + col];
        float zf = z[1][nt][q] + mab[q] * Bv[(1 * 5 + 2) * 64 + col] + mbb[q] * Bv[(1 * 5 + 3) * 64 + col] + Bv[(1 * 5 + 4) * 64 + col];
        float zo = z[2][nt][q] + mab[q] * Bv[(2 * 5 + 2) * 64 + col] + mbb[q] * Bv[(2 * 5 + 3) * 64 + col] + Bv[(2 * 5 + 4) * 64 + col];
        float zg = z[3][nt][q] + mab[q] * Bv[(3 * 5 + 2) * 64 + col] + mbb[q] * Bv[(3 * 5 + 3) * 64 + col] + Bv[(3 * 5 + 4) * 64 + col];
        float ig = fast_sigmoid(zi);
        float fg = fast_sigmoid(zf);
        float og = fast_sigmoid(zo);
        float gg = fast_tanh(zg);
        size_t idx = (size_t)rr * 64 + col;
        float cv = fg * c_b[idx] + ig * gg;
        h[idx] = og * fast_tanh(cv);
        cn[idx] = cv;
      }
    }
  }
}

extern "C" void kernel_launch(void* const* d_in, const int* in_sizes, int n_in,
                              void* d_out, int out_size, void* d_ws, size_t ws_size,
                              hipStream_t stream) {
  (void)in_sizes; (void)n_in; (void)out_size; (void)ws_size;
  const float* x_a    = (const float*)d_in[0];
  const float* x_b    = (const float*)d_in[1];
  const float* c_a    = (const float*)d_in[2];
  const float* c_b    = (const float*)d_in[3];
  const float* lin_w  = (const float*)d_in[4];
  const float* lin_b  = (const float*)d_in[5];
  const float* conv_wl = (const float*)d_in[6];
  const float* conv_wr = (const float*)d_in[7];
  const float* conv_cb = (const float*)d_in[8];
  const int* src_aa = (const int*)d_in[9];
  const int* dst_aa = (const int*)d_in[10];
  const int* src_ab = (const int*)d_in[11];
  const int* dst_ab = (const int*)d_in[12];
  const int* src_bb = (const int*)d_in[13];
  const int* dst_bb = (const int*)d_in[14];

  char* ws = (char*)d_ws;
  size_t off = 0;
  auto alloc = [&](size_t bytes) -> char* {
    off = (off + 255) & ~(size_t)255;
    char* p = ws + off;
    off += bytes;
    return p;
  };
  bf16* xab = (bf16*)alloc((size_t)NA * 32 * 2);
  bf16* xbb = (bf16*)alloc((size_t)NB * 32 * 2);
  bf16* P   = (bf16*)alloc((size_t)NA * 32 * 2);
  bf16* P2  = (bf16*)alloc((size_t)NA * 32 * 2);
  bf16* Q   = (bf16*)alloc((size_t)NB * 32 * 2);
  bf16* R   = (bf16*)alloc((size_t)NB * 32 * 2);
  bf16* Q2  = (bf16*)alloc((size_t)NB * 32 * 2);
  bf16* S   = (bf16*)alloc((size_t)NB * 32 * 2);
  bf16* T   = (bf16*)alloc((size_t)NB * 32 * 2);
  float* Wf = (float*)alloc((size_t)36 * 2048 * 4);
  float* Bv = (float*)alloc((size_t)4 * 5 * 64 * 4);
  int* col_aa  = (int*)alloc((size_t)EAA * 4);
  int* col_ab  = (int*)alloc((size_t)EAB * 4);
  int* col_bb  = (int*)alloc((size_t)EBB * 4);
  int* pk_aa   = (int*)alloc((size_t)EAA * 4);
  int* pk_ab   = (int*)alloc((size_t)EAB * 4);
  int* pk_bb   = (int*)alloc((size_t)EBB * 4);
  int* start_aa = (int*)alloc((size_t)NA * 4);
  int* start_ab = (int*)alloc((size_t)NB * 4);
  int* start_bb = (int*)alloc((size_t)NB * 4);
  int* cnt_aa  = (int*)alloc((size_t)NA * 4);
  int* cnt_ab  = (int*)alloc((size_t)NB * 4);
  int* cnt_bb  = (int*)alloc((size_t)NB * 4);
  int* binAA   = (int*)alloc((size_t)BKA * NBKAA * 4);
  int* binAB   = (int*)alloc((size_t)BKB * NBKB * 4);
  int* binBB   = (int*)alloc((size_t)BKB * NBKB * 4);
  int* totAA   = (int*)alloc((size_t)NBKAA * 4);
  int* totAB   = (int*)alloc((size_t)NBKB * 4);
  int* totBB   = (int*)alloc((size_t)NBKB * 4);
  int* bsAA    = (int*)alloc((size_t)(NBKAA + 1) * 4);
  int* bsAB    = (int*)alloc((size_t)(NBKB + 1) * 4);
  int* bsBB    = (int*)alloc((size_t)(NBKB + 1) * 4);

  // independent prep
  k_wfold<<<4, 256, 0, stream>>>(lin_w, conv_wl, conv_wr, conv_cb, lin_b, Wf, Bv);
  k_cast2<<<4688, 256, 0, stream>>>(x_a, x_b, xab, xbb);

  // atomic-free CSR build (counting sort)
  kA_bin<<<BKA + 2 * BKB, 256, 0, stream>>>(dst_aa, dst_ab, dst_bb, binAA, binAB, binBB);
  kB1<<<(NBKAA + 2 * NBKB) / 4, 256, 0, stream>>>(binAA, binAB, binBB, totAA, totAB, totBB);
  kB2<<<3, 256, 0, stream>>>(totAA, totAB, totBB, bsAA, bsAB, bsBB);
  kC_scatter<<<BKA + 2 * BKB, 256, 0, stream>>>(src_aa, dst_aa, src_ab, dst_ab, src_bb, dst_bb,
                                                binAA, binAB, binBB, bsAA, bsAB, bsBB,
                                                pk_aa, pk_ab, pk_bb);
  kD_nodesort<<<NBKAA + 2 * NBKB, 256, 0, stream>>>(pk_aa, pk_ab, pk_bb, bsAA, bsAB, bsBB,
                                                    col_aa, col_ab, col_bb,
                                                    start_aa, cnt_aa, start_ab, cnt_ab,
                                                    start_bb, cnt_bb);

  // aggregation chains (32-ch rows only)
  k_aggP1<<<50000, 256, 0, stream>>>(xab, xbb, P, Q, R,
                                     start_aa, cnt_aa, col_aa,
                                     start_ab, cnt_ab, col_ab,
                                     start_bb, cnt_bb, col_bb);
  k_aggP2<<<50000, 256, 0, stream>>>(P, Q, R, P2, Q2, S, T,
                                     start_aa, cnt_aa, col_aa,
                                     start_ab, cnt_ab, col_ab,
                                     start_bb, cnt_bb, col_bb);

  // fused z-matmul + LSTM
  k_finA<<<391, 256, 0, stream>>>(xab, P, P2, Wf, Bv, cnt_aa, c_a, (float*)d_out);
  k_finB<<<196, 256, 24 * 4 * 64 * 8 * sizeof(short), stream>>>(
      xbb, Q, R, Q2, S, T, Wf, Bv, cnt_ab, cnt_bb, c_b, (float*)d_out);
}

// Round 6
// 384.638 us; speedup vs baseline: 34.3096x; 1.4560x over previous
//
#include <hip/hip_runtime.h>
#include <hip/hip_bf16.h>

#define NA 100000
#define NB 50000
#define EAA 1600000
#define EAB 800000
#define EBB 800000

#define NBKAA 782   // ceil(NA/128)
#define NBKB  391   // ceil(NB/128)
#define BKA 200     // blocks for aa set (8000 edges each)
#define BKB 100     // blocks for ab/bb sets (8000 edges each)
#define DCAP 4096   // kD staging capacity

#define GFA 1563    // ceil(NA/64) fin blocks for A
#define GFB 782     // ceil(NB/64) fin blocks for B

typedef __hip_bfloat16 bf16;
typedef __attribute__((ext_vector_type(8))) short bf16x8;
typedef __attribute__((ext_vector_type(4))) float f32x4;

__device__ __forceinline__ float u2f(unsigned short u) {
  union { unsigned int i; float f; } x; x.i = ((unsigned int)u) << 16; return x.f;
}
__device__ __forceinline__ unsigned short f2u(float f) {
  __hip_bfloat16 h = __float2bfloat16(f);
  return *reinterpret_cast<unsigned short*>(&h);
}
__device__ __forceinline__ short f2bs(float f) {
  __hip_bfloat16 h = __float2bfloat16(f);
  return *reinterpret_cast<short*>(&h);
}
__device__ __forceinline__ float fast_sigmoid(float z) {
  return 1.f / (1.f + __expf(-z));
}
__device__ __forceinline__ float fast_tanh(float z) {
  z = fminf(fmaxf(z, -15.f), 15.f);
  float t = __expf(2.f * z);
  return (t - 1.f) / (t + 1.f);
}

// =============== CSR build: atomic-free counting sort ===============
__global__ __launch_bounds__(256) void kA_bin(
    const int* __restrict__ d1, const int* __restrict__ d2, const int* __restrict__ d3,
    int* __restrict__ binAA, int* __restrict__ binAB, int* __restrict__ binBB) {
  __shared__ int h[1024];
  int blk = blockIdx.x;
  const int* dst; int* out; int e0, nbk;
  if (blk < BKA)            { dst = d1; out = binAA + blk * NBKAA; e0 = blk * 8000; nbk = NBKAA; }
  else if (blk < BKA + BKB) { int k = blk - BKA; dst = d2; out = binAB + k * NBKB; e0 = k * 8000; nbk = NBKB; }
  else                      { int k = blk - BKA - BKB; dst = d3; out = binBB + k * NBKB; e0 = k * 8000; nbk = NBKB; }
  for (int i = threadIdx.x; i < nbk; i += 256) h[i] = 0;
  __syncthreads();
  for (int i = threadIdx.x; i < 8000; i += 256) atomicAdd(&h[dst[e0 + i] >> 7], 1);
  __syncthreads();
  for (int i = threadIdx.x; i < nbk; i += 256) out[i] = h[i];
}

__global__ __launch_bounds__(256) void kB1(
    int* __restrict__ binAA, int* __restrict__ binAB, int* __restrict__ binBB,
    int* __restrict__ totAA, int* __restrict__ totAB, int* __restrict__ totBB) {
  int wave = threadIdx.x >> 6, lane = threadIdx.x & 63;
  int wid = blockIdx.x * 4 + wave;
  int* bin; int* tot; int b, nblk, nbk;
  if (wid < NBKAA)              { bin = binAA; tot = totAA; b = wid; nblk = BKA; nbk = NBKAA; }
  else if (wid < NBKAA + NBKB)  { bin = binAB; tot = totAB; b = wid - NBKAA; nblk = BKB; nbk = NBKB; }
  else                          { bin = binBB; tot = totBB; b = wid - NBKAA - NBKB; nblk = BKB; nbk = NBKB; }
  int C = (nblk + 63) / 64;
  int vals[4]; int s = 0;
  for (int j = 0; j < C; ++j) { int k = lane * C + j; vals[j] = (k < nblk) ? bin[k * nbk + b] : 0; s += vals[j]; }
  int pre = s;
  for (int o = 1; o < 64; o <<= 1) { int x = __shfl_up(pre, o); if (lane >= o) pre += x; }
  int run = pre - s;
  for (int j = 0; j < C; ++j) { int k = lane * C + j; if (k < nblk) { int v = vals[j]; bin[k * nbk + b] = run; run += v; } }
  if (lane == 63) tot[b] = pre;
}

__global__ __launch_bounds__(256) void kB2(
    const int* __restrict__ totAA, const int* __restrict__ totAB, const int* __restrict__ totBB,
    int* __restrict__ bsAA, int* __restrict__ bsAB, int* __restrict__ bsBB) {
  __shared__ int part[256];
  int set = blockIdx.x; const int* tot; int* bs; int nbk;
  if (set == 0)      { tot = totAA; bs = bsAA; nbk = NBKAA; }
  else if (set == 1) { tot = totAB; bs = bsAB; nbk = NBKB; }
  else               { tot = totBB; bs = bsBB; nbk = NBKB; }
  int t = threadIdx.x;
  int v[4]; int s = 0;
  #pragma unroll
  for (int j = 0; j < 4; ++j) { int k = t * 4 + j; v[j] = (k < nbk) ? tot[k] : 0; s += v[j]; }
  part[t] = s;
  __syncthreads();
  for (int o = 1; o < 256; o <<= 1) {
    int x = (t >= o) ? part[t - o] : 0;
    __syncthreads();
    part[t] += x;
    __syncthreads();
  }
  int run = part[t] - s;
  #pragma unroll
  for (int j = 0; j < 4; ++j) { int k = t * 4 + j; if (k < nbk) { bs[k] = run; run += v[j]; } }
  if (t == 255) bs[nbk] = part[255];
}

__global__ __launch_bounds__(256) void kC_scatter(
    const int* __restrict__ s1, const int* __restrict__ d1,
    const int* __restrict__ s2, const int* __restrict__ d2,
    const int* __restrict__ s3, const int* __restrict__ d3,
    const int* __restrict__ binAA, const int* __restrict__ binAB, const int* __restrict__ binBB,
    const int* __restrict__ bsAA, const int* __restrict__ bsAB, const int* __restrict__ bsBB,
    int* __restrict__ pkAA, int* __restrict__ pkAB, int* __restrict__ pkBB) {
  __shared__ int baseL[1024];
  __shared__ int run[1024];
  int blk = blockIdx.x;
  const int* src; const int* dst; const int* bin; const int* bs; int* pk; int e0, nbk, bofs;
  if (blk < BKA)            { src = s1; dst = d1; bin = binAA; bs = bsAA; pk = pkAA; e0 = blk * 8000; nbk = NBKAA; bofs = blk * NBKAA; }
  else if (blk < BKA + BKB) { int k = blk - BKA; src = s2; dst = d2; bin = binAB; bs = bsAB; pk = pkAB; e0 = k * 8000; nbk = NBKB; bofs = k * NBKB; }
  else                      { int k = blk - BKA - BKB; src = s3; dst = d3; bin = binBB; bs = bsBB; pk = pkBB; e0 = k * 8000; nbk = NBKB; bofs = k * NBKB; }
  for (int i = threadIdx.x; i < nbk; i += 256) { baseL[i] = bs[i] + bin[bofs + i]; run[i] = 0; }
  __syncthreads();
  for (int i = threadIdx.x; i < 8000; i += 256) {
    int d = dst[e0 + i];
    int b = d >> 7;
    int off = atomicAdd(&run[b], 1);
    pk[baseL[b] + off] = src[e0 + i] | ((d & 127) << 24);
  }
}

__global__ __launch_bounds__(256) void kD_nodesort(
    const int* __restrict__ pkAA, const int* __restrict__ pkAB, const int* __restrict__ pkBB,
    const int* __restrict__ bsAA, const int* __restrict__ bsAB, const int* __restrict__ bsBB,
    int* __restrict__ colAA, int* __restrict__ colAB, int* __restrict__ colBB,
    int* __restrict__ stAA, int* __restrict__ ctAA,
    int* __restrict__ stAB, int* __restrict__ ctAB,
    int* __restrict__ stBB, int* __restrict__ ctBB) {
  __shared__ int hist[128], nodeOff[129], run[128];
  __shared__ int stage[DCAP];
  int wid = blockIdx.x;
  const int* pk; const int* bs; int* col; int* stn; int* ctn; int b, N;
  if (wid < NBKAA)             { pk = pkAA; bs = bsAA; col = colAA; stn = stAA; ctn = ctAA; b = wid; N = NA; }
  else if (wid < NBKAA + NBKB) { pk = pkAB; bs = bsAB; col = colAB; stn = stAB; ctn = ctAB; b = wid - NBKAA; N = NB; }
  else                         { pk = pkBB; bs = bsBB; col = colBB; stn = stBB; ctn = ctBB; b = wid - NBKAA - NBKB; N = NB; }
  int node0 = b * 128;
  int base = bs[b], cntB = bs[b + 1] - base;
  int t = threadIdx.x;
  if (t < 128) hist[t] = 0;
  __syncthreads();
  for (int i = t; i < cntB; i += 256) atomicAdd(&hist[pk[base + i] >> 24], 1);
  __syncthreads();
  if (t < 64) {
    int v0 = hist[2 * t], v1 = hist[2 * t + 1];
    int s = v0 + v1; int pre = s;
    for (int o = 1; o < 64; o <<= 1) { int x = __shfl_up(pre, o); if (t >= o) pre += x; }
    int ex = pre - s;
    nodeOff[2 * t] = ex; nodeOff[2 * t + 1] = ex + v0;
    if (t == 63) nodeOff[128] = pre;
    run[2 * t] = 0; run[2 * t + 1] = 0;
  }
  __syncthreads();
  if (t < 128) {
    int n = node0 + t;
    if (n < N) { ctn[n] = hist[t]; stn[n] = base + nodeOff[t]; }
  }
  if (cntB <= DCAP) {
    for (int i = t; i < cntB; i += 256) {
      int e = pk[base + i]; int ln = e >> 24;
      int off = atomicAdd(&run[ln], 1);
      stage[nodeOff[ln] + off] = e & 0xFFFFFF;
    }
    __syncthreads();
    for (int i = t; i < cntB; i += 256) col[base + i] = stage[i];
  } else {
    for (int i = t; i < cntB; i += 256) {
      int e = pk[base + i]; int ln = e >> 24;
      int off = atomicAdd(&run[ln], 1);
      col[base + nodeOff[ln] + off] = e & 0xFFFFFF;
    }
  }
}

// ---------------- cast x (f32) -> bf16 ----------------
__global__ __launch_bounds__(256) void k_cast2(const float* __restrict__ xa, const float* __restrict__ xb,
                                               bf16* __restrict__ ya, bf16* __restrict__ yb) {
  int i = blockIdx.x * 256 + threadIdx.x;
  const float* x; bf16* y; int base;
  if (i < 800000)       { x = xa; y = ya; base = i * 4; }
  else if (i < 1200000) { x = xb; y = yb; base = (i - 800000) * 4; }
  else return;
  float4 v = *(const float4*)(x + base);
  ushort4 o; o.x = f2u(v.x); o.y = f2u(v.y); o.z = f2u(v.z); o.w = f2u(v.w);
  *(ushort4*)(y + base) = o;
}

// ---------------- fold the entire linear 2-layer chain into 32x64 mats ----------------
__global__ __launch_bounds__(256) void k_wfold(
    const float* __restrict__ lin_w, const float* __restrict__ wl, const float* __restrict__ wr,
    const float* __restrict__ cbv, const float* __restrict__ lin_b,
    float* __restrict__ Wf, float* __restrict__ Bv) {
  int g = blockIdx.x;
  __shared__ float M1[32][64], M2[32][64], N1[32][64], N2[32][64], N3[32][64];
  int r = threadIdx.x >> 3;
  int c0 = (threadIdx.x & 7) * 8;
  const float* L0 = lin_w + (size_t)(g * 2 + 0) * 2048;
  const float* L1 = lin_w + (size_t)(g * 2 + 1) * 2048;
  const float* wl00 = wl + (size_t)((g * 2 + 0) * 3 + 0) * 4096;
  const float* wl10 = wl + (size_t)((g * 2 + 0) * 3 + 1) * 4096;
  const float* wl20 = wl + (size_t)((g * 2 + 0) * 3 + 2) * 4096;
  const float* wr00 = wr + (size_t)((g * 2 + 0) * 3 + 0) * 4096;
  const float* wr10 = wr + (size_t)((g * 2 + 0) * 3 + 1) * 4096;
  const float* wr20 = wr + (size_t)((g * 2 + 0) * 3 + 2) * 4096;
  const float* wl01 = wl + (size_t)((g * 2 + 1) * 3 + 0) * 4096;
  const float* wl11 = wl + (size_t)((g * 2 + 1) * 3 + 1) * 4096;
  const float* wl21 = wl + (size_t)((g * 2 + 1) * 3 + 2) * 4096;
  const float* wr01 = wr + (size_t)((g * 2 + 1) * 3 + 0) * 4096;
  const float* wr11 = wr + (size_t)((g * 2 + 1) * 3 + 1) * 4096;
  const float* wr21 = wr + (size_t)((g * 2 + 1) * 3 + 2) * 4096;

  {
    float a1[8], a2[8], a3[8], a4[8], a5[8];
    #pragma unroll
    for (int j = 0; j < 8; ++j) { a1[j] = a2[j] = a3[j] = a4[j] = a5[j] = 0.f; }
    for (int k = 0; k < 64; ++k) {
      float l0 = L0[r * 64 + k], l1 = L1[r * 64 + k];
      #pragma unroll
      for (int j = 0; j < 8; ++j) {
        int c = c0 + j;
        a1[j] += l0 * wl00[k * 64 + c];
        a2[j] += l0 * wr00[k * 64 + c];
        a3[j] += l0 * wl10[k * 64 + c];
        a4[j] += l1 * wl20[k * 64 + c];
        a5[j] += l1 * (wr10[k * 64 + c] + wr20[k * 64 + c]);
      }
    }
    #pragma unroll
    for (int j = 0; j < 8; ++j) {
      M1[r][c0 + j] = a1[j]; M2[r][c0 + j] = a2[j]; N1[r][c0 + j] = a3[j];
      N2[r][c0 + j] = a4[j]; N3[r][c0 + j] = a5[j];
    }
  }
  __syncthreads();

  float* WA = Wf + (size_t)(g * 3) * 2048;
  float* WB = Wf + (size_t)(12 + g * 6) * 2048;
  {
    float o0[8], o1[8], o2[8], o3[8], o4[8], o5[8], o6[8], o7[8], o8[8];
    #pragma unroll
    for (int j = 0; j < 8; ++j) { o0[j]=o1[j]=o2[j]=o3[j]=o4[j]=o5[j]=o6[j]=o7[j]=o8[j]=0.f; }
    for (int k = 0; k < 64; ++k) {
      float m1 = M1[r][k], m2 = M2[r][k], n1 = N1[r][k], n2 = N2[r][k], n3 = N3[r][k];
      #pragma unroll
      for (int j = 0; j < 8; ++j) {
        int c = c0 + j;
        float vwl01 = wl01[k * 64 + c], vwr01 = wr01[k * 64 + c];
        float vwl11 = wl11[k * 64 + c], vwl21 = wl21[k * 64 + c];
        float vwrB1 = wr11[k * 64 + c] + wr21[k * 64 + c];
        o0[j] += m1 * vwl01;
        o1[j] += m2 * vwl01 + m1 * vwr01;
        o2[j] += m2 * vwr01;
        o3[j] += m1 * vwl11;
        o4[j] += m2 * vwl11 + n1 * vwrB1;
        o5[j] += n1 * vwl21;
        o6[j] += n2 * vwl21;
        o7[j] += n2 * vwrB1 + n3 * vwl21;
        o8[j] += n3 * vwrB1;
      }
    }
    #pragma unroll
    for (int j = 0; j < 8; ++j) {
      int c = c0 + j;
      WA[0 * 2048 + r * 64 + c] = o0[j];
      WA[1 * 2048 + r * 64 + c] = o1[j];
      WA[2 * 2048 + r * 64 + c] = o2[j];
      WB[0 * 2048 + r * 64 + c] = o3[j];
      WB[1 * 2048 + r * 64 + c] = o4[j];
      WB[2 * 2048 + r * 64 + c] = o5[j];
      WB[3 * 2048 + r * 64 + c] = o6[j];
      WB[4 * 2048 + r * 64 + c] = o7[j];
      WB[5 * 2048 + r * 64 + c] = o8[j];
    }
  }

  if (threadIdx.x < 64) {
    int c = threadIdx.x;
    const float* b00 = cbv + (size_t)((g * 2 + 0) * 3 + 0) * 64;
    const float* b10 = cbv + (size_t)((g * 2 + 0) * 3 + 1) * 64;
    const float* b20 = cbv + (size_t)((g * 2 + 0) * 3 + 2) * 64;
    const float* b01 = cbv + (size_t)((g * 2 + 1) * 3 + 0) * 64;
    const float* b11 = cbv + (size_t)((g * 2 + 1) * 3 + 1) * 64;
    const float* b21 = cbv + (size_t)((g * 2 + 1) * 3 + 2) * 64;
    float s_maa = 0.f, s_ca = 0.f, s_mab = 0.f, s_mbb = 0.f, s_cb = 0.f;
    for (int k = 0; k < 64; ++k) {
      float v0 = b00[k], vb = b10[k] + b20[k];
      s_maa += v0 * wl01[k * 64 + c];
      s_ca  += v0 * wr01[k * 64 + c];
      s_mab += v0 * wl11[k * 64 + c];
      s_mbb += vb * wl21[k * 64 + c];
      s_cb  += vb * (wr11[k * 64 + c] + wr21[k * 64 + c]);
    }
    Bv[(g * 5 + 0) * 64 + c] = s_maa;
    Bv[(g * 5 + 1) * 64 + c] = s_ca + b01[c] + lin_b[(g * 2 + 0) * 64 + c];
    Bv[(g * 5 + 2) * 64 + c] = s_mab;
    Bv[(g * 5 + 3) * 64 + c] = s_mbb;
    Bv[(g * 5 + 4) * 64 + c] = s_cb + b11[c] + b21[c] + lin_b[(g * 2 + 1) * 64 + c];
  }
}

// ---- convert Wf (f32 [36][32][64]) into bf16 MFMA B-fragment layout ----
// Wfrag[((mat*4 + nt)*64 + lane)*8 + j] = bf16(Wf[mat][(lane>>4)*8 + j][nt*16 + (lane&15)])
__global__ __launch_bounds__(256) void k_frag(const float* __restrict__ Wf, bf16* __restrict__ Wfrag) {
  int mat = blockIdx.x;
  int nt = threadIdx.x >> 6, ln = threadIdx.x & 63;
  const float* w = Wf + (size_t)mat * 2048 + (size_t)((ln >> 4) * 8) * 64 + nt * 16 + (ln & 15);
  bf16x8 v;
  #pragma unroll
  for (int j = 0; j < 8; ++j) v[j] = f2bs(w[j * 64]);
  *(bf16x8*)(Wfrag + ((size_t)(mat * 4 + nt) * 64 + ln) * 8) = v;
}

// ---- pass-1 32-ch mean agg: P=A_aa(xa), Q=A_ab(xa), R=A_bb(xb) ----
__global__ __launch_bounds__(256) void k_aggP1(
    const bf16* __restrict__ xa, const bf16* __restrict__ xb,
    bf16* __restrict__ P, bf16* __restrict__ Q, bf16* __restrict__ R,
    const int* __restrict__ st_aa, const int* __restrict__ ct_aa, const int* __restrict__ col_aa,
    const int* __restrict__ st_ab, const int* __restrict__ ct_ab, const int* __restrict__ col_ab,
    const int* __restrict__ st_bb, const int* __restrict__ ct_bb, const int* __restrict__ col_bb) {
  int b = blockIdx.x;
  const bf16* src; bf16* dst; const int* start; const int* cnt; const int* col; int n0;
  if (b < 25000)      { src = xa; dst = P; start = st_aa; cnt = ct_aa; col = col_aa; n0 = b * 4; }
  else if (b < 37500) { src = xa; dst = Q; start = st_ab; cnt = ct_ab; col = col_ab; n0 = (b - 25000) * 4; }
  else                { src = xb; dst = R; start = st_bb; cnt = ct_bb; col = col_bb; n0 = (b - 37500) * 4; }
  int wave = threadIdx.x >> 6, lane = threadIdx.x & 63;
  int n = n0 + wave;
  int e4 = lane >> 4, c16 = lane & 15;
  int st = start[n];
  int deg = cnt[n];
  float s0 = 0.f, s1 = 0.f;
  #pragma unroll 4
  for (int e = e4; e < deg; e += 4) {
    int i = col[st + e];
    ushort2 v = *(const ushort2*)(src + (size_t)i * 32 + c16 * 2);
    s0 += u2f(v.x);
    s1 += u2f(v.y);
  }
  s0 += __shfl_xor(s0, 16); s1 += __shfl_xor(s1, 16);
  s0 += __shfl_xor(s0, 32); s1 += __shfl_xor(s1, 32);
  if (e4 == 0) {
    float inv = 1.f / (float)(deg > 1 ? deg : 1);
    ushort2 o; o.x = f2u(s0 * inv); o.y = f2u(s1 * inv);
    *(ushort2*)(dst + (size_t)n * 32 + c16 * 2) = o;
  }
}

// ---- pass-2: P2=A_aa(P), Q2=A_ab(P), S=A_bb(Q) & T=A_bb(R) fused ----
__global__ __launch_bounds__(256) void k_aggP2(
    const bf16* __restrict__ P, const bf16* __restrict__ Q, const bf16* __restrict__ R,
    bf16* __restrict__ P2, bf16* __restrict__ Q2, bf16* __restrict__ S, bf16* __restrict__ T,
    const int* __restrict__ st_aa, const int* __restrict__ ct_aa, const int* __restrict__ col_aa,
    const int* __restrict__ st_ab, const int* __restrict__ ct_ab, const int* __restrict__ col_ab,
    const int* __restrict__ st_bb, const int* __restrict__ ct_bb, const int* __restrict__ col_bb) {
  int b = blockIdx.x;
  int wave = threadIdx.x >> 6, lane = threadIdx.x & 63;
  int e4 = lane >> 4, c16 = lane & 15;
  if (b < 37500) {
    const bf16* src; bf16* dst; const int* start; const int* cnt; const int* col; int n0;
    if (b < 25000) { src = P; dst = P2; start = st_aa; cnt = ct_aa; col = col_aa; n0 = b * 4; }
    else           { src = P; dst = Q2; start = st_ab; cnt = ct_ab; col = col_ab; n0 = (b - 25000) * 4; }
    int n = n0 + wave;
    int st = start[n];
    int deg = cnt[n];
    float s0 = 0.f, s1 = 0.f;
    #pragma unroll 4
    for (int e = e4; e < deg; e += 4) {
      int i = col[st + e];
      ushort2 v = *(const ushort2*)(src + (size_t)i * 32 + c16 * 2);
      s0 += u2f(v.x);
      s1 += u2f(v.y);
    }
    s0 += __shfl_xor(s0, 16); s1 += __shfl_xor(s1, 16);
    s0 += __shfl_xor(s0, 32); s1 += __shfl_xor(s1, 32);
    if (e4 == 0) {
      float inv = 1.f / (float)(deg > 1 ? deg : 1);
      ushort2 o; o.x = f2u(s0 * inv); o.y = f2u(s1 * inv);
      *(ushort2*)(dst + (size_t)n * 32 + c16 * 2) = o;
    }
  } else {
    int n = (b - 37500) * 4 + wave;
    int st = st_bb[n];
    int deg = ct_bb[n];
    float q0 = 0.f, q1 = 0.f, r0 = 0.f, r1 = 0.f;
    #pragma unroll 2
    for (int e = e4; e < deg; e += 4) {
      int i = col_bb[st + e];
      ushort2 vq = *(const ushort2*)(Q + (size_t)i * 32 + c16 * 2);
      ushort2 vr = *(const ushort2*)(R + (size_t)i * 32 + c16 * 2);
      q0 += u2f(vq.x); q1 += u2f(vq.y);
      r0 += u2f(vr.x); r1 += u2f(vr.y);
    }
    q0 += __shfl_xor(q0, 16); q1 += __shfl_xor(q1, 16);
    r0 += __shfl_xor(r0, 16); r1 += __shfl_xor(r1, 16);
    q0 += __shfl_xor(q0, 32); q1 += __shfl_xor(q1, 32);
    r0 += __shfl_xor(r0, 32); r1 += __shfl_xor(r1, 32);
    if (e4 == 0) {
      float inv = 1.f / (float)(deg > 1 ? deg : 1);
      ushort2 o1v; o1v.x = f2u(q0 * inv); o1v.y = f2u(q1 * inv);
      *(ushort2*)(S + (size_t)n * 32 + c16 * 2) = o1v;
      ushort2 o2v; o2v.x = f2u(r0 * inv); o2v.y = f2u(r1 * inv);
      *(ushort2*)(T + (size_t)n * 32 + c16 * 2) = o2v;
    }
  }
}

// ---- fused final: z-matmul (frags from global/L2) + mask/bias + LSTM, A and B sides ----
__global__ __launch_bounds__(256, 2) void k_fin(
    const bf16* __restrict__ xa, const bf16* __restrict__ P, const bf16* __restrict__ P2,
    const bf16* __restrict__ xb, const bf16* __restrict__ Q, const bf16* __restrict__ R,
    const bf16* __restrict__ Q2, const bf16* __restrict__ S, const bf16* __restrict__ T,
    const bf16* __restrict__ Wfrag, const float* __restrict__ Bv,
    const int* __restrict__ cnt_aa, const int* __restrict__ cnt_ab, const int* __restrict__ cnt_bb,
    const float* __restrict__ c_a, const float* __restrict__ c_b,
    float* __restrict__ out) {
  int blk = blockIdx.x;
  int wave = threadIdx.x >> 6, lane = threadIdx.x & 63;
  int l15 = lane & 15, l4 = lane >> 4;
  const size_t TOTA = (size_t)NA * 64, TOTB = (size_t)NB * 64;
  #define FRAG(mat, nt) (*(const bf16x8*)(Wfrag + ((size_t)((mat) * 4 + (nt)) * 64 + lane) * 8))

  if (blk < GFA) {
    int row0 = (blk * 4 + wave) * 16;
    int r = row0 + l15;
    bool ok = r < NA;
    bf16x8 a0 = {0,0,0,0,0,0,0,0}, a1 = a0, a2 = a0;
    if (ok) {
      a0 = *(const bf16x8*)(P2 + (size_t)r * 32 + l4 * 8);
      a1 = *(const bf16x8*)(P  + (size_t)r * 32 + l4 * 8);
      a2 = *(const bf16x8*)(xa + (size_t)r * 32 + l4 * 8);
    }
    f32x4 z[4][4];
    #pragma unroll
    for (int g = 0; g < 4; ++g) {
      #pragma unroll
      for (int nt = 0; nt < 4; ++nt) {
        f32x4 acc = {0.f, 0.f, 0.f, 0.f};
        acc = __builtin_amdgcn_mfma_f32_16x16x32_bf16(a0, FRAG(g * 3 + 0, nt), acc, 0, 0, 0);
        acc = __builtin_amdgcn_mfma_f32_16x16x32_bf16(a1, FRAG(g * 3 + 1, nt), acc, 0, 0, 0);
        acc = __builtin_amdgcn_mfma_f32_16x16x32_bf16(a2, FRAG(g * 3 + 2, nt), acc, 0, 0, 0);
        z[g][nt] = acc;
      }
    }
    float m[4];
    #pragma unroll
    for (int q = 0; q < 4; ++q) {
      int rr = row0 + l4 * 4 + q;
      m[q] = (rr < NA && cnt_aa[rr] > 0) ? 1.f : 0.f;
    }
    float* h = out;
    float* cn = out + TOTA + TOTB;
    #pragma unroll
    for (int nt = 0; nt < 4; ++nt) {
      int col = nt * 16 + l15;
      #pragma unroll
      for (int q = 0; q < 4; ++q) {
        int rr = row0 + l4 * 4 + q;
        if (rr >= NA) continue;
        float zi = z[0][nt][q] + m[q] * Bv[(0 * 5 + 0) * 64 + col] + Bv[(0 * 5 + 1) * 64 + col];
        float zf = z[1][nt][q] + m[q] * Bv[(1 * 5 + 0) * 64 + col] + Bv[(1 * 5 + 1) * 64 + col];
        float zo = z[2][nt][q] + m[q] * Bv[(2 * 5 + 0) * 64 + col] + Bv[(2 * 5 + 1) * 64 + col];
        float zg = z[3][nt][q] + m[q] * Bv[(3 * 5 + 0) * 64 + col] + Bv[(3 * 5 + 1) * 64 + col];
        float ig = fast_sigmoid(zi);
        float fg = fast_sigmoid(zf);
        float og = fast_sigmoid(zo);
        float gg = fast_tanh(zg);
        size_t idx = (size_t)rr * 64 + col;
        float cv = fg * c_a[idx] + ig * gg;
        h[idx] = og * fast_tanh(cv);
        cn[idx] = cv;
      }
    }
  } else {
    int bb = blk - GFA;
    int row0 = (bb * 4 + wave) * 16;
    int r = row0 + l15;
    bool ok = r < NB;
    bf16x8 a0 = {0,0,0,0,0,0,0,0}, a1 = a0, a2 = a0, a3 = a0, a4 = a0, a5 = a0;
    if (ok) {
      a0 = *(const bf16x8*)(Q2 + (size_t)r * 32 + l4 * 8);
      a1 = *(const bf16x8*)(Q  + (size_t)r * 32 + l4 * 8);
      a2 = *(const bf16x8*)(S  + (size_t)r * 32 + l4 * 8);
      a3 = *(const bf16x8*)(T  + (size_t)r * 32 + l4 * 8);
      a4 = *(const bf16x8*)(R  + (size_t)r * 32 + l4 * 8);
      a5 = *(const bf16x8*)(xb + (size_t)r * 32 + l4 * 8);
    }
    f32x4 z[4][4];
    #pragma unroll
    for (int g = 0; g < 4; ++g) {
      #pragma unroll
      for (int nt = 0; nt < 4; ++nt) {
        int mb = 12 + g * 6;
        f32x4 acc = {0.f, 0.f, 0.f, 0.f};
        acc = __builtin_amdgcn_mfma_f32_16x16x32_bf16(a0, FRAG(mb + 0, nt), acc, 0, 0, 0);
        acc = __builtin_amdgcn_mfma_f32_16x16x32_bf16(a1, FRAG(mb + 1, nt), acc, 0, 0, 0);
        acc = __builtin_amdgcn_mfma_f32_16x16x32_bf16(a2, FRAG(mb + 2, nt), acc, 0, 0, 0);
        acc = __builtin_amdgcn_mfma_f32_16x16x32_bf16(a3, FRAG(mb + 3, nt), acc, 0, 0, 0);
        acc = __builtin_amdgcn_mfma_f32_16x16x32_bf16(a4, FRAG(mb + 4, nt), acc, 0, 0, 0);
        acc = __builtin_amdgcn_mfma_f32_16x16x32_bf16(a5, FRAG(mb + 5, nt), acc, 0, 0, 0);
        z[g][nt] = acc;
      }
    }
    float mab[4], mbb[4];
    #pragma unroll
    for (int q = 0; q < 4; ++q) {
      int rr = row0 + l4 * 4 + q;
      bool okr = rr < NB;
      mab[q] = (okr && cnt_ab[rr] > 0) ? 1.f : 0.f;
      mbb[q] = (okr && cnt_bb[rr] > 0) ? 1.f : 0.f;
    }
    float* h = out + TOTA;
    float* cn = out + 2 * TOTA + TOTB;
    #pragma unroll
    for (int nt = 0; nt < 4; ++nt) {
      int col = nt * 16 + l15;
      #pragma unroll
      for (int q = 0; q < 4; ++q) {
        int rr = row0 + l4 * 4 + q;
        if (rr >= NB) continue;
        float zi = z[0][nt][q] + mab[q] * Bv[(0 * 5 + 2) * 64 + col] + mbb[q] * Bv[(0 * 5 + 3) * 64 + col] + Bv[(0 * 5 + 4) * 64 + col];
        float zf = z[1][nt][q] + mab[q] * Bv[(1 * 5 + 2) * 64 + col] + mbb[q] * Bv[(1 * 5 + 3) * 64 + col] + Bv[(1 * 5 + 4) * 64 + col];
        float zo = z[2][nt][q] + mab[q] * Bv[(2 * 5 + 2) * 64 + col] + mbb[q] * Bv[(2 * 5 + 3) * 64 + col] + Bv[(2 * 5 + 4) * 64 + col];
        float zg = z[3][nt][q] + mab[q] * Bv[(3 * 5 + 2) * 64 + col] + mbb[q] * Bv[(3 * 5 + 3) * 64 + col] + Bv[(3 * 5 + 4) * 64 + col];
        float ig = fast_sigmoid(zi);
        float fg = fast_sigmoid(zf);
        float og = fast_sigmoid(zo);
        float gg = fast_tanh(zg);
        size_t idx = (size_t)rr * 64 + col;
        float cv = fg * c_b[idx] + ig * gg;
        h[idx] = og * fast_tanh(cv);
        cn[idx] = cv;
      }
    }
  }
  #undef FRAG
}

extern "C" void kernel_launch(void* const* d_in, const int* in_sizes, int n_in,
                              void* d_out, int out_size, void* d_ws, size_t ws_size,
                              hipStream_t stream) {
  (void)in_sizes; (void)n_in; (void)out_size; (void)ws_size;
  const float* x_a    = (const float*)d_in[0];
  const float* x_b    = (const float*)d_in[1];
  const float* c_a    = (const float*)d_in[2];
  const float* c_b    = (const float*)d_in[3];
  const float* lin_w  = (const float*)d_in[4];
  const float* lin_b  = (const float*)d_in[5];
  const float* conv_wl = (const float*)d_in[6];
  const float* conv_wr = (const float*)d_in[7];
  const float* conv_cb = (const float*)d_in[8];
  const int* src_aa = (const int*)d_in[9];
  const int* dst_aa = (const int*)d_in[10];
  const int* src_ab = (const int*)d_in[11];
  const int* dst_ab = (const int*)d_in[12];
  const int* src_bb = (const int*)d_in[13];
  const int* dst_bb = (const int*)d_in[14];

  char* ws = (char*)d_ws;
  size_t off = 0;
  auto alloc = [&](size_t bytes) -> char* {
    off = (off + 255) & ~(size_t)255;
    char* p = ws + off;
    off += bytes;
    return p;
  };
  bf16* xab = (bf16*)alloc((size_t)NA * 32 * 2);
  bf16* xbb = (bf16*)alloc((size_t)NB * 32 * 2);
  bf16* P   = (bf16*)alloc((size_t)NA * 32 * 2);
  bf16* P2  = (bf16*)alloc((size_t)NA * 32 * 2);
  bf16* Q   = (bf16*)alloc((size_t)NB * 32 * 2);
  bf16* R   = (bf16*)alloc((size_t)NB * 32 * 2);
  bf16* Q2  = (bf16*)alloc((size_t)NB * 32 * 2);
  bf16* S   = (bf16*)alloc((size_t)NB * 32 * 2);
  bf16* T   = (bf16*)alloc((size_t)NB * 32 * 2);
  float* Wf = (float*)alloc((size_t)36 * 2048 * 4);
  bf16* Wfrag = (bf16*)alloc((size_t)36 * 4 * 64 * 8 * 2);
  float* Bv = (float*)alloc((size_t)4 * 5 * 64 * 4);
  int* col_aa  = (int*)alloc((size_t)EAA * 4);
  int* col_ab  = (int*)alloc((size_t)EAB * 4);
  int* col_bb  = (int*)alloc((size_t)EBB * 4);
  int* pk_aa   = (int*)alloc((size_t)EAA * 4);
  int* pk_ab   = (int*)alloc((size_t)EAB * 4);
  int* pk_bb   = (int*)alloc((size_t)EBB * 4);
  int* start_aa = (int*)alloc((size_t)NA * 4);
  int* start_ab = (int*)alloc((size_t)NB * 4);
  int* start_bb = (int*)alloc((size_t)NB * 4);
  int* cnt_aa  = (int*)alloc((size_t)NA * 4);
  int* cnt_ab  = (int*)alloc((size_t)NB * 4);
  int* cnt_bb  = (int*)alloc((size_t)NB * 4);
  int* binAA   = (int*)alloc((size_t)BKA * NBKAA * 4);
  int* binAB   = (int*)alloc((size_t)BKB * NBKB * 4);
  int* binBB   = (int*)alloc((size_t)BKB * NBKB * 4);
  int* totAA   = (int*)alloc((size_t)NBKAA * 4);
  int* totAB   = (int*)alloc((size_t)NBKB * 4);
  int* totBB   = (int*)alloc((size_t)NBKB * 4);
  int* bsAA    = (int*)alloc((size_t)(NBKAA + 1) * 4);
  int* bsAB    = (int*)alloc((size_t)(NBKB + 1) * 4);
  int* bsBB    = (int*)alloc((size_t)(NBKB + 1) * 4);

  // independent prep
  k_wfold<<<4, 256, 0, stream>>>(lin_w, conv_wl, conv_wr, conv_cb, lin_b, Wf, Bv);
  k_frag<<<36, 256, 0, stream>>>(Wf, Wfrag);
  k_cast2<<<4688, 256, 0, stream>>>(x_a, x_b, xab, xbb);

  // atomic-free CSR build (counting sort)
  kA_bin<<<BKA + 2 * BKB, 256, 0, stream>>>(dst_aa, dst_ab, dst_bb, binAA, binAB, binBB);
  kB1<<<(NBKAA + 2 * NBKB) / 4, 256, 0, stream>>>(binAA, binAB, binBB, totAA, totAB, totBB);
  kB2<<<3, 256, 0, stream>>>(totAA, totAB, totBB, bsAA, bsAB, bsBB);
  kC_scatter<<<BKA + 2 * BKB, 256, 0, stream>>>(src_aa, dst_aa, src_ab, dst_ab, src_bb, dst_bb,
                                                binAA, binAB, binBB, bsAA, bsAB, bsBB,
                                                pk_aa, pk_ab, pk_bb);
  kD_nodesort<<<NBKAA + 2 * NBKB, 256, 0, stream>>>(pk_aa, pk_ab, pk_bb, bsAA, bsAB, bsBB,
                                                    col_aa, col_ab, col_bb,
                                                    start_aa, cnt_aa, start_ab, cnt_ab,
                                                    start_bb, cnt_bb);

  // aggregation chains (32-ch rows only)
  k_aggP1<<<50000, 256, 0, stream>>>(xab, xbb, P, Q, R,
                                     start_aa, cnt_aa, col_aa,
                                     start_ab, cnt_ab, col_ab,
                                     start_bb, cnt_bb, col_bb);
  k_aggP2<<<50000, 256, 0, stream>>>(P, Q, R, P2, Q2, S, T,
                                     start_aa, cnt_aa, col_aa,
                                     start_ab, cnt_ab, col_ab,
                                     start_bb, cnt_bb, col_bb);

  // fused z-matmul + LSTM (A and B in one launch)
  k_fin<<<GFA + GFB, 256, 0, stream>>>(xab, P, P2, xbb, Q, R, Q2, S, T,
                                       Wfrag, Bv, cnt_aa, cnt_ab, cnt_bb,
                                       c_a, c_b, (float*)d_out);
}

// Round 7
// 304.184 us; speedup vs baseline: 43.3843x; 1.2645x over previous
//
#include <hip/hip_runtime.h>
#include <hip/hip_bf16.h>

#define NA 100000
#define NB 50000
#define EAA 1600000
#define EAB 800000
#define EBB 800000

#define NBKAA 782   // ceil(NA/128)
#define NBKB  391   // ceil(NB/128)
#define BKA 200     // blocks for aa set (8000 edges each)
#define BKB 100     // blocks for ab/bb sets (8000 edges each)
#define DCAP 4096   // kD staging capacity

#define GFA 1563    // ceil(NA/64) fin blocks for A
#define GFB 782     // ceil(NB/64) fin blocks for B

typedef __hip_bfloat16 bf16;
typedef __attribute__((ext_vector_type(8))) short bf16x8;
typedef __attribute__((ext_vector_type(4))) float f32x4;

__device__ __forceinline__ float u2f(unsigned short u) {
  union { unsigned int i; float f; } x; x.i = ((unsigned int)u) << 16; return x.f;
}
__device__ __forceinline__ unsigned short f2u(float f) {
  __hip_bfloat16 h = __float2bfloat16(f);
  return *reinterpret_cast<unsigned short*>(&h);
}
__device__ __forceinline__ short f2bs(float f) {
  __hip_bfloat16 h = __float2bfloat16(f);
  return *reinterpret_cast<short*>(&h);
}
__device__ __forceinline__ float fast_sigmoid(float z) {
  return 1.f / (1.f + __expf(-z));
}
__device__ __forceinline__ float fast_tanh(float z) {
  z = fminf(fmaxf(z, -15.f), 15.f);
  float t = __expf(2.f * z);
  return (t - 1.f) / (t + 1.f);
}

// =============== CSR build: atomic-free counting sort ===============
__global__ __launch_bounds__(256) void kA_bin(
    const int* __restrict__ d1, const int* __restrict__ d2, const int* __restrict__ d3,
    int* __restrict__ binAA, int* __restrict__ binAB, int* __restrict__ binBB) {
  __shared__ int h[1024];
  int blk = blockIdx.x;
  const int* dst; int* out; int e0, nbk;
  if (blk < BKA)            { dst = d1; out = binAA + blk * NBKAA; e0 = blk * 8000; nbk = NBKAA; }
  else if (blk < BKA + BKB) { int k = blk - BKA; dst = d2; out = binAB + k * NBKB; e0 = k * 8000; nbk = NBKB; }
  else                      { int k = blk - BKA - BKB; dst = d3; out = binBB + k * NBKB; e0 = k * 8000; nbk = NBKB; }
  for (int i = threadIdx.x; i < nbk; i += 256) h[i] = 0;
  __syncthreads();
  for (int i = threadIdx.x; i < 8000; i += 256) atomicAdd(&h[dst[e0 + i] >> 7], 1);
  __syncthreads();
  for (int i = threadIdx.x; i < nbk; i += 256) out[i] = h[i];
}

__global__ __launch_bounds__(256) void kB1(
    int* __restrict__ binAA, int* __restrict__ binAB, int* __restrict__ binBB,
    int* __restrict__ totAA, int* __restrict__ totAB, int* __restrict__ totBB) {
  int wave = threadIdx.x >> 6, lane = threadIdx.x & 63;
  int wid = blockIdx.x * 4 + wave;
  int* bin; int* tot; int b, nblk, nbk;
  if (wid < NBKAA)              { bin = binAA; tot = totAA; b = wid; nblk = BKA; nbk = NBKAA; }
  else if (wid < NBKAA + NBKB)  { bin = binAB; tot = totAB; b = wid - NBKAA; nblk = BKB; nbk = NBKB; }
  else                          { bin = binBB; tot = totBB; b = wid - NBKAA - NBKB; nblk = BKB; nbk = NBKB; }
  int C = (nblk + 63) / 64;
  int vals[4]; int s = 0;
  for (int j = 0; j < C; ++j) { int k = lane * C + j; vals[j] = (k < nblk) ? bin[k * nbk + b] : 0; s += vals[j]; }
  int pre = s;
  for (int o = 1; o < 64; o <<= 1) { int x = __shfl_up(pre, o); if (lane >= o) pre += x; }
  int run = pre - s;
  for (int j = 0; j < C; ++j) { int k = lane * C + j; if (k < nblk) { int v = vals[j]; bin[k * nbk + b] = run; run += v; } }
  if (lane == 63) tot[b] = pre;
}

__global__ __launch_bounds__(256) void kB2(
    const int* __restrict__ totAA, const int* __restrict__ totAB, const int* __restrict__ totBB,
    int* __restrict__ bsAA, int* __restrict__ bsAB, int* __restrict__ bsBB) {
  __shared__ int part[256];
  int set = blockIdx.x; const int* tot; int* bs; int nbk;
  if (set == 0)      { tot = totAA; bs = bsAA; nbk = NBKAA; }
  else if (set == 1) { tot = totAB; bs = bsAB; nbk = NBKB; }
  else               { tot = totBB; bs = bsBB; nbk = NBKB; }
  int t = threadIdx.x;
  int v[4]; int s = 0;
  #pragma unroll
  for (int j = 0; j < 4; ++j) { int k = t * 4 + j; v[j] = (k < nbk) ? tot[k] : 0; s += v[j]; }
  part[t] = s;
  __syncthreads();
  for (int o = 1; o < 256; o <<= 1) {
    int x = (t >= o) ? part[t - o] : 0;
    __syncthreads();
    part[t] += x;
    __syncthreads();
  }
  int run = part[t] - s;
  #pragma unroll
  for (int j = 0; j < 4; ++j) { int k = t * 4 + j; if (k < nbk) { bs[k] = run; run += v[j]; } }
  if (t == 255) bs[nbk] = part[255];
}

__global__ __launch_bounds__(256) void kC_scatter(
    const int* __restrict__ s1, const int* __restrict__ d1,
    const int* __restrict__ s2, const int* __restrict__ d2,
    const int* __restrict__ s3, const int* __restrict__ d3,
    const int* __restrict__ binAA, const int* __restrict__ binAB, const int* __restrict__ binBB,
    const int* __restrict__ bsAA, const int* __restrict__ bsAB, const int* __restrict__ bsBB,
    int* __restrict__ pkAA, int* __restrict__ pkAB, int* __restrict__ pkBB) {
  __shared__ int baseL[1024];
  __shared__ int run[1024];
  int blk = blockIdx.x;
  const int* src; const int* dst; const int* bin; const int* bs; int* pk; int e0, nbk, bofs;
  if (blk < BKA)            { src = s1; dst = d1; bin = binAA; bs = bsAA; pk = pkAA; e0 = blk * 8000; nbk = NBKAA; bofs = blk * NBKAA; }
  else if (blk < BKA + BKB) { int k = blk - BKA; src = s2; dst = d2; bin = binAB; bs = bsAB; pk = pkAB; e0 = k * 8000; nbk = NBKB; bofs = k * NBKB; }
  else                      { int k = blk - BKA - BKB; src = s3; dst = d3; bin = binBB; bs = bsBB; pk = pkBB; e0 = k * 8000; nbk = NBKB; bofs = k * NBKB; }
  for (int i = threadIdx.x; i < nbk; i += 256) { baseL[i] = bs[i] + bin[bofs + i]; run[i] = 0; }
  __syncthreads();
  for (int i = threadIdx.x; i < 8000; i += 256) {
    int d = dst[e0 + i];
    int b = d >> 7;
    int off = atomicAdd(&run[b], 1);
    pk[baseL[b] + off] = src[e0 + i] | ((d & 127) << 24);
  }
}

__global__ __launch_bounds__(256) void kD_nodesort(
    const int* __restrict__ pkAA, const int* __restrict__ pkAB, const int* __restrict__ pkBB,
    const int* __restrict__ bsAA, const int* __restrict__ bsAB, const int* __restrict__ bsBB,
    int* __restrict__ colAA, int* __restrict__ colAB, int* __restrict__ colBB,
    int* __restrict__ stAA, int* __restrict__ ctAA,
    int* __restrict__ stAB, int* __restrict__ ctAB,
    int* __restrict__ stBB, int* __restrict__ ctBB) {
  __shared__ int hist[128], nodeOff[129], run[128];
  __shared__ int stage[DCAP];
  int wid = blockIdx.x;
  const int* pk; const int* bs; int* col; int* stn; int* ctn; int b, N;
  if (wid < NBKAA)             { pk = pkAA; bs = bsAA; col = colAA; stn = stAA; ctn = ctAA; b = wid; N = NA; }
  else if (wid < NBKAA + NBKB) { pk = pkAB; bs = bsAB; col = colAB; stn = stAB; ctn = ctAB; b = wid - NBKAA; N = NB; }
  else                         { pk = pkBB; bs = bsBB; col = colBB; stn = stBB; ctn = ctBB; b = wid - NBKAA - NBKB; N = NB; }
  int node0 = b * 128;
  int base = bs[b], cntB = bs[b + 1] - base;
  int t = threadIdx.x;
  if (t < 128) hist[t] = 0;
  __syncthreads();
  for (int i = t; i < cntB; i += 256) atomicAdd(&hist[pk[base + i] >> 24], 1);
  __syncthreads();
  if (t < 64) {
    int v0 = hist[2 * t], v1 = hist[2 * t + 1];
    int s = v0 + v1; int pre = s;
    for (int o = 1; o < 64; o <<= 1) { int x = __shfl_up(pre, o); if (t >= o) pre += x; }
    int ex = pre - s;
    nodeOff[2 * t] = ex; nodeOff[2 * t + 1] = ex + v0;
    if (t == 63) nodeOff[128] = pre;
    run[2 * t] = 0; run[2 * t + 1] = 0;
  }
  __syncthreads();
  if (t < 128) {
    int n = node0 + t;
    if (n < N) { ctn[n] = hist[t]; stn[n] = base + nodeOff[t]; }
  }
  if (cntB <= DCAP) {
    for (int i = t; i < cntB; i += 256) {
      int e = pk[base + i]; int ln = e >> 24;
      int off = atomicAdd(&run[ln], 1);
      stage[nodeOff[ln] + off] = e & 0xFFFFFF;
    }
    __syncthreads();
    for (int i = t; i < cntB; i += 256) col[base + i] = stage[i];
  } else {
    for (int i = t; i < cntB; i += 256) {
      int e = pk[base + i]; int ln = e >> 24;
      int off = atomicAdd(&run[ln], 1);
      col[base + nodeOff[ln] + off] = e & 0xFFFFFF;
    }
  }
}

// ---------------- cast x (f32) -> bf16 ----------------
__global__ __launch_bounds__(256) void k_cast2(const float* __restrict__ xa, const float* __restrict__ xb,
                                               bf16* __restrict__ ya, bf16* __restrict__ yb) {
  int i = blockIdx.x * 256 + threadIdx.x;
  const float* x; bf16* y; int base;
  if (i < 800000)       { x = xa; y = ya; base = i * 4; }
  else if (i < 1200000) { x = xb; y = yb; base = (i - 800000) * 4; }
  else return;
  float4 v = *(const float4*)(x + base);
  ushort4 o; o.x = f2u(v.x); o.y = f2u(v.y); o.z = f2u(v.z); o.w = f2u(v.w);
  *(ushort4*)(y + base) = o;
}

// ---- kW1: phase-1 intermediates M[term][g] = L @ R  (20 blocks) ----
// terms: 0:M1=L0@wl00  1:M2=L0@wr00  2:N1=L0@wl10  3:N2=L1@wl20  4:N3=L1@(wr10+wr20)
__global__ __launch_bounds__(256) void kW1(
    const float* __restrict__ lin_w, const float* __restrict__ wl, const float* __restrict__ wr,
    float* __restrict__ Mbuf) {
  __shared__ float Ls[32][64];
  __shared__ float Rs[64][64];
  int id = blockIdx.x, term = id >> 2, g = id & 3;
  const float* L = lin_w + ((size_t)g * 2 + (term >= 3 ? 1 : 0)) * 2048;
  const float* R1; const float* R2 = nullptr;
  switch (term) {
    case 0: R1 = wl + ((size_t)(g * 2) * 3 + 0) * 4096; break;
    case 1: R1 = wr + ((size_t)(g * 2) * 3 + 0) * 4096; break;
    case 2: R1 = wl + ((size_t)(g * 2) * 3 + 1) * 4096; break;
    case 3: R1 = wl + ((size_t)(g * 2) * 3 + 2) * 4096; break;
    default: R1 = wr + ((size_t)(g * 2) * 3 + 1) * 4096; R2 = wr + ((size_t)(g * 2) * 3 + 2) * 4096; break;
  }
  for (int i = threadIdx.x; i < 2048; i += 256) Ls[i >> 6][i & 63] = L[i];
  for (int i = threadIdx.x; i < 4096; i += 256) Rs[i >> 6][i & 63] = R2 ? (R1[i] + R2[i]) : R1[i];
  __syncthreads();
  int c = threadIdx.x & 63, rq = threadIdx.x >> 6;
  float acc[8] = {0, 0, 0, 0, 0, 0, 0, 0};
  for (int k = 0; k < 64; ++k) {
    float rv = Rs[k][c];
    #pragma unroll
    for (int i = 0; i < 8; ++i) acc[i] += Ls[rq * 8 + i][k] * rv;
  }
  #pragma unroll
  for (int i = 0; i < 8; ++i)
    Mbuf[(size_t)(term * 4 + g) * 2048 + (rq * 8 + i) * 64 + c] = acc[i];
}

// ---- kW2: 36 output mats (written directly as bf16 MFMA B-fragments) + 4 bias blocks ----
// A mats (blk<12, mat=g*3+m): m0: M1@wl01 | m1: M2@wl01 + M1@wr01 | m2: M2@wr01
// B mats (blk=12+g*6+m): m0: M1@wl11 | m1: M2@wl11 + N1@wrB | m2: N1@wl21
//                        m3: N2@wl21 | m4: N2@wrB + N3@wl21  | m5: N3@wrB     (wrB = wr11+wr21)
__global__ __launch_bounds__(256) void kW2(
    const float* __restrict__ Mbuf, const float* __restrict__ wl, const float* __restrict__ wr,
    const float* __restrict__ cbv, const float* __restrict__ lin_b,
    bf16* __restrict__ Wfrag, float* __restrict__ Bv) {
  __shared__ float Ps[2][32][65];
  __shared__ float Ws[2][64][64];
  int blk = blockIdx.x;
  if (blk >= 36) {
    // bias fold for gate g
    int g = blk - 36;
    if (threadIdx.x < 64) {
      int c = threadIdx.x;
      const float* b00 = cbv + (size_t)((g * 2 + 0) * 3 + 0) * 64;
      const float* b10 = cbv + (size_t)((g * 2 + 0) * 3 + 1) * 64;
      const float* b20 = cbv + (size_t)((g * 2 + 0) * 3 + 2) * 64;
      const float* b01 = cbv + (size_t)((g * 2 + 1) * 3 + 0) * 64;
      const float* b11 = cbv + (size_t)((g * 2 + 1) * 3 + 1) * 64;
      const float* b21 = cbv + (size_t)((g * 2 + 1) * 3 + 2) * 64;
      const float* wl01 = wl + (size_t)((g * 2 + 1) * 3 + 0) * 4096;
      const float* wl11 = wl + (size_t)((g * 2 + 1) * 3 + 1) * 4096;
      const float* wl21 = wl + (size_t)((g * 2 + 1) * 3 + 2) * 4096;
      const float* wr01 = wr + (size_t)((g * 2 + 1) * 3 + 0) * 4096;
      const float* wr11 = wr + (size_t)((g * 2 + 1) * 3 + 1) * 4096;
      const float* wr21 = wr + (size_t)((g * 2 + 1) * 3 + 2) * 4096;
      float s_maa = 0.f, s_ca = 0.f, s_mab = 0.f, s_mbb = 0.f, s_cb = 0.f;
      for (int k = 0; k < 64; ++k) {
        float v0 = b00[k], vb = b10[k] + b20[k];
        s_maa += v0 * wl01[k * 64 + c];
        s_ca  += v0 * wr01[k * 64 + c];
        s_mab += v0 * wl11[k * 64 + c];
        s_mbb += vb * wl21[k * 64 + c];
        s_cb  += vb * (wr11[k * 64 + c] + wr21[k * 64 + c]);
      }
      Bv[(g * 5 + 0) * 64 + c] = s_maa;
      Bv[(g * 5 + 1) * 64 + c] = s_ca + b01[c] + lin_b[(g * 2 + 0) * 64 + c];
      Bv[(g * 5 + 2) * 64 + c] = s_mab;
      Bv[(g * 5 + 3) * 64 + c] = s_mbb;
      Bv[(g * 5 + 4) * 64 + c] = s_cb + b11[c] + b21[c] + lin_b[(g * 2 + 1) * 64 + c];
    }
    return;
  }
  int mat = blk, g, m;
  if (blk < 12) { g = blk / 3; m = blk % 3; }
  else          { g = (blk - 12) / 6; m = (blk - 12) % 6 + 3; }   // m 3..8 for B-side
  const float* wl01 = wl + (size_t)((g * 2 + 1) * 3 + 0) * 4096;
  const float* wl11 = wl + (size_t)((g * 2 + 1) * 3 + 1) * 4096;
  const float* wl21 = wl + (size_t)((g * 2 + 1) * 3 + 2) * 4096;
  const float* wr01 = wr + (size_t)((g * 2 + 1) * 3 + 0) * 4096;
  const float* wr11 = wr + (size_t)((g * 2 + 1) * 3 + 1) * 4096;
  const float* wr21 = wr + (size_t)((g * 2 + 1) * 3 + 2) * 4096;
  // product table: Pterm (0..4 = M1,M2,N1,N2,N3), W pointer (w2 set => pairwise sum)
  int   p1t, p2t = -1;
  const float *w1a = nullptr, *w1b = nullptr, *w2a = nullptr, *w2b = nullptr;
  switch (m) {
    case 0: p1t = 0; w1a = wl01; break;                                   // WA2
    case 1: p1t = 1; w1a = wl01; p2t = 0; w2a = wr01; break;              // WA1
    case 2: p1t = 1; w1a = wr01; break;                                   // WA0
    case 3: p1t = 0; w1a = wl11; break;                                   // WQ2
    case 4: p1t = 1; w1a = wl11; p2t = 2; w2a = wr11; w2b = wr21; break;  // WQ
    case 5: p1t = 2; w1a = wl21; break;                                   // WS
    case 6: p1t = 3; w1a = wl21; break;                                   // WT
    case 7: p1t = 3; w1a = wr11; w1b = wr21; p2t = 4; w2a = wl21; break;  // WR
    default: p1t = 4; w1a = wr11; w1b = wr21; break;                      // WX
  }
  int nprod = (p2t >= 0) ? 2 : 1;
  for (int i = threadIdx.x; i < 2048; i += 256) Ps[0][i >> 6][i & 63] = Mbuf[(size_t)(p1t * 4 + g) * 2048 + i];
  for (int i = threadIdx.x; i < 4096; i += 256) Ws[0][i >> 6][i & 63] = w1b ? (w1a[i] + w1b[i]) : w1a[i];
  if (nprod == 2) {
    for (int i = threadIdx.x; i < 2048; i += 256) Ps[1][i >> 6][i & 63] = Mbuf[(size_t)(p2t * 4 + g) * 2048 + i];
    for (int i = threadIdx.x; i < 4096; i += 256) Ws[1][i >> 6][i & 63] = w2b ? (w2a[i] + w2b[i]) : w2a[i];
  }
  __syncthreads();
  int nt = threadIdx.x >> 6, lane = threadIdx.x & 63;
  int c = nt * 16 + (lane & 15), kb = (lane >> 4) * 8;
  float acc[8] = {0, 0, 0, 0, 0, 0, 0, 0};
  for (int k = 0; k < 64; ++k) {
    float w1v = Ws[0][k][c];
    #pragma unroll
    for (int j = 0; j < 8; ++j) acc[j] += Ps[0][kb + j][k] * w1v;
  }
  if (nprod == 2) {
    for (int k = 0; k < 64; ++k) {
      float w2v = Ws[1][k][c];
      #pragma unroll
      for (int j = 0; j < 8; ++j) acc[j] += Ps[1][kb + j][k] * w2v;
    }
  }
  bf16x8 v;
  #pragma unroll
  for (int j = 0; j < 8; ++j) v[j] = f2bs(acc[j]);
  *(bf16x8*)(Wfrag + ((size_t)(mat * 4 + nt) * 64 + lane) * 8) = v;
}

// ---- pass-1 32-ch mean agg: P=A_aa(xa), Q=A_ab(xa), R=A_bb(xb); 8 edge-slots/wave ----
__global__ __launch_bounds__(256) void k_aggP1(
    const bf16* __restrict__ xa, const bf16* __restrict__ xb,
    bf16* __restrict__ P, bf16* __restrict__ Q, bf16* __restrict__ R,
    const int* __restrict__ st_aa, const int* __restrict__ ct_aa, const int* __restrict__ col_aa,
    const int* __restrict__ st_ab, const int* __restrict__ ct_ab, const int* __restrict__ col_ab,
    const int* __restrict__ st_bb, const int* __restrict__ ct_bb, const int* __restrict__ col_bb) {
  int b = blockIdx.x;
  const bf16* src; bf16* dst; const int* start; const int* cnt; const int* col; int n0;
  if (b < 25000)      { src = xa; dst = P; start = st_aa; cnt = ct_aa; col = col_aa; n0 = b * 4; }
  else if (b < 37500) { src = xa; dst = Q; start = st_ab; cnt = ct_ab; col = col_ab; n0 = (b - 25000) * 4; }
  else                { src = xb; dst = R; start = st_bb; cnt = ct_bb; col = col_bb; n0 = (b - 37500) * 4; }
  int wave = threadIdx.x >> 6, lane = threadIdx.x & 63;
  int n = n0 + wave;
  int e8 = lane >> 3, c8 = lane & 7;
  int st = start[n];
  int deg = cnt[n];
  float s0 = 0.f, s1 = 0.f, s2 = 0.f, s3 = 0.f;
  #pragma unroll 2
  for (int e = e8; e < deg; e += 8) {
    int i = col[st + e];
    ushort4 v = *(const ushort4*)(src + (size_t)i * 32 + c8 * 4);
    s0 += u2f(v.x); s1 += u2f(v.y); s2 += u2f(v.z); s3 += u2f(v.w);
  }
  s0 += __shfl_xor(s0, 8);  s1 += __shfl_xor(s1, 8);  s2 += __shfl_xor(s2, 8);  s3 += __shfl_xor(s3, 8);
  s0 += __shfl_xor(s0, 16); s1 += __shfl_xor(s1, 16); s2 += __shfl_xor(s2, 16); s3 += __shfl_xor(s3, 16);
  s0 += __shfl_xor(s0, 32); s1 += __shfl_xor(s1, 32); s2 += __shfl_xor(s2, 32); s3 += __shfl_xor(s3, 32);
  if (e8 == 0) {
    float inv = 1.f / (float)(deg > 1 ? deg : 1);
    ushort4 o; o.x = f2u(s0 * inv); o.y = f2u(s1 * inv); o.z = f2u(s2 * inv); o.w = f2u(s3 * inv);
    *(ushort4*)(dst + (size_t)n * 32 + c8 * 4) = o;
  }
}

// ---- pass-2: P2=A_aa(P), Q2=A_ab(P), S=A_bb(Q) & T=A_bb(R) fused ----
__global__ __launch_bounds__(256) void k_aggP2(
    const bf16* __restrict__ P, const bf16* __restrict__ Q, const bf16* __restrict__ R,
    bf16* __restrict__ P2, bf16* __restrict__ Q2, bf16* __restrict__ S, bf16* __restrict__ T,
    const int* __restrict__ st_aa, const int* __restrict__ ct_aa, const int* __restrict__ col_aa,
    const int* __restrict__ st_ab, const int* __restrict__ ct_ab, const int* __restrict__ col_ab,
    const int* __restrict__ st_bb, const int* __restrict__ ct_bb, const int* __restrict__ col_bb) {
  int b = blockIdx.x;
  int wave = threadIdx.x >> 6, lane = threadIdx.x & 63;
  int e8 = lane >> 3, c8 = lane & 7;
  if (b < 37500) {
    const bf16* src; bf16* dst; const int* start; const int* cnt; const int* col; int n0;
    if (b < 25000) { src = P; dst = P2; start = st_aa; cnt = ct_aa; col = col_aa; n0 = b * 4; }
    else           { src = P; dst = Q2; start = st_ab; cnt = ct_ab; col = col_ab; n0 = (b - 25000) * 4; }
    int n = n0 + wave;
    int st = start[n];
    int deg = cnt[n];
    float s0 = 0.f, s1 = 0.f, s2 = 0.f, s3 = 0.f;
    #pragma unroll 2
    for (int e = e8; e < deg; e += 8) {
      int i = col[st + e];
      ushort4 v = *(const ushort4*)(src + (size_t)i * 32 + c8 * 4);
      s0 += u2f(v.x); s1 += u2f(v.y); s2 += u2f(v.z); s3 += u2f(v.w);
    }
    s0 += __shfl_xor(s0, 8);  s1 += __shfl_xor(s1, 8);  s2 += __shfl_xor(s2, 8);  s3 += __shfl_xor(s3, 8);
    s0 += __shfl_xor(s0, 16); s1 += __shfl_xor(s1, 16); s2 += __shfl_xor(s2, 16); s3 += __shfl_xor(s3, 16);
    s0 += __shfl_xor(s0, 32); s1 += __shfl_xor(s1, 32); s2 += __shfl_xor(s2, 32); s3 += __shfl_xor(s3, 32);
    if (e8 == 0) {
      float inv = 1.f / (float)(deg > 1 ? deg : 1);
      ushort4 o; o.x = f2u(s0 * inv); o.y = f2u(s1 * inv); o.z = f2u(s2 * inv); o.w = f2u(s3 * inv);
      *(ushort4*)(dst + (size_t)n * 32 + c8 * 4) = o;
    }
  } else {
    int n = (b - 37500) * 4 + wave;
    int st = st_bb[n];
    int deg = ct_bb[n];
    float q0 = 0.f, q1 = 0.f, q2 = 0.f, q3 = 0.f;
    float r0 = 0.f, r1 = 0.f, r2 = 0.f, r3 = 0.f;
    for (int e = e8; e < deg; e += 8) {
      int i = col_bb[st + e];
      ushort4 vq = *(const ushort4*)(Q + (size_t)i * 32 + c8 * 4);
      ushort4 vr = *(const ushort4*)(R + (size_t)i * 32 + c8 * 4);
      q0 += u2f(vq.x); q1 += u2f(vq.y); q2 += u2f(vq.z); q3 += u2f(vq.w);
      r0 += u2f(vr.x); r1 += u2f(vr.y); r2 += u2f(vr.z); r3 += u2f(vr.w);
    }
    q0 += __shfl_xor(q0, 8);  q1 += __shfl_xor(q1, 8);  q2 += __shfl_xor(q2, 8);  q3 += __shfl_xor(q3, 8);
    r0 += __shfl_xor(r0, 8);  r1 += __shfl_xor(r1, 8);  r2 += __shfl_xor(r2, 8);  r3 += __shfl_xor(r3, 8);
    q0 += __shfl_xor(q0, 16); q1 += __shfl_xor(q1, 16); q2 += __shfl_xor(q2, 16); q3 += __shfl_xor(q3, 16);
    r0 += __shfl_xor(r0, 16); r1 += __shfl_xor(r1, 16); r2 += __shfl_xor(r2, 16); r3 += __shfl_xor(r3, 16);
    q0 += __shfl_xor(q0, 32); q1 += __shfl_xor(q1, 32); q2 += __shfl_xor(q2, 32); q3 += __shfl_xor(q3, 32);
    r0 += __shfl_xor(r0, 32); r1 += __shfl_xor(r1, 32); r2 += __shfl_xor(r2, 32); r3 += __shfl_xor(r3, 32);
    if (e8 == 0) {
      float inv = 1.f / (float)(deg > 1 ? deg : 1);
      ushort4 o1v; o1v.x = f2u(q0 * inv); o1v.y = f2u(q1 * inv); o1v.z = f2u(q2 * inv); o1v.w = f2u(q3 * inv);
      *(ushort4*)(S + (size_t)n * 32 + c8 * 4) = o1v;
      ushort4 o2v; o2v.x = f2u(r0 * inv); o2v.y = f2u(r1 * inv); o2v.z = f2u(r2 * inv); o2v.w = f2u(r3 * inv);
      *(ushort4*)(T + (size_t)n * 32 + c8 * 4) = o2v;
    }
  }
}

// ---- fused final: z-matmul (frags from global/L2) + mask/bias + LSTM, A and B sides ----
__global__ __launch_bounds__(256, 2) void k_fin(
    const bf16* __restrict__ xa, const bf16* __restrict__ P, const bf16* __restrict__ P2,
    const bf16* __restrict__ xb, const bf16* __restrict__ Q, const bf16* __restrict__ R,
    const bf16* __restrict__ Q2, const bf16* __restrict__ S, const bf16* __restrict__ T,
    const bf16* __restrict__ Wfrag, const float* __restrict__ Bv,
    const int* __restrict__ cnt_aa, const int* __restrict__ cnt_ab, const int* __restrict__ cnt_bb,
    const float* __restrict__ c_a, const float* __restrict__ c_b,
    float* __restrict__ out) {
  int blk = blockIdx.x;
  int wave = threadIdx.x >> 6, lane = threadIdx.x & 63;
  int l15 = lane & 15, l4 = lane >> 4;
  const size_t TOTA = (size_t)NA * 64, TOTB = (size_t)NB * 64;
  #define FRAG(mat, nt) (*(const bf16x8*)(Wfrag + ((size_t)((mat) * 4 + (nt)) * 64 + lane) * 8))

  if (blk < GFA) {
    int row0 = (blk * 4 + wave) * 16;
    int r = row0 + l15;
    bool ok = r < NA;
    bf16x8 a0 = {0,0,0,0,0,0,0,0}, a1 = a0, a2 = a0;
    if (ok) {
      a0 = *(const bf16x8*)(P2 + (size_t)r * 32 + l4 * 8);
      a1 = *(const bf16x8*)(P  + (size_t)r * 32 + l4 * 8);
      a2 = *(const bf16x8*)(xa + (size_t)r * 32 + l4 * 8);
    }
    f32x4 z[4][4];
    #pragma unroll
    for (int g = 0; g < 4; ++g) {
      #pragma unroll
      for (int nt = 0; nt < 4; ++nt) {
        f32x4 acc = {0.f, 0.f, 0.f, 0.f};
        acc = __builtin_amdgcn_mfma_f32_16x16x32_bf16(a0, FRAG(g * 3 + 0, nt), acc, 0, 0, 0);
        acc = __builtin_amdgcn_mfma_f32_16x16x32_bf16(a1, FRAG(g * 3 + 1, nt), acc, 0, 0, 0);
        acc = __builtin_amdgcn_mfma_f32_16x16x32_bf16(a2, FRAG(g * 3 + 2, nt), acc, 0, 0, 0);
        z[g][nt] = acc;
      }
    }
    float m[4];
    #pragma unroll
    for (int q = 0; q < 4; ++q) {
      int rr = row0 + l4 * 4 + q;
      m[q] = (rr < NA && cnt_aa[rr] > 0) ? 1.f : 0.f;
    }
    float* h = out;
    float* cn = out + TOTA + TOTB;
    #pragma unroll
    for (int nt = 0; nt < 4; ++nt) {
      int col = nt * 16 + l15;
      #pragma unroll
      for (int q = 0; q < 4; ++q) {
        int rr = row0 + l4 * 4 + q;
        if (rr >= NA) continue;
        float zi = z[0][nt][q] + m[q] * Bv[(0 * 5 + 0) * 64 + col] + Bv[(0 * 5 + 1) * 64 + col];
        float zf = z[1][nt][q] + m[q] * Bv[(1 * 5 + 0) * 64 + col] + Bv[(1 * 5 + 1) * 64 + col];
        float zo = z[2][nt][q] + m[q] * Bv[(2 * 5 + 0) * 64 + col] + Bv[(2 * 5 + 1) * 64 + col];
        float zg = z[3][nt][q] + m[q] * Bv[(3 * 5 + 0) * 64 + col] + Bv[(3 * 5 + 1) * 64 + col];
        float ig = fast_sigmoid(zi);
        float fg = fast_sigmoid(zf);
        float og = fast_sigmoid(zo);
        float gg = fast_tanh(zg);
        size_t idx = (size_t)rr * 64 + col;
        float cv = fg * c_a[idx] + ig * gg;
        h[idx] = og * fast_tanh(cv);
        cn[idx] = cv;
      }
    }
  } else {
    int bb = blk - GFA;
    int row0 = (bb * 4 + wave) * 16;
    int r = row0 + l15;
    bool ok = r < NB;
    bf16x8 a0 = {0,0,0,0,0,0,0,0}, a1 = a0, a2 = a0, a3 = a0, a4 = a0, a5 = a0;
    if (ok) {
      a0 = *(const bf16x8*)(Q2 + (size_t)r * 32 + l4 * 8);
      a1 = *(const bf16x8*)(Q  + (size_t)r * 32 + l4 * 8);
      a2 = *(const bf16x8*)(S  + (size_t)r * 32 + l4 * 8);
      a3 = *(const bf16x8*)(T  + (size_t)r * 32 + l4 * 8);
      a4 = *(const bf16x8*)(R  + (size_t)r * 32 + l4 * 8);
      a5 = *(const bf16x8*)(xb + (size_t)r * 32 + l4 * 8);
    }
    f32x4 z[4][4];
    #pragma unroll
    for (int g = 0; g < 4; ++g) {
      #pragma unroll
      for (int nt = 0; nt < 4; ++nt) {
        int mb = 12 + g * 6;
        f32x4 acc = {0.f, 0.f, 0.f, 0.f};
        acc = __builtin_amdgcn_mfma_f32_16x16x32_bf16(a0, FRAG(mb + 0, nt), acc, 0, 0, 0);
        acc = __builtin_amdgcn_mfma_f32_16x16x32_bf16(a1, FRAG(mb + 1, nt), acc, 0, 0, 0);
        acc = __builtin_amdgcn_mfma_f32_16x16x32_bf16(a2, FRAG(mb + 2, nt), acc, 0, 0, 0);
        acc = __builtin_amdgcn_mfma_f32_16x16x32_bf16(a3, FRAG(mb + 3, nt), acc, 0, 0, 0);
        acc = __builtin_amdgcn_mfma_f32_16x16x32_bf16(a4, FRAG(mb + 4, nt), acc, 0, 0, 0);
        acc = __builtin_amdgcn_mfma_f32_16x16x32_bf16(a5, FRAG(mb + 5, nt), acc, 0, 0, 0);
        z[g][nt] = acc;
      }
    }
    float mab[4], mbb[4];
    #pragma unroll
    for (int q = 0; q < 4; ++q) {
      int rr = row0 + l4 * 4 + q;
      bool okr = rr < NB;
      mab[q] = (okr && cnt_ab[rr] > 0) ? 1.f : 0.f;
      mbb[q] = (okr && cnt_bb[rr] > 0) ? 1.f : 0.f;
    }
    float* h = out + TOTA;
    float* cn = out + 2 * TOTA + TOTB;
    #pragma unroll
    for (int nt = 0; nt < 4; ++nt) {
      int col = nt * 16 + l15;
      #pragma unroll
      for (int q = 0; q < 4; ++q) {
        int rr = row0 + l4 * 4 + q;
        if (rr >= NB) continue;
        float zi = z[0][nt][q] + mab[q] * Bv[(0 * 5 + 2) * 64 + col] + mbb[q] * Bv[(0 * 5 + 3) * 64 + col] + Bv[(0 * 5 + 4) * 64 + col];
        float zf = z[1][nt][q] + mab[q] * Bv[(1 * 5 + 2) * 64 + col] + mbb[q] * Bv[(1 * 5 + 3) * 64 + col] + Bv[(1 * 5 + 4) * 64 + col];
        float zo = z[2][nt][q] + mab[q] * Bv[(2 * 5 + 2) * 64 + col] + mbb[q] * Bv[(2 * 5 + 3) * 64 + col] + Bv[(2 * 5 + 4) * 64 + col];
        float zg = z[3][nt][q] + mab[q] * Bv[(3 * 5 + 2) * 64 + col] + mbb[q] * Bv[(3 * 5 + 3) * 64 + col] + Bv[(3 * 5 + 4) * 64 + col];
        float ig = fast_sigmoid(zi);
        float fg = fast_sigmoid(zf);
        float og = fast_sigmoid(zo);
        float gg = fast_tanh(zg);
        size_t idx = (size_t)rr * 64 + col;
        float cv = fg * c_b[idx] + ig * gg;
        h[idx] = og * fast_tanh(cv);
        cn[idx] = cv;
      }
    }
  }
  #undef FRAG
}

extern "C" void kernel_launch(void* const* d_in, const int* in_sizes, int n_in,
                              void* d_out, int out_size, void* d_ws, size_t ws_size,
                              hipStream_t stream) {
  (void)in_sizes; (void)n_in; (void)out_size; (void)ws_size;
  const float* x_a    = (const float*)d_in[0];
  const float* x_b    = (const float*)d_in[1];
  const float* c_a    = (const float*)d_in[2];
  const float* c_b    = (const float*)d_in[3];
  const float* lin_w  = (const float*)d_in[4];
  const float* lin_b  = (const float*)d_in[5];
  const float* conv_wl = (const float*)d_in[6];
  const float* conv_wr = (const float*)d_in[7];
  const float* conv_cb = (const float*)d_in[8];
  const int* src_aa = (const int*)d_in[9];
  const int* dst_aa = (const int*)d_in[10];
  const int* src_ab = (const int*)d_in[11];
  const int* dst_ab = (const int*)d_in[12];
  const int* src_bb = (const int*)d_in[13];
  const int* dst_bb = (const int*)d_in[14];

  char* ws = (char*)d_ws;
  size_t off = 0;
  auto alloc = [&](size_t bytes) -> char* {
    off = (off + 255) & ~(size_t)255;
    char* p = ws + off;
    off += bytes;
    return p;
  };
  bf16* xab = (bf16*)alloc((size_t)NA * 32 * 2);
  bf16* xbb = (bf16*)alloc((size_t)NB * 32 * 2);
  bf16* P   = (bf16*)alloc((size_t)NA * 32 * 2);
  bf16* P2  = (bf16*)alloc((size_t)NA * 32 * 2);
  bf16* Q   = (bf16*)alloc((size_t)NB * 32 * 2);
  bf16* R   = (bf16*)alloc((size_t)NB * 32 * 2);
  bf16* Q2  = (bf16*)alloc((size_t)NB * 32 * 2);
  bf16* S   = (bf16*)alloc((size_t)NB * 32 * 2);
  bf16* T   = (bf16*)alloc((size_t)NB * 32 * 2);
  float* Mbuf = (float*)alloc((size_t)20 * 2048 * 4);
  bf16* Wfrag = (bf16*)alloc((size_t)36 * 4 * 64 * 8 * 2);
  float* Bv = (float*)alloc((size_t)4 * 5 * 64 * 4);
  int* col_aa  = (int*)alloc((size_t)EAA * 4);
  int* col_ab  = (int*)alloc((size_t)EAB * 4);
  int* col_bb  = (int*)alloc((size_t)EBB * 4);
  int* pk_aa   = (int*)alloc((size_t)EAA * 4);
  int* pk_ab   = (int*)alloc((size_t)EAB * 4);
  int* pk_bb   = (int*)alloc((size_t)EBB * 4);
  int* start_aa = (int*)alloc((size_t)NA * 4);
  int* start_ab = (int*)alloc((size_t)NB * 4);
  int* start_bb = (int*)alloc((size_t)NB * 4);
  int* cnt_aa  = (int*)alloc((size_t)NA * 4);
  int* cnt_ab  = (int*)alloc((size_t)NB * 4);
  int* cnt_bb  = (int*)alloc((size_t)NB * 4);
  int* binAA   = (int*)alloc((size_t)BKA * NBKAA * 4);
  int* binAB   = (int*)alloc((size_t)BKB * NBKB * 4);
  int* binBB   = (int*)alloc((size_t)BKB * NBKB * 4);
  int* totAA   = (int*)alloc((size_t)NBKAA * 4);
  int* totAB   = (int*)alloc((size_t)NBKB * 4);
  int* totBB   = (int*)alloc((size_t)NBKB * 4);
  int* bsAA    = (int*)alloc((size_t)(NBKAA + 1) * 4);
  int* bsAB    = (int*)alloc((size_t)(NBKB + 1) * 4);
  int* bsBB    = (int*)alloc((size_t)(NBKB + 1) * 4);

  // weight folding (parallelized) + x cast
  kW1<<<20, 256, 0, stream>>>(lin_w, conv_wl, conv_wr, Mbuf);
  kW2<<<40, 256, 0, stream>>>(Mbuf, conv_wl, conv_wr, conv_cb, lin_b, Wfrag, Bv);
  k_cast2<<<4688, 256, 0, stream>>>(x_a, x_b, xab, xbb);

  // atomic-free CSR build (counting sort)
  kA_bin<<<BKA + 2 * BKB, 256, 0, stream>>>(dst_aa, dst_ab, dst_bb, binAA, binAB, binBB);
  kB1<<<(NBKAA + 2 * NBKB) / 4, 256, 0, stream>>>(binAA, binAB, binBB, totAA, totAB, totBB);
  kB2<<<3, 256, 0, stream>>>(totAA, totAB, totBB, bsAA, bsAB, bsBB);
  kC_scatter<<<BKA + 2 * BKB, 256, 0, stream>>>(src_aa, dst_aa, src_ab, dst_ab, src_bb, dst_bb,
                                                binAA, binAB, binBB, bsAA, bsAB, bsBB,
                                                pk_aa, pk_ab, pk_bb);
  kD_nodesort<<<NBKAA + 2 * NBKB, 256, 0, stream>>>(pk_aa, pk_ab, pk_bb, bsAA, bsAB, bsBB,
                                                    col_aa, col_ab, col_bb,
                                                    start_aa, cnt_aa, start_ab, cnt_ab,
                                                    start_bb, cnt_bb);

  // aggregation chains (32-ch rows only)
  k_aggP1<<<50000, 256, 0, stream>>>(xab, xbb, P, Q, R,
                                     start_aa, cnt_aa, col_aa,
                                     start_ab, cnt_ab, col_ab,
                                     start_bb, cnt_bb, col_bb);
  k_aggP2<<<50000, 256, 0, stream>>>(P, Q, R, P2, Q2, S, T,
                                     start_aa, cnt_aa, col_aa,
                                     start_ab, cnt_ab, col_ab,
                                     start_bb, cnt_bb, col_bb);

  // fused z-matmul + LSTM (A and B in one launch)
  k_fin<<<GFA + GFB, 256, 0, stream>>>(xab, P, P2, xbb, Q, R, Q2, S, T,
                                       Wfrag, Bv, cnt_aa, cnt_ab, cnt_bb,
                                       c_a, c_b, (float*)d_out);
}